// Round 4
// baseline (704.185 us; speedup 1.0000x reference)
//
#include <hip/hip_runtime.h>
#include <math.h>

#define P 16384               // 128*128 pixels
#define SCALEF 0.08838834764831845f             // 128^-0.5
#define QSCALE 0.12752075616290145f             // SCALEF * log2(e)

typedef short bf16x8 __attribute__((ext_vector_type(8)));
typedef float f32x4 __attribute__((ext_vector_type(4)));

__device__ __forceinline__ unsigned short f2bf(float x) {
  union { float f; unsigned int u; } v; v.f = x;
  unsigned int r = v.u + 0x7fffu + ((v.u >> 16) & 1u);  // RNE
  return (unsigned short)(r >> 16);
}
__device__ __forceinline__ unsigned int packbf(float a, float b) {
  return (unsigned int)f2bf(a) | ((unsigned int)f2bf(b) << 16);
}
// pack two f32 -> bf16 pair (round-half-up) via v_perm: 3 VALU
__device__ __forceinline__ unsigned int pr2(float a, float b) {
  union { float f; unsigned int u; } ua, ub; ua.f = a; ub.f = b;
  return __builtin_amdgcn_perm(ub.u + 0x8000u, ua.u + 0x8000u, 0x07060302u);
}

#define AS1C(p) ((__attribute__((address_space(1))) void*)((void*)(p)))
#define AS3(p)  ((__attribute__((address_space(3))) void*)((void*)(p)))
#define GLDS16(g, l) __builtin_amdgcn_global_load_lds(AS1C(g), AS3(l), 16, 0, 0)

// ---------------------------------------------------------------------------
// Generic 1x1 conv as GEMM: out[oc][p] = sum_ic w[oc][ic]*in[ic][p] (+bias)
// ---------------------------------------------------------------------------
__global__ __launch_bounds__(256) void k_conv1x1(
    const float* __restrict__ in, const float* __restrict__ w,
    const float* __restrict__ bias, float* __restrict__ out, int IC)
{
  __shared__ float aL[16][64];    // [kk][oc]
  __shared__ float bL[16][128];   // [kk][pp]
  const int p0  = blockIdx.x * 128;
  const int oc0 = blockIdx.y * 64;
  const int tid = threadIdx.x;
  const int pcol = tid & 31;
  const int orow = tid >> 5;
  float acc[8][4] = {};

  for (int k0 = 0; k0 < IC; k0 += 16) {
    {
      int e = tid * 4;
      int oc_l = e >> 4;
      int kk = e & 15;
      float4 wv = *(const float4*)&w[(oc0 + oc_l) * IC + k0 + kk];
      aL[kk+0][oc_l] = wv.x; aL[kk+1][oc_l] = wv.y;
      aL[kk+2][oc_l] = wv.z; aL[kk+3][oc_l] = wv.w;
    }
    {
      #pragma unroll
      for (int q = 0; q < 2; ++q) {
        int e4 = tid * 2 + q;
        int kk = e4 >> 5;
        int p4 = e4 & 31;
        float4 bv = *(const float4*)&in[(k0 + kk) * P + p0 + p4 * 4];
        *(float4*)&bL[kk][p4 * 4] = bv;
      }
    }
    __syncthreads();
    #pragma unroll
    for (int kk = 0; kk < 16; ++kk) {
      float4 bv = *(const float4*)&bL[kk][pcol * 4];
      float a[8];
      #pragma unroll
      for (int i = 0; i < 8; ++i) a[i] = aL[kk][orow * 8 + i];
      #pragma unroll
      for (int i = 0; i < 8; ++i) {
        acc[i][0] += a[i] * bv.x; acc[i][1] += a[i] * bv.y;
        acc[i][2] += a[i] * bv.z; acc[i][3] += a[i] * bv.w;
      }
    }
    __syncthreads();
  }
  #pragma unroll
  for (int i = 0; i < 8; ++i) {
    int oc = oc0 + orow * 8 + i;
    float bb = bias ? bias[oc] : 0.f;
    float4 o;
    o.x = acc[i][0] + bb; o.y = acc[i][1] + bb;
    o.z = acc[i][2] + bb; o.w = acc[i][3] + bb;
    *(float4*)&out[oc * P + p0 + pcol * 4] = o;
  }
}

// ---------------------------------------------------------------------------
// Depthwise KxK conv
// ---------------------------------------------------------------------------
template<int K>
__global__ __launch_bounds__(256) void k_dw(
    const float* __restrict__ in, const float* __restrict__ w,
    float* __restrict__ out)
{
  const int c = blockIdx.y;
  const int p = blockIdx.x * 256 + threadIdx.x;
  const int y = p >> 7, x = p & 127;
  const float* wp = &w[c * K * K];
  const float* ip = &in[c * P];
  float acc = 0.f;
  #pragma unroll
  for (int dy = 0; dy < K; ++dy) {
    int yy = y + dy - K / 2;
    if (yy < 0 || yy > 127) continue;
    #pragma unroll
    for (int dx = 0; dx < K; ++dx) {
      int xx = x + dx - K / 2;
      if (xx < 0 || xx > 127) continue;
      acc += wp[dy * K + dx] * ip[yy * 128 + xx];
    }
  }
  out[c * P + p] = acc;
}

// ---------------------------------------------------------------------------
// Grouped pointwise (12 groups of 32->32)
// ---------------------------------------------------------------------------
__global__ __launch_bounds__(256) void k_pw(
    const float* __restrict__ in, const float* __restrict__ w,
    float* __restrict__ out)
{
  const int g = blockIdx.y;
  const int p = blockIdx.x * 256 + threadIdx.x;
  __shared__ float wL[1024];
  for (int e = threadIdx.x; e < 1024; e += 256) wL[e] = w[g * 1024 + e];
  __syncthreads();
  float r[32];
  #pragma unroll
  for (int i = 0; i < 32; ++i) r[i] = in[(g * 32 + i) * P + p];
  #pragma unroll
  for (int o = 0; o < 32; ++o) {
    float acc = 0.f;
    #pragma unroll
    for (int i = 0; i < 32; ++i) acc += wL[o * 32 + i] * r[i];
    out[(g * 32 + o) * P + p] = acc;
  }
}

// ---------------------------------------------------------------------------
// Window max of q (ch 0..127) and k (ch 128..255)
// ---------------------------------------------------------------------------
__global__ __launch_bounds__(256) void k_winmax(
    const float* __restrict__ e0, const float* __restrict__ e1,
    const float* __restrict__ e2, float* __restrict__ qwin,
    float* __restrict__ kwin)
{
  const int b = blockIdx.y;
  const int wIdx = blockIdx.x;
  const float* e = (b == 0) ? e0 : ((b == 1) ? e1 : e2);
  const int c = threadIdx.x;
  const int wy = wIdx >> 3, wx = wIdx & 7;
  const float* base = &e[c * P + (wy * 16) * 128 + wx * 16];
  float m = -INFINITY;
  for (int iy = 0; iy < 16; ++iy) {
    const float4* row = (const float4*)&base[iy * 128];
    #pragma unroll
    for (int j = 0; j < 4; ++j) {
      float4 v = row[j];
      m = fmaxf(m, fmaxf(fmaxf(v.x, v.y), fmaxf(v.z, v.w)));
    }
  }
  if (c < 128) qwin[(b * 64 + wIdx) * 128 + c] = m;
  else         kwin[(b * 64 + wIdx) * 128 + (c - 128)] = m;
}

// ---------------------------------------------------------------------------
// Window logits (64x64) + top-4 (ties -> lowest index) — exact fp32
// dot phase parallelized 4x; selection sweep on first wave.
// ---------------------------------------------------------------------------
__global__ __launch_bounds__(256) void k_topk(
    const float* __restrict__ qwin, const float* __restrict__ kwin,
    int* __restrict__ ridx)
{
  const int b = blockIdx.x;
  const int i = threadIdx.x & 63, jq = threadIdx.x >> 6;
  __shared__ float lg[64][68];
  float4 qr[32];
  const float4* q4 = (const float4*)&qwin[(b * 64 + i) * 128];
  #pragma unroll
  for (int t = 0; t < 32; ++t) qr[t] = q4[t];
  for (int jj = 0; jj < 16; ++jj) {
    const int j = jq * 16 + jj;
    const float4* k4 = (const float4*)&kwin[(b * 64 + j) * 128];
    float acc = 0.f;
    #pragma unroll
    for (int t = 0; t < 32; ++t) {
      float4 kv = k4[t];
      acc += qr[t].x * kv.x + qr[t].y * kv.y + qr[t].z * kv.z + qr[t].w * kv.w;
    }
    lg[i][j] = acc * SCALEF;
  }
  __syncthreads();
  if (threadIdx.x < 64) {
    unsigned long long mask = 0ull;
    for (int r = 0; r < 4; ++r) {
      float best = -INFINITY; int bj = 0;
      for (int j = 0; j < 64; ++j) {
        if ((mask >> j) & 1ull) continue;
        float v = lg[i][j];
        if (v > best) { best = v; bj = j; }   // strict > keeps lowest index
      }
      mask |= (1ull << bj);
      ridx[(b * 64 + i) * 4 + r] = bj;
    }
  }
}

// ---------------------------------------------------------------------------
// Repack Q/K/V into bf16 images pre-laid-out in LDS byte order.
// Per (b,h,w): kvimg block = 8192 u32: [half0: K 128x16 u32 | V 32x64 u32]
//                                      [half1: K | V], swizzles baked in.
// qimg block = 4096 u32: [q 0..255][16 d-pair u32], Q scaled by SCALE*log2e.
// ---------------------------------------------------------------------------
__global__ __launch_bounds__(256) void k_repack(
    const float* __restrict__ e0, const float* __restrict__ e1,
    const float* __restrict__ e2, unsigned int* __restrict__ kvimg,
    unsigned int* __restrict__ qimg)
{
  const int b = blockIdx.z, h = blockIdx.y, w = blockIdx.x;
  const float* e = (b == 0) ? e0 : ((b == 1) ? e1 : e2);
  const int wy = w >> 3, wx = w & 7;
  const int jbase = wy * 16 * 128 + wx * 16;
  const int t = threadIdx.x;
  unsigned int* kwin_img = kvimg + (size_t)((b * 4 + h) * 64 + w) * 8192;
  unsigned int* qwin_img = qimg  + (size_t)((b * 4 + h) * 64 + w) * 4096;

  // K + Q: thread = pixel (key/query) 0..255, 16 u32 each
  {
    const int key = t;
    const int hw = jbase + (key >> 4) * 128 + (key & 15);
    const float* eK = e + (size_t)(128 + h * 32) * P + hw;
    const float* eQ = e + (size_t)(h * 32) * P + hw;
    const int half = key >> 7, kl = key & 127;
    unsigned int* kd = kwin_img + half * 4096 + kl * 16;
    unsigned int* qd = qwin_img + key * 16;
    #pragma unroll
    for (int dd = 0; dd < 16; ++dd) {
      float k0 = eK[(size_t)(2 * dd) * P], k1 = eK[(size_t)(2 * dd + 1) * P];
      kd[dd ^ ((kl & 3) << 2)] = packbf(k0, k1);
      float q0 = eQ[(size_t)(2 * dd) * P] * QSCALE;
      float q1 = eQ[(size_t)(2 * dd + 1) * P] * QSCALE;
      qd[dd] = packbf(q0, q1);
    }
  }
  // V^T: [d][key] row-XOR swizzled, u32 = key-pair; 16 u32 per thread
  // (4 threads per (half,d) row x 16 u32 = 64 u32 = 128 keys: full row)
  {
    const int half = t >> 7, tt = t & 127;
    const int d = tt >> 2;
    const int kp0 = (tt & 3) * 16;
    const float* eV = e + (size_t)(256 + h * 32 + d) * P;
    unsigned int* vd = kwin_img + half * 4096 + 2048 + d * 64;
    #pragma unroll
    for (int i = 0; i < 16; ++i) {
      const int kp2 = kp0 + i;
      const int key = half * 128 + kp2 * 2;
      const int hw = jbase + (key >> 4) * 128 + (key & 15);
      float v0 = eV[hw], v1 = eV[hw + 1];
      vd[kp2 ^ ((d & 7) << 2)] = packbf(v0, v1);
    }
  }
}

// ---------------------------------------------------------------------------
// MFMA flash attention, pipelined. block = (w,h,b); 4 waves x 64 queries.
// 128-key chunks double-buffered in LDS via global_load_lds (linear 16KB
// copies of pre-swizzled images), counted vmcnt(4) so prefetch loads stay
// in flight across raw s_barriers. Softmax in exp2 domain; P packed via
// v_perm; K-frags reused across 2 query tiles, V-frags across all 4.
// ---------------------------------------------------------------------------
__global__ __launch_bounds__(256) void k_attn_mfma(
    const unsigned int* __restrict__ kvimg, const unsigned int* __restrict__ qimg,
    const int* __restrict__ ridx, float* __restrict__ attnch)
{
  const int b = blockIdx.z, h = blockIdx.y, w = blockIdx.x;
  const int tid = threadIdx.x;
  const int wv = tid >> 6, lane = tid & 63;
  const int qi = lane & 15, g = lane >> 4;
  const int wy = w >> 3, wx = w & 7;

  __shared__ __align__(16) unsigned int kvbuf[2][4096];   // 2 x 16KB

  const unsigned int* kwin = kvimg + (size_t)((b * 4 + h) * 64) * 8192;
  const unsigned int* qwin = qimg + (size_t)((b * 4 + h) * 64 + w) * 4096;

  // Q fragments: lane (qi,g), tile s: Q[q=(wv*4+s)*16+qi][d=8g..8g+7]
  bf16x8 qv[4];
  #pragma unroll
  for (int s = 0; s < 4; ++s) {
    union { uint4 u; bf16x8 v; } tq;
    tq.u = *(const uint4*)(qwin + ((wv * 4 + s) * 16 + qi) * 16 + g * 4);
    qv[s] = tq.v;
  }
  const int4 jv = *(const int4*)(ridx + (b * 64 + w) * 4);
  const int ja[4] = {jv.x, jv.y, jv.z, jv.w};

  const f32x4 fz = {0.f, 0.f, 0.f, 0.f};
  float m[4], l[4];
  f32x4 acc[4][2];
  #pragma unroll
  for (int s = 0; s < 4; ++s) {
    m[s] = -3.0e38f; l[s] = 0.f; acc[s][0] = fz; acc[s][1] = fz;
  }

  // drain Q/ridx loads so vmcnt counts below are exact
  asm volatile("s_waitcnt vmcnt(0)" ::: "memory");
  __builtin_amdgcn_sched_barrier(0);

  // prologue: stage chunk 0
  {
    const unsigned int* src = kwin + (size_t)ja[0] * 8192;
    #pragma unroll
    for (int i = 0; i < 4; ++i)
      GLDS16(src + wv * 1024 + i * 256 + lane * 4,
             (unsigned int*)kvbuf[0] + wv * 1024 + i * 256);
  }

#define SOFTMAX_PACK(SC, S) {                                               \
    float wmax = -3.0e38f;                                                  \
    _Pragma("unroll") for (int c = 0; c < 4; ++c)                           \
      _Pragma("unroll") for (int u = 0; u < 2; ++u)                         \
        _Pragma("unroll") for (int t2 = 0; t2 < 4; ++t2)                    \
          wmax = fmaxf(wmax, SC[c][u][t2]);                                 \
    wmax = fmaxf(wmax, __shfl_xor(wmax, 16, 64));                           \
    wmax = fmaxf(wmax, __shfl_xor(wmax, 32, 64));                           \
    const float mnew = fmaxf(m[S], wmax);                                   \
    const float corr = exp2f(m[S] - mnew);                                  \
    m[S] = mnew;                                                            \
    acc[S][0] *= corr; acc[S][1] *= corr;                                   \
    float psum = 0.f;                                                       \
    _Pragma("unroll") for (int c = 0; c < 4; ++c)                           \
      _Pragma("unroll") for (int u = 0; u < 2; ++u) {                       \
        const float p0 = exp2f(SC[c][u][0] - mnew);                         \
        const float p1 = exp2f(SC[c][u][1] - mnew);                         \
        const float p2 = exp2f(SC[c][u][2] - mnew);                         \
        const float p3 = exp2f(SC[c][u][3] - mnew);                         \
        psum += (p0 + p1) + (p2 + p3);                                      \
        pb[S][c][2 * u]     = pr2(p0, p1);                                  \
        pb[S][c][2 * u + 1] = pr2(p2, p3);                                  \
      }                                                                     \
    psum += __shfl_xor(psum, 16, 64);                                       \
    psum += __shfl_xor(psum, 32, 64);                                       \
    l[S] = l[S] * corr + psum;                                              \
  }

  #pragma unroll
  for (int ch = 0; ch < 8; ++ch) {
    const int cur = ch & 1;
    asm volatile("s_barrier" ::: "memory");      // buf[cur^1] free to overwrite
    if (ch < 7) {
      const int nx = ch + 1;
      const unsigned int* src = kwin + (size_t)ja[nx >> 1] * 8192 + (nx & 1) * 4096;
      #pragma unroll
      for (int i = 0; i < 4; ++i)
        GLDS16(src + wv * 1024 + i * 256 + lane * 4,
               (unsigned int*)kvbuf[cur ^ 1] + wv * 1024 + i * 256);
      asm volatile("s_waitcnt vmcnt(4)" ::: "memory");   // buf[cur] landed
    } else {
      asm volatile("s_waitcnt vmcnt(0)" ::: "memory");
    }
    __builtin_amdgcn_sched_barrier(0);
    asm volatile("s_barrier" ::: "memory");      // all waves see buf[cur]

    const bf16x8* kp = (const bf16x8*)kvbuf[cur];
    const unsigned short* vsh = (const unsigned short*)(kvbuf[cur] + 2048);
    unsigned int pb[4][4][4];

    #pragma unroll
    for (int pr = 0; pr < 2; ++pr) {
      f32x4 scA[4][2], scB[4][2];
      #pragma unroll
      for (int c = 0; c < 4; ++c) {
        #pragma unroll
        for (int u = 0; u < 2; ++u) {
          const int key = 32 * c + 8 * (qi >> 2) + 4 * u + (qi & 3);
          const bf16x8 ka = kp[key * 4 + (g ^ (qi & 3))];
          scA[c][u] = __builtin_amdgcn_mfma_f32_16x16x32_bf16(ka, qv[2 * pr], fz, 0, 0, 0);
          scB[c][u] = __builtin_amdgcn_mfma_f32_16x16x32_bf16(ka, qv[2 * pr + 1], fz, 0, 0, 0);
        }
      }
      SOFTMAX_PACK(scA, (2 * pr));
      SOFTMAX_PACK(scB, (2 * pr + 1));
    }
    // PV: V-frag loaded once, feeds all 4 query tiles
    #pragma unroll
    for (int c = 0; c < 4; ++c) {
      #pragma unroll
      for (int dt = 0; dt < 2; ++dt) {
        const int d0 = dt * 16 + qi;
        const bf16x8 va = *(const bf16x8*)&vsh[
            (unsigned)((d0 * 128 + 32 * c + 8 * g) ^ ((d0 & 7) << 3))];
        #pragma unroll
        for (int s = 0; s < 4; ++s) {
          union { unsigned int u4[4]; bf16x8 v; } pv;
          pv.u4[0] = pb[s][c][0]; pv.u4[1] = pb[s][c][1];
          pv.u4[2] = pb[s][c][2]; pv.u4[3] = pb[s][c][3];
          acc[s][dt] = __builtin_amdgcn_mfma_f32_16x16x32_bf16(va, pv.v, acc[s][dt], 0, 0, 0);
        }
      }
    }
  }
#undef SOFTMAX_PACK

  // epilogue: lane (qi,g) holds O^T[d = dt*16+4g+t][q = s*16+qi]
  #pragma unroll
  for (int s = 0; s < 4; ++s) {
    const float inv = 1.f / l[s];
    const int hwq = (wy * 16 + wv * 4 + s) * 128 + wx * 16 + qi;
    #pragma unroll
    for (int dt = 0; dt < 2; ++dt)
      #pragma unroll
      for (int t = 0; t < 4; ++t) {
        const int d = dt * 16 + 4 * g + t;
        attnch[(size_t)(b * 128 + h * 32 + d) * P + hwq] = acc[s][dt][t] * inv;
      }
  }
}

// ---------------------------------------------------------------------------
// LayerNorm over 128 channels per pixel. 256 blocks x 256 thr (4 ch-groups)
// ---------------------------------------------------------------------------
__global__ __launch_bounds__(256) void k_ln(
    const float* __restrict__ in, const float* __restrict__ gg,
    const float* __restrict__ bta, float* __restrict__ out)
{
  const int l = threadIdx.x & 63;
  const int grp = threadIdx.x >> 6;
  const int p = blockIdx.x * 64 + l;
  __shared__ float s1[4][64], s2[4][64];
  float vals[32];
  float a = 0.f, b2 = 0.f;
  #pragma unroll
  for (int i = 0; i < 32; ++i) {
    float v = in[(size_t)(grp * 32 + i) * P + p];
    vals[i] = v; a += v; b2 += v * v;
  }
  s1[grp][l] = a; s2[grp][l] = b2;
  __syncthreads();
  const float sum = s1[0][l] + s1[1][l] + s1[2][l] + s1[3][l];
  const float sq  = s2[0][l] + s2[1][l] + s2[2][l] + s2[3][l];
  const float mu = sum * (1.f / 128.f);
  const float var = sq * (1.f / 128.f) - mu * mu;
  const float rs = rsqrtf(var + 1e-5f);
  #pragma unroll
  for (int i = 0; i < 32; ++i) {
    const int c = grp * 32 + i;
    out[(size_t)c * P + p] = (vals[i] - mu) * rs * gg[c] + bta[c];
  }
}

// ---------------------------------------------------------------------------
extern "C" void kernel_launch(void* const* d_in, const int* in_sizes, int n_in,
                              void* d_out, int out_size, void* d_ws, size_t ws_size,
                              hipStream_t stream)
{
  (void)in_sizes; (void)n_in; (void)out_size;
  const float* x      = (const float*)d_in[0];
  const float* qkv2_w = (const float*)d_in[1];
  const float* dw3_w  = (const float*)d_in[2];
  const float* pw3_w  = (const float*)d_in[3];
  const float* dw5_w  = (const float*)d_in[4];
  const float* pw5_w  = (const float*)d_in[5];
  const float* mlp_w  = (const float*)d_in[6];
  const float* mlp_b  = (const float*)d_in[7];
  const float* proj_w = (const float*)d_in[8];
  const float* ln_g   = (const float*)d_in[9];
  const float* ln_b   = (const float*)d_in[10];

  float* ws = (float*)d_ws;
  const size_t CH = (size_t)384 * P;
  // region liveness:
  //  ws+0   : qkv (fp32)            -> projo (after repack)
  //  ws+CH  : dwt (dw tmp)          -> qimg (bf16, after pw5)
  //  ws+2CH : y3                    -> attnch (after repack)
  //  ws+3CH : y5
  //  ws+4CH : kvimg (bf16, 25.2MB)  -> cat (after attn)
  //  ws+5CH : qwin | kwin | ridx
  float* qkv    = ws;
  float* dwt    = ws + CH;
  float* y3     = ws + 2 * CH;
  float* y5     = ws + 3 * CH;
  float* cat    = ws + 4 * CH;
  float* qwin   = ws + 5 * CH;
  float* kwin   = qwin + 3 * 64 * 128;
  int*   ridx   = (int*)(kwin + 3 * 64 * 128);
  unsigned int* kvimg = (unsigned int*)cat;
  unsigned int* qimg  = (unsigned int*)dwt;
  float* attnch = y3;
  float* projo  = qkv;
  (void)ws_size;

  k_conv1x1<<<dim3(128, 6), 256, 0, stream>>>(x, qkv2_w, nullptr, qkv, 128);
  k_dw<3><<<dim3(64, 384), 256, 0, stream>>>(qkv, dw3_w, dwt);
  k_pw<<<dim3(64, 12), 256, 0, stream>>>(dwt, pw3_w, y3);
  k_dw<5><<<dim3(64, 384), 256, 0, stream>>>(qkv, dw5_w, dwt);
  k_pw<<<dim3(64, 12), 256, 0, stream>>>(dwt, pw5_w, y5);
  k_winmax<<<dim3(64, 3), 256, 0, stream>>>(qkv, y3, y5, qwin, kwin);
  k_topk<<<dim3(3), 256, 0, stream>>>(qwin, kwin, ridx);
  k_repack<<<dim3(64, 4, 3), 256, 0, stream>>>(qkv, y3, y5, kvimg, qimg);
  k_attn_mfma<<<dim3(64, 4, 3), 256, 0, stream>>>(kvimg, qimg, ridx, attnch);
  for (int b = 0; b < 3; ++b)
    k_conv1x1<<<dim3(128, 2), 256, 0, stream>>>(attnch + (size_t)b * 128 * P,
                                                mlp_w, mlp_b,
                                                cat + (size_t)b * 128 * P, 128);
  k_conv1x1<<<dim3(128, 2), 256, 0, stream>>>(cat, proj_w, nullptr, projo, 384);
  k_ln<<<dim3(256), 256, 0, stream>>>(projo, ln_g, ln_b, (float*)d_out);
}

// Round 5
// 513.462 us; speedup vs baseline: 1.3714x; 1.3714x over previous
//
#include <hip/hip_runtime.h>
#include <math.h>

#define P 16384               // 128*128 pixels
#define SCALEF 0.08838834764831845f             // 128^-0.5
#define QSCALE 0.12752075616290145f             // SCALEF * log2(e)

typedef short bf16x8 __attribute__((ext_vector_type(8)));
typedef float f32x4 __attribute__((ext_vector_type(4)));

__device__ __forceinline__ unsigned short f2bf(float x) {
  union { float f; unsigned int u; } v; v.f = x;
  unsigned int r = v.u + 0x7fffu + ((v.u >> 16) & 1u);  // RNE
  return (unsigned short)(r >> 16);
}
__device__ __forceinline__ unsigned int packbf(float a, float b) {
  return (unsigned int)f2bf(a) | ((unsigned int)f2bf(b) << 16);
}
// pack two f32 -> bf16 pair (round-half-up) via v_perm: 3 VALU
__device__ __forceinline__ unsigned int pr2(float a, float b) {
  union { float f; unsigned int u; } ua, ub; ua.f = a; ub.f = b;
  return __builtin_amdgcn_perm(ub.u + 0x8000u, ua.u + 0x8000u, 0x07060302u);
}

// ---------------------------------------------------------------------------
// Generic 1x1 conv as GEMM: out[oc][p] = sum_ic w[oc][ic]*in[ic][p] (+bias)
// ---------------------------------------------------------------------------
__global__ __launch_bounds__(256) void k_conv1x1(
    const float* __restrict__ in, const float* __restrict__ w,
    const float* __restrict__ bias, float* __restrict__ out, int IC)
{
  __shared__ float aL[16][64];    // [kk][oc]
  __shared__ float bL[16][128];   // [kk][pp]
  const int p0  = blockIdx.x * 128;
  const int oc0 = blockIdx.y * 64;
  const int tid = threadIdx.x;
  const int pcol = tid & 31;
  const int orow = tid >> 5;
  float acc[8][4] = {};

  for (int k0 = 0; k0 < IC; k0 += 16) {
    {
      int e = tid * 4;
      int oc_l = e >> 4;
      int kk = e & 15;
      float4 wv = *(const float4*)&w[(oc0 + oc_l) * IC + k0 + kk];
      aL[kk+0][oc_l] = wv.x; aL[kk+1][oc_l] = wv.y;
      aL[kk+2][oc_l] = wv.z; aL[kk+3][oc_l] = wv.w;
    }
    {
      #pragma unroll
      for (int q = 0; q < 2; ++q) {
        int e4 = tid * 2 + q;
        int kk = e4 >> 5;
        int p4 = e4 & 31;
        float4 bv = *(const float4*)&in[(k0 + kk) * P + p0 + p4 * 4];
        *(float4*)&bL[kk][p4 * 4] = bv;
      }
    }
    __syncthreads();
    #pragma unroll
    for (int kk = 0; kk < 16; ++kk) {
      float4 bv = *(const float4*)&bL[kk][pcol * 4];
      float a[8];
      #pragma unroll
      for (int i = 0; i < 8; ++i) a[i] = aL[kk][orow * 8 + i];
      #pragma unroll
      for (int i = 0; i < 8; ++i) {
        acc[i][0] += a[i] * bv.x; acc[i][1] += a[i] * bv.y;
        acc[i][2] += a[i] * bv.z; acc[i][3] += a[i] * bv.w;
      }
    }
    __syncthreads();
  }
  #pragma unroll
  for (int i = 0; i < 8; ++i) {
    int oc = oc0 + orow * 8 + i;
    float bb = bias ? bias[oc] : 0.f;
    float4 o;
    o.x = acc[i][0] + bb; o.y = acc[i][1] + bb;
    o.z = acc[i][2] + bb; o.w = acc[i][3] + bb;
    *(float4*)&out[oc * P + p0 + pcol * 4] = o;
  }
}

// ---------------------------------------------------------------------------
// Depthwise KxK conv
// ---------------------------------------------------------------------------
template<int K>
__global__ __launch_bounds__(256) void k_dw(
    const float* __restrict__ in, const float* __restrict__ w,
    float* __restrict__ out)
{
  const int c = blockIdx.y;
  const int p = blockIdx.x * 256 + threadIdx.x;
  const int y = p >> 7, x = p & 127;
  const float* wp = &w[c * K * K];
  const float* ip = &in[c * P];
  float acc = 0.f;
  #pragma unroll
  for (int dy = 0; dy < K; ++dy) {
    int yy = y + dy - K / 2;
    if (yy < 0 || yy > 127) continue;
    #pragma unroll
    for (int dx = 0; dx < K; ++dx) {
      int xx = x + dx - K / 2;
      if (xx < 0 || xx > 127) continue;
      acc += wp[dy * K + dx] * ip[yy * 128 + xx];
    }
  }
  out[c * P + p] = acc;
}

// ---------------------------------------------------------------------------
// Grouped pointwise (12 groups of 32->32)
// ---------------------------------------------------------------------------
__global__ __launch_bounds__(256) void k_pw(
    const float* __restrict__ in, const float* __restrict__ w,
    float* __restrict__ out)
{
  const int g = blockIdx.y;
  const int p = blockIdx.x * 256 + threadIdx.x;
  __shared__ float wL[1024];
  for (int e = threadIdx.x; e < 1024; e += 256) wL[e] = w[g * 1024 + e];
  __syncthreads();
  float r[32];
  #pragma unroll
  for (int i = 0; i < 32; ++i) r[i] = in[(g * 32 + i) * P + p];
  #pragma unroll
  for (int o = 0; o < 32; ++o) {
    float acc = 0.f;
    #pragma unroll
    for (int i = 0; i < 32; ++i) acc += wL[o * 32 + i] * r[i];
    out[(g * 32 + o) * P + p] = acc;
  }
}

// ---------------------------------------------------------------------------
// Window max of q (ch 0..127) and k (ch 128..255)
// ---------------------------------------------------------------------------
__global__ __launch_bounds__(256) void k_winmax(
    const float* __restrict__ e0, const float* __restrict__ e1,
    const float* __restrict__ e2, float* __restrict__ qwin,
    float* __restrict__ kwin)
{
  const int b = blockIdx.y;
  const int wIdx = blockIdx.x;
  const float* e = (b == 0) ? e0 : ((b == 1) ? e1 : e2);
  const int c = threadIdx.x;
  const int wy = wIdx >> 3, wx = wIdx & 7;
  const float* base = &e[c * P + (wy * 16) * 128 + wx * 16];
  float m = -INFINITY;
  for (int iy = 0; iy < 16; ++iy) {
    const float4* row = (const float4*)&base[iy * 128];
    #pragma unroll
    for (int j = 0; j < 4; ++j) {
      float4 v = row[j];
      m = fmaxf(m, fmaxf(fmaxf(v.x, v.y), fmaxf(v.z, v.w)));
    }
  }
  if (c < 128) qwin[(b * 64 + wIdx) * 128 + c] = m;
  else         kwin[(b * 64 + wIdx) * 128 + (c - 128)] = m;
}

// ---------------------------------------------------------------------------
// Window logits (64x64) + top-4 (ties -> lowest index) — exact fp32
// ---------------------------------------------------------------------------
__global__ __launch_bounds__(256) void k_topk(
    const float* __restrict__ qwin, const float* __restrict__ kwin,
    int* __restrict__ ridx)
{
  const int b = blockIdx.x;
  const int i = threadIdx.x & 63, jq = threadIdx.x >> 6;
  __shared__ float lg[64][68];
  float4 qr[32];
  const float4* q4 = (const float4*)&qwin[(b * 64 + i) * 128];
  #pragma unroll
  for (int t = 0; t < 32; ++t) qr[t] = q4[t];
  for (int jj = 0; jj < 16; ++jj) {
    const int j = jq * 16 + jj;
    const float4* k4 = (const float4*)&kwin[(b * 64 + j) * 128];
    float acc = 0.f;
    #pragma unroll
    for (int t = 0; t < 32; ++t) {
      float4 kv = k4[t];
      acc += qr[t].x * kv.x + qr[t].y * kv.y + qr[t].z * kv.z + qr[t].w * kv.w;
    }
    lg[i][j] = acc * SCALEF;
  }
  __syncthreads();
  if (threadIdx.x < 64) {
    unsigned long long mask = 0ull;
    for (int r = 0; r < 4; ++r) {
      float best = -INFINITY; int bj = 0;
      for (int j = 0; j < 64; ++j) {
        if ((mask >> j) & 1ull) continue;
        float v = lg[i][j];
        if (v > best) { best = v; bj = j; }   // strict > keeps lowest index
      }
      mask |= (1ull << bj);
      ridx[(b * 64 + i) * 4 + r] = bj;
    }
  }
}

// ---------------------------------------------------------------------------
// Repack Q/K/V into bf16 images pre-laid-out in LDS byte order.
// Per (b,h,w): kvimg block = 8192 u32: [half0: K 128x16 u32 | V 32x64 u32]
//                                      [half1: K | V], swizzles baked in.
// qimg block = 4096 u32: [q 0..255][16 d-pair u32], Q scaled by SCALE*log2e.
// ---------------------------------------------------------------------------
__global__ __launch_bounds__(256) void k_repack(
    const float* __restrict__ e0, const float* __restrict__ e1,
    const float* __restrict__ e2, unsigned int* __restrict__ kvimg,
    unsigned int* __restrict__ qimg)
{
  const int b = blockIdx.z, h = blockIdx.y, w = blockIdx.x;
  const float* e = (b == 0) ? e0 : ((b == 1) ? e1 : e2);
  const int wy = w >> 3, wx = w & 7;
  const int jbase = wy * 16 * 128 + wx * 16;
  const int t = threadIdx.x;
  unsigned int* kwin_img = kvimg + (size_t)((b * 4 + h) * 64 + w) * 8192;
  unsigned int* qwin_img = qimg  + (size_t)((b * 4 + h) * 64 + w) * 4096;

  // K + Q: thread = pixel (key/query) 0..255, 16 u32 each
  {
    const int key = t;
    const int hw = jbase + (key >> 4) * 128 + (key & 15);
    const float* eK = e + (size_t)(128 + h * 32) * P + hw;
    const float* eQ = e + (size_t)(h * 32) * P + hw;
    const int half = key >> 7, kl = key & 127;
    unsigned int* kd = kwin_img + half * 4096 + kl * 16;
    unsigned int* qd = qwin_img + key * 16;
    #pragma unroll
    for (int dd = 0; dd < 16; ++dd) {
      float k0 = eK[(size_t)(2 * dd) * P], k1 = eK[(size_t)(2 * dd + 1) * P];
      kd[dd ^ ((kl & 3) << 2)] = packbf(k0, k1);
      float q0 = eQ[(size_t)(2 * dd) * P] * QSCALE;
      float q1 = eQ[(size_t)(2 * dd + 1) * P] * QSCALE;
      qd[dd] = packbf(q0, q1);
    }
  }
  // V^T: [d][key] row-XOR swizzled, u32 = key-pair; 16 u32 per thread
  {
    const int half = t >> 7, tt = t & 127;
    const int d = tt >> 2;
    const int kp0 = (tt & 3) * 16;
    const float* eV = e + (size_t)(256 + h * 32 + d) * P;
    unsigned int* vd = kwin_img + half * 4096 + 2048 + d * 64;
    #pragma unroll
    for (int i = 0; i < 16; ++i) {
      const int kp2 = kp0 + i;
      const int key = half * 128 + kp2 * 2;
      const int hw = jbase + (key >> 4) * 128 + (key & 15);
      float v0 = eV[hw], v1 = eV[hw + 1];
      vd[kp2 ^ ((d & 7) << 2)] = packbf(v0, v1);
    }
  }
}

// ---------------------------------------------------------------------------
// MFMA flash attention v3. block = (w,h,b); 4 waves x 64 queries.
// T14 async-STAGE: issue next chunk's 4 uint4 global loads into regs before
// the current chunk's compute (latency hides under MFMA+softmax), ds_write
// after the trailing barrier. No raw asm; loop not unrolled. l-reduce
// deferred to epilogue (rescale factors are row-uniform).
// ---------------------------------------------------------------------------
__global__ __launch_bounds__(256, 3) void k_attn_mfma(
    const unsigned int* __restrict__ kvimg, const unsigned int* __restrict__ qimg,
    const int* __restrict__ ridx, float* __restrict__ attnch)
{
  const int b = blockIdx.z, h = blockIdx.y, w = blockIdx.x;
  const int tid = threadIdx.x;
  const int wv = tid >> 6, lane = tid & 63;
  const int qi = lane & 15, g = lane >> 4;
  const int wy = w >> 3, wx = w & 7;

  __shared__ __align__(16) unsigned int kvbuf[2][4096];   // 2 x 16KB

  const unsigned int* kwin = kvimg + (size_t)((b * 4 + h) * 64) * 8192;
  const unsigned int* qwin = qimg + (size_t)((b * 4 + h) * 64 + w) * 4096;

  // Q fragments: lane (qi,g), tile s: Q[q=(wv*4+s)*16+qi][d=8g..8g+7]
  bf16x8 qv[4];
  #pragma unroll
  for (int s = 0; s < 4; ++s) {
    union { uint4 u; bf16x8 v; } tq;
    tq.u = *(const uint4*)(qwin + ((wv * 4 + s) * 16 + qi) * 16 + g * 4);
    qv[s] = tq.v;
  }
  const int4 jv = *(const int4*)(ridx + (b * 64 + w) * 4);
  const int ja[4] = {jv.x, jv.y, jv.z, jv.w};

  const f32x4 fz = {0.f, 0.f, 0.f, 0.f};
  float m[4], l[4];
  f32x4 acc[4][2];
  #pragma unroll
  for (int s = 0; s < 4; ++s) {
    m[s] = -3.0e38f; l[s] = 0.f; acc[s][0] = fz; acc[s][1] = fz;
  }

  // prologue: stage chunk 0 (regs -> LDS)
  uint4 st[4];
  {
    const uint4* s4 = (const uint4*)(kwin + (size_t)ja[0] * 8192);
    #pragma unroll
    for (int i = 0; i < 4; ++i) st[i] = s4[i * 256 + tid];
    uint4* d4 = (uint4*)kvbuf[0];
    #pragma unroll
    for (int i = 0; i < 4; ++i) d4[i * 256 + tid] = st[i];
  }

// softmax for one score tile -> packed bf16 P frags; l kept lane-local
#define SOFTMAX_PACK(SC, S, PB) {                                           \
    float wmax = -3.0e38f;                                                  \
    _Pragma("unroll") for (int c = 0; c < 4; ++c)                           \
      _Pragma("unroll") for (int u = 0; u < 2; ++u)                         \
        _Pragma("unroll") for (int t2 = 0; t2 < 4; ++t2)                    \
          wmax = fmaxf(wmax, SC[c][u][t2]);                                 \
    wmax = fmaxf(wmax, __shfl_xor(wmax, 16, 64));                           \
    wmax = fmaxf(wmax, __shfl_xor(wmax, 32, 64));                           \
    const float mnew = fmaxf(m[S], wmax);                                   \
    const float corr = exp2f(m[S] - mnew);                                  \
    m[S] = mnew;                                                            \
    acc[S][0] *= corr; acc[S][1] *= corr;                                   \
    float psum = 0.f;                                                       \
    _Pragma("unroll") for (int c = 0; c < 4; ++c)                           \
      _Pragma("unroll") for (int u = 0; u < 2; ++u) {                       \
        const float p0 = exp2f(SC[c][u][0] - mnew);                         \
        const float p1 = exp2f(SC[c][u][1] - mnew);                         \
        const float p2 = exp2f(SC[c][u][2] - mnew);                         \
        const float p3 = exp2f(SC[c][u][3] - mnew);                         \
        psum += (p0 + p1) + (p2 + p3);                                      \
        PB[c][2 * u]     = pr2(p0, p1);                                     \
        PB[c][2 * u + 1] = pr2(p2, p3);                                     \
      }                                                                     \
    l[S] = l[S] * corr + psum;                                              \
  }

  for (int ch = 0; ch < 8; ++ch) {
    // issue next chunk's loads early — latency hides under compute below
    if (ch < 7) {
      const int nx = ch + 1;
      const uint4* s4 = (const uint4*)(kwin + (size_t)ja[nx >> 1] * 8192
                                       + (size_t)(nx & 1) * 4096);
      #pragma unroll
      for (int i = 0; i < 4; ++i) st[i] = s4[i * 256 + tid];
    }
    __syncthreads();               // chunk ch's LDS writes visible everywhere

    const unsigned int* bc = kvbuf[ch & 1];
    const bf16x8* kp = (const bf16x8*)bc;
    const unsigned short* vsh = (const unsigned short*)(bc + 2048);

    #pragma unroll
    for (int pr = 0; pr < 2; ++pr) {
      f32x4 scA[4][2], scB[4][2];
      #pragma unroll
      for (int c = 0; c < 4; ++c) {
        #pragma unroll
        for (int u = 0; u < 2; ++u) {
          const int key = 32 * c + 8 * (qi >> 2) + 4 * u + (qi & 3);
          const bf16x8 ka = kp[key * 4 + (g ^ (qi & 3))];
          scA[c][u] = __builtin_amdgcn_mfma_f32_16x16x32_bf16(ka, qv[2 * pr], fz, 0, 0, 0);
          scB[c][u] = __builtin_amdgcn_mfma_f32_16x16x32_bf16(ka, qv[2 * pr + 1], fz, 0, 0, 0);
        }
      }
      unsigned int pbA[4][4], pbB[4][4];
      SOFTMAX_PACK(scA, (2 * pr), pbA);
      SOFTMAX_PACK(scB, (2 * pr + 1), pbB);
      // PV for tiles 2pr, 2pr+1; V-frag read once per pr
      #pragma unroll
      for (int c = 0; c < 4; ++c) {
        #pragma unroll
        for (int dt = 0; dt < 2; ++dt) {
          const int d0 = dt * 16 + qi;
          const bf16x8 va = *(const bf16x8*)&vsh[
              (unsigned)((d0 * 128 + 32 * c + 8 * g) ^ ((d0 & 7) << 3))];
          union { unsigned int u4[4]; bf16x8 v; } pva, pvb;
          pva.u4[0] = pbA[c][0]; pva.u4[1] = pbA[c][1];
          pva.u4[2] = pbA[c][2]; pva.u4[3] = pbA[c][3];
          pvb.u4[0] = pbB[c][0]; pvb.u4[1] = pbB[c][1];
          pvb.u4[2] = pbB[c][2]; pvb.u4[3] = pbB[c][3];
          acc[2 * pr][dt] = __builtin_amdgcn_mfma_f32_16x16x32_bf16(va, pva.v, acc[2 * pr][dt], 0, 0, 0);
          acc[2 * pr + 1][dt] = __builtin_amdgcn_mfma_f32_16x16x32_bf16(va, pvb.v, acc[2 * pr + 1][dt], 0, 0, 0);
        }
      }
    }
    __syncthreads();               // everyone done reading kvbuf[ch&1]
    if (ch < 7) {                  // write staged regs into the other buffer
      uint4* d4 = (uint4*)kvbuf[(ch & 1) ^ 1];
      #pragma unroll
      for (int i = 0; i < 4; ++i) d4[i * 256 + tid] = st[i];
    }
  }
#undef SOFTMAX_PACK

  // epilogue: reduce l across the 4 lane-groups, then write O^T
  #pragma unroll
  for (int s = 0; s < 4; ++s) {
    float lsum = l[s];
    lsum += __shfl_xor(lsum, 16, 64);
    lsum += __shfl_xor(lsum, 32, 64);
    const float inv = 1.f / lsum;
    const int hwq = (wy * 16 + wv * 4 + s) * 128 + wx * 16 + qi;
    #pragma unroll
    for (int dt = 0; dt < 2; ++dt)
      #pragma unroll
      for (int t = 0; t < 4; ++t) {
        const int d = dt * 16 + 4 * g + t;
        attnch[(size_t)(b * 128 + h * 32 + d) * P + hwq] = acc[s][dt][t] * inv;
      }
  }
}

// ---------------------------------------------------------------------------
// LayerNorm over 128 channels per pixel. 256 blocks x 256 thr (4 ch-groups)
// ---------------------------------------------------------------------------
__global__ __launch_bounds__(256) void k_ln(
    const float* __restrict__ in, const float* __restrict__ gg,
    const float* __restrict__ bta, float* __restrict__ out)
{
  const int l = threadIdx.x & 63;
  const int grp = threadIdx.x >> 6;
  const int p = blockIdx.x * 64 + l;
  __shared__ float s1[4][64], s2[4][64];
  float vals[32];
  float a = 0.f, b2 = 0.f;
  #pragma unroll
  for (int i = 0; i < 32; ++i) {
    float v = in[(size_t)(grp * 32 + i) * P + p];
    vals[i] = v; a += v; b2 += v * v;
  }
  s1[grp][l] = a; s2[grp][l] = b2;
  __syncthreads();
  const float sum = s1[0][l] + s1[1][l] + s1[2][l] + s1[3][l];
  const float sq  = s2[0][l] + s2[1][l] + s2[2][l] + s2[3][l];
  const float mu = sum * (1.f / 128.f);
  const float var = sq * (1.f / 128.f) - mu * mu;
  const float rs = rsqrtf(var + 1e-5f);
  #pragma unroll
  for (int i = 0; i < 32; ++i) {
    const int c = grp * 32 + i;
    out[(size_t)c * P + p] = (vals[i] - mu) * rs * gg[c] + bta[c];
  }
}

// ---------------------------------------------------------------------------
extern "C" void kernel_launch(void* const* d_in, const int* in_sizes, int n_in,
                              void* d_out, int out_size, void* d_ws, size_t ws_size,
                              hipStream_t stream)
{
  (void)in_sizes; (void)n_in; (void)out_size;
  const float* x      = (const float*)d_in[0];
  const float* qkv2_w = (const float*)d_in[1];
  const float* dw3_w  = (const float*)d_in[2];
  const float* pw3_w  = (const float*)d_in[3];
  const float* dw5_w  = (const float*)d_in[4];
  const float* pw5_w  = (const float*)d_in[5];
  const float* mlp_w  = (const float*)d_in[6];
  const float* mlp_b  = (const float*)d_in[7];
  const float* proj_w = (const float*)d_in[8];
  const float* ln_g   = (const float*)d_in[9];
  const float* ln_b   = (const float*)d_in[10];

  float* ws = (float*)d_ws;
  const size_t CH = (size_t)384 * P;
  // region liveness:
  //  ws+0   : qkv (fp32)            -> projo (after repack)
  //  ws+CH  : dwt (dw tmp)          -> qimg (bf16, after pw5)
  //  ws+2CH : y3                    -> attnch (after repack)
  //  ws+3CH : y5
  //  ws+4CH : kvimg (bf16, 25.2MB)  -> cat (after attn)
  //  ws+5CH : qwin | kwin | ridx
  float* qkv    = ws;
  float* dwt    = ws + CH;
  float* y3     = ws + 2 * CH;
  float* y5     = ws + 3 * CH;
  float* cat    = ws + 4 * CH;
  float* qwin   = ws + 5 * CH;
  float* kwin   = qwin + 3 * 64 * 128;
  int*   ridx   = (int*)(kwin + 3 * 64 * 128);
  unsigned int* kvimg = (unsigned int*)cat;
  unsigned int* qimg  = (unsigned int*)dwt;
  float* attnch = y3;
  float* projo  = qkv;
  (void)ws_size;

  k_conv1x1<<<dim3(128, 6), 256, 0, stream>>>(x, qkv2_w, nullptr, qkv, 128);
  k_dw<3><<<dim3(64, 384), 256, 0, stream>>>(qkv, dw3_w, dwt);
  k_pw<<<dim3(64, 12), 256, 0, stream>>>(dwt, pw3_w, y3);
  k_dw<5><<<dim3(64, 384), 256, 0, stream>>>(qkv, dw5_w, dwt);
  k_pw<<<dim3(64, 12), 256, 0, stream>>>(dwt, pw5_w, y5);
  k_winmax<<<dim3(64, 3), 256, 0, stream>>>(qkv, y3, y5, qwin, kwin);
  k_topk<<<dim3(3), 256, 0, stream>>>(qwin, kwin, ridx);
  k_repack<<<dim3(64, 4, 3), 256, 0, stream>>>(qkv, y3, y5, kvimg, qimg);
  k_attn_mfma<<<dim3(64, 4, 3), 256, 0, stream>>>(kvimg, qimg, ridx, attnch);
  for (int b = 0; b < 3; ++b)
    k_conv1x1<<<dim3(128, 2), 256, 0, stream>>>(attnch + (size_t)b * 128 * P,
                                                mlp_w, mlp_b,
                                                cat + (size_t)b * 128 * P, 128);
  k_conv1x1<<<dim3(128, 2), 256, 0, stream>>>(cat, proj_w, nullptr, projo, 384);
  k_ln<<<dim3(256), 256, 0, stream>>>(projo, ln_g, ln_b, (float*)d_out);
}

// Round 6
// 392.166 us; speedup vs baseline: 1.7956x; 1.3093x over previous
//
#include <hip/hip_runtime.h>
#include <math.h>

#define P 16384               // 128*128 pixels
#define SCALEF 0.08838834764831845f             // 128^-0.5
#define QSCALE 0.12752075616290145f             // SCALEF * log2(e)

typedef short bf16x8 __attribute__((ext_vector_type(8)));
typedef float f32x4 __attribute__((ext_vector_type(4)));

__device__ __forceinline__ unsigned short f2bf(float x) {
  union { float f; unsigned int u; } v; v.f = x;
  unsigned int r = v.u + 0x7fffu + ((v.u >> 16) & 1u);  // RNE
  return (unsigned short)(r >> 16);
}
__device__ __forceinline__ unsigned int packbf(float a, float b) {
  return (unsigned int)f2bf(a) | ((unsigned int)f2bf(b) << 16);
}
// pack two f32 -> bf16 pair (round-half-up) via v_perm: 3 VALU
__device__ __forceinline__ unsigned int pr2(float a, float b) {
  union { float f; unsigned int u; } ua, ub; ua.f = a; ub.f = b;
  return __builtin_amdgcn_perm(ub.u + 0x8000u, ua.u + 0x8000u, 0x07060302u);
}

// ---------------------------------------------------------------------------
// Split-bf16 MFMA GEMM for 1x1 conv: out[oc][p] = sum_ic w[oc][ic]*in[ic][p].
// NS=2: x=H+L, 3 terms (err ~2^-16). NS=3: x=H+M+L, 6 terms (err ~2^-24,
// fp32-equivalent — required for qkv which feeds discrete top-k).
// Block: 64 oc x 256 px, 4 waves; wave handles 4 px-tiles x 4 oc-tiles.
// Standard m89 fragment layout; kS4-style XOR swizzle (attention-validated).
// ---------------------------------------------------------------------------
template<int NS>
__global__ __launch_bounds__(256) void k_conv_mfma(
    const float* __restrict__ in, const float* __restrict__ w,
    const float* __restrict__ bias, float* __restrict__ out,
    const int IC, const int in_zstr, const int out_zstr)
{
  const int p0  = blockIdx.x * 256;
  const int oc0 = blockIdx.y * 64;
  in  += (size_t)blockIdx.z * (size_t)in_zstr;
  out += (size_t)blockIdx.z * (size_t)out_zstr;
  const int tid = threadIdx.x;
  const int wv = tid >> 6;
  const int lane = tid & 63;
  const int qi = lane & 15, g = lane >> 4;

  __shared__ __align__(16) unsigned int bS[NS][256 * 16];
  __shared__ __align__(16) unsigned int aS[NS][64 * 16];

  const f32x4 fz = {0.f, 0.f, 0.f, 0.f};
  f32x4 acc[4][4];
  #pragma unroll
  for (int j = 0; j < 4; ++j)
    #pragma unroll
    for (int o = 0; o < 4; ++o) acc[j][o] = fz;

  for (int k0 = 0; k0 < IC; k0 += 32) {
    __syncthreads();
    // ---- stage B: thread = k-pair (tid>>4), 16 px starting (tid&15)*16 ----
    {
      const int kB = tid >> 4;
      const int pB = (tid & 15) * 16;
      const float* r0 = in + (size_t)(k0 + 2 * kB) * P + p0 + pB;
      #pragma unroll
      for (int half = 0; half < 2; ++half) {
        float x0[8], x1[8];
        #pragma unroll
        for (int v = 0; v < 2; ++v) {
          float4 a = ((const float4*)r0)[half * 2 + v];
          float4 c = ((const float4*)(r0 + P))[half * 2 + v];
          x0[4*v] = a.x; x0[4*v+1] = a.y; x0[4*v+2] = a.z; x0[4*v+3] = a.w;
          x1[4*v] = c.x; x1[4*v+1] = c.y; x1[4*v+2] = c.z; x1[4*v+3] = c.w;
        }
        #pragma unroll
        for (int ii = 0; ii < 8; ++ii) {
          const int i8 = (ii + tid) & 7;           // bank rotation
          const int i = half * 8 + i8;
          const unsigned idx = (unsigned)((pB + i) * 16 + (kB ^ ((i & 3) << 2)));
          const unsigned u0 = __float_as_uint(x0[i8]);
          const unsigned u1 = __float_as_uint(x1[i8]);
          bS[0][idx] = __builtin_amdgcn_perm(u1, u0, 0x07060302u);
          const float r0f = x0[i8] - __uint_as_float(u0 & 0xffff0000u);
          const float r1f = x1[i8] - __uint_as_float(u1 & 0xffff0000u);
          if (NS == 2) {
            bS[1][idx] = pr2(r0f, r1f);
          } else {
            const unsigned m0 = __float_as_uint(r0f);
            const unsigned m1 = __float_as_uint(r1f);
            bS[1][idx] = __builtin_amdgcn_perm(m1, m0, 0x07060302u);
            const float s0 = r0f - __uint_as_float(m0 & 0xffff0000u);
            const float s1 = r1f - __uint_as_float(m1 & 0xffff0000u);
            bS[NS - 1][idx] = pr2(s0, s1);
          }
        }
      }
    }
    // ---- stage A: thread = oc row tid>>2, k span (tid&3)*8 ----
    {
      const int oA = tid >> 2;
      const int kA = (tid & 3) * 8;
      const float* rw = w + (size_t)(oc0 + oA) * IC + k0 + kA;
      float4 wa = ((const float4*)rw)[0];
      float4 wb = ((const float4*)rw)[1];
      float y[8] = {wa.x, wa.y, wa.z, wa.w, wb.x, wb.y, wb.z, wb.w};
      #pragma unroll
      for (int i = 0; i < 4; ++i) {
        const int dd = (kA >> 1) + i;
        const unsigned idx = (unsigned)(oA * 16 + (dd ^ ((oA & 3) << 2)));
        const unsigned u0 = __float_as_uint(y[2*i]);
        const unsigned u1 = __float_as_uint(y[2*i+1]);
        aS[0][idx] = __builtin_amdgcn_perm(u1, u0, 0x07060302u);
        const float r0f = y[2*i]   - __uint_as_float(u0 & 0xffff0000u);
        const float r1f = y[2*i+1] - __uint_as_float(u1 & 0xffff0000u);
        if (NS == 2) {
          aS[1][idx] = pr2(r0f, r1f);
        } else {
          const unsigned m0 = __float_as_uint(r0f);
          const unsigned m1 = __float_as_uint(r1f);
          aS[1][idx] = __builtin_amdgcn_perm(m1, m0, 0x07060302u);
          const float s0 = r0f - __uint_as_float(m0 & 0xffff0000u);
          const float s1 = r1f - __uint_as_float(m1 & 0xffff0000u);
          aS[NS - 1][idx] = pr2(s0, s1);
        }
      }
    }
    __syncthreads();

    bf16x8 aF[4][NS];
    #pragma unroll
    for (int o = 0; o < 4; ++o) {
      const unsigned ab = (unsigned)((o * 16 + qi) * 16 + 4 * (g ^ (qi & 3)));
      #pragma unroll
      for (int s = 0; s < NS; ++s)
        aF[o][s] = *(const bf16x8*)&aS[s][ab];
    }
    #pragma unroll
    for (int j = 0; j < 4; ++j) {
      const unsigned bb = (unsigned)(((wv * 4 + j) * 16 + qi) * 16 + 4 * (g ^ (qi & 3)));
      const bf16x8 b0 = *(const bf16x8*)&bS[0][bb];
      const bf16x8 b1 = *(const bf16x8*)&bS[1][bb];
      if (NS == 2) {
        #pragma unroll
        for (int o = 0; o < 4; ++o) {
          acc[j][o] = __builtin_amdgcn_mfma_f32_16x16x32_bf16(aF[o][0], b0, acc[j][o], 0, 0, 0);
          acc[j][o] = __builtin_amdgcn_mfma_f32_16x16x32_bf16(aF[o][0], b1, acc[j][o], 0, 0, 0);
          acc[j][o] = __builtin_amdgcn_mfma_f32_16x16x32_bf16(aF[o][1], b0, acc[j][o], 0, 0, 0);
        }
      } else {
        const bf16x8 b2 = *(const bf16x8*)&bS[NS - 1][bb];
        #pragma unroll
        for (int o = 0; o < 4; ++o) {
          acc[j][o] = __builtin_amdgcn_mfma_f32_16x16x32_bf16(aF[o][0], b0, acc[j][o], 0, 0, 0);
          acc[j][o] = __builtin_amdgcn_mfma_f32_16x16x32_bf16(aF[o][0], b1, acc[j][o], 0, 0, 0);
          acc[j][o] = __builtin_amdgcn_mfma_f32_16x16x32_bf16(aF[o][1], b0, acc[j][o], 0, 0, 0);
          acc[j][o] = __builtin_amdgcn_mfma_f32_16x16x32_bf16(aF[o][1], b1, acc[j][o], 0, 0, 0);
          acc[j][o] = __builtin_amdgcn_mfma_f32_16x16x32_bf16(aF[o][0], b2, acc[j][o], 0, 0, 0);
          acc[j][o] = __builtin_amdgcn_mfma_f32_16x16x32_bf16(aF[o][NS - 1], b0, acc[j][o], 0, 0, 0);
        }
      }
    }
  }

  float bv[4][4];
  #pragma unroll
  for (int o = 0; o < 4; ++o)
    #pragma unroll
    for (int t = 0; t < 4; ++t)
      bv[o][t] = bias ? bias[oc0 + o * 16 + 4 * g + t] : 0.f;

  #pragma unroll
  for (int j = 0; j < 4; ++j) {
    const int px = p0 + (wv * 4 + j) * 16 + qi;
    #pragma unroll
    for (int o = 0; o < 4; ++o)
      #pragma unroll
      for (int t = 0; t < 4; ++t)
        out[(size_t)(oc0 + o * 16 + 4 * g + t) * P + px] = acc[j][o][t] + bv[o][t];
  }
}

// ---------------------------------------------------------------------------
// Depthwise KxK conv
// ---------------------------------------------------------------------------
template<int K>
__global__ __launch_bounds__(256) void k_dw(
    const float* __restrict__ in, const float* __restrict__ w,
    float* __restrict__ out)
{
  const int c = blockIdx.y;
  const int p = blockIdx.x * 256 + threadIdx.x;
  const int y = p >> 7, x = p & 127;
  const float* wp = &w[c * K * K];
  const float* ip = &in[c * P];
  float acc = 0.f;
  #pragma unroll
  for (int dy = 0; dy < K; ++dy) {
    int yy = y + dy - K / 2;
    if (yy < 0 || yy > 127) continue;
    #pragma unroll
    for (int dx = 0; dx < K; ++dx) {
      int xx = x + dx - K / 2;
      if (xx < 0 || xx > 127) continue;
      acc += wp[dy * K + dx] * ip[yy * 128 + xx];
    }
  }
  out[c * P + p] = acc;
}

// ---------------------------------------------------------------------------
// Grouped pointwise (12 groups of 32->32)
// ---------------------------------------------------------------------------
__global__ __launch_bounds__(256) void k_pw(
    const float* __restrict__ in, const float* __restrict__ w,
    float* __restrict__ out)
{
  const int g = blockIdx.y;
  const int p = blockIdx.x * 256 + threadIdx.x;
  __shared__ float wL[1024];
  for (int e = threadIdx.x; e < 1024; e += 256) wL[e] = w[g * 1024 + e];
  __syncthreads();
  float r[32];
  #pragma unroll
  for (int i = 0; i < 32; ++i) r[i] = in[(g * 32 + i) * P + p];
  #pragma unroll
  for (int o = 0; o < 32; ++o) {
    float acc = 0.f;
    #pragma unroll
    for (int i = 0; i < 32; ++i) acc += wL[o * 32 + i] * r[i];
    out[(g * 32 + o) * P + p] = acc;
  }
}

// ---------------------------------------------------------------------------
// Window max of q (ch 0..127) and k (ch 128..255)
// ---------------------------------------------------------------------------
__global__ __launch_bounds__(256) void k_winmax(
    const float* __restrict__ e0, const float* __restrict__ e1,
    const float* __restrict__ e2, float* __restrict__ qwin,
    float* __restrict__ kwin)
{
  const int b = blockIdx.y;
  const int wIdx = blockIdx.x;
  const float* e = (b == 0) ? e0 : ((b == 1) ? e1 : e2);
  const int c = threadIdx.x;
  const int wy = wIdx >> 3, wx = wIdx & 7;
  const float* base = &e[c * P + (wy * 16) * 128 + wx * 16];
  float m = -INFINITY;
  for (int iy = 0; iy < 16; ++iy) {
    const float4* row = (const float4*)&base[iy * 128];
    #pragma unroll
    for (int j = 0; j < 4; ++j) {
      float4 v = row[j];
      m = fmaxf(m, fmaxf(fmaxf(v.x, v.y), fmaxf(v.z, v.w)));
    }
  }
  if (c < 128) qwin[(b * 64 + wIdx) * 128 + c] = m;
  else         kwin[(b * 64 + wIdx) * 128 + (c - 128)] = m;
}

// ---------------------------------------------------------------------------
// Window logits (64x64) + top-4 (ties -> lowest index) — exact fp32
// ---------------------------------------------------------------------------
__global__ __launch_bounds__(256) void k_topk(
    const float* __restrict__ qwin, const float* __restrict__ kwin,
    int* __restrict__ ridx)
{
  const int b = blockIdx.x;
  const int i = threadIdx.x & 63, jq = threadIdx.x >> 6;
  __shared__ float lg[64][68];
  float4 qr[32];
  const float4* q4 = (const float4*)&qwin[(b * 64 + i) * 128];
  #pragma unroll
  for (int t = 0; t < 32; ++t) qr[t] = q4[t];
  for (int jj = 0; jj < 16; ++jj) {
    const int j = jq * 16 + jj;
    const float4* k4 = (const float4*)&kwin[(b * 64 + j) * 128];
    float acc = 0.f;
    #pragma unroll
    for (int t = 0; t < 32; ++t) {
      float4 kv = k4[t];
      acc += qr[t].x * kv.x + qr[t].y * kv.y + qr[t].z * kv.z + qr[t].w * kv.w;
    }
    lg[i][j] = acc * SCALEF;
  }
  __syncthreads();
  if (threadIdx.x < 64) {
    unsigned long long mask = 0ull;
    for (int r = 0; r < 4; ++r) {
      float best = -INFINITY; int bj = 0;
      for (int j = 0; j < 64; ++j) {
        if ((mask >> j) & 1ull) continue;
        float v = lg[i][j];
        if (v > best) { best = v; bj = j; }   // strict > keeps lowest index
      }
      mask |= (1ull << bj);
      ridx[(b * 64 + i) * 4 + r] = bj;
    }
  }
}

// ---------------------------------------------------------------------------
// Repack Q/K/V into bf16 images pre-laid-out in LDS byte order.
// XCD-swizzled block mapping (same as attn) for warm-L2 handoff.
// ---------------------------------------------------------------------------
__global__ __launch_bounds__(256) void k_repack(
    const float* __restrict__ e0, const float* __restrict__ e1,
    const float* __restrict__ e2, unsigned int* __restrict__ kvimg,
    unsigned int* __restrict__ qimg)
{
  const int fl = blockIdx.x + 64 * (blockIdx.y + 4 * blockIdx.z);
  const int nf = (fl & 7) * 96 + (fl >> 3);       // bijective: 768 = 8*96
  const int w = nf & 63, h = (nf >> 6) & 3, b = nf >> 8;
  const float* e = (b == 0) ? e0 : ((b == 1) ? e1 : e2);
  const int wy = w >> 3, wx = w & 7;
  const int jbase = wy * 16 * 128 + wx * 16;
  const int t = threadIdx.x;
  unsigned int* kwin_img = kvimg + (size_t)((b * 4 + h) * 64 + w) * 8192;
  unsigned int* qwin_img = qimg  + (size_t)((b * 4 + h) * 64 + w) * 4096;

  // K + Q: thread = pixel (key/query) 0..255, 16 u32 each
  {
    const int key = t;
    const int hw = jbase + (key >> 4) * 128 + (key & 15);
    const float* eK = e + (size_t)(128 + h * 32) * P + hw;
    const float* eQ = e + (size_t)(h * 32) * P + hw;
    const int half = key >> 7, kl = key & 127;
    unsigned int* kd = kwin_img + half * 4096 + kl * 16;
    unsigned int* qd = qwin_img + key * 16;
    #pragma unroll
    for (int dd = 0; dd < 16; ++dd) {
      float k0 = eK[(size_t)(2 * dd) * P], k1 = eK[(size_t)(2 * dd + 1) * P];
      kd[dd ^ ((kl & 3) << 2)] = packbf(k0, k1);
      float q0 = eQ[(size_t)(2 * dd) * P] * QSCALE;
      float q1 = eQ[(size_t)(2 * dd + 1) * P] * QSCALE;
      qd[dd] = packbf(q0, q1);
    }
  }
  // V^T: [d][key] row-XOR swizzled, u32 = key-pair; 16 u32 per thread
  {
    const int half = t >> 7, tt = t & 127;
    const int d = tt >> 2;
    const int kp0 = (tt & 3) * 16;
    const float* eV = e + (size_t)(256 + h * 32 + d) * P;
    unsigned int* vd = kwin_img + half * 4096 + 2048 + d * 64;
    #pragma unroll
    for (int i = 0; i < 16; ++i) {
      const int kp2 = kp0 + i;
      const int key = half * 128 + kp2 * 2;
      const int hw = jbase + (key >> 4) * 128 + (key & 15);
      float v0 = eV[hw], v1 = eV[hw + 1];
      vd[kp2 ^ ((d & 7) << 2)] = packbf(v0, v1);
    }
  }
}

// ---------------------------------------------------------------------------
// MFMA flash attention v4. 8 waves x 32 queries; XCD-swizzled blocks so each
// XCD's L2 holds its ~3MB kvimg working set. T14 reg staging, double-buffered
// LDS. Per-wave state halved vs v3 -> 16 waves/CU.
// ---------------------------------------------------------------------------
__global__ __launch_bounds__(512, 4) void k_attn_mfma(
    const unsigned int* __restrict__ kvimg, const unsigned int* __restrict__ qimg,
    const int* __restrict__ ridx, float* __restrict__ attnch)
{
  const int fl = blockIdx.x + 64 * (blockIdx.y + 4 * blockIdx.z);
  const int nf = (fl & 7) * 96 + (fl >> 3);       // bijective XCD swizzle
  const int w = nf & 63, h = (nf >> 6) & 3, b = nf >> 8;
  const int tid = threadIdx.x;
  const int wv = tid >> 6, lane = tid & 63;
  const int qi = lane & 15, g = lane >> 4;
  const int wy = w >> 3, wx = w & 7;

  __shared__ __align__(16) unsigned int kvbuf[2][4096];   // 2 x 16KB

  const unsigned int* kwin = kvimg + (size_t)((b * 4 + h) * 64) * 8192;
  const unsigned int* qwin = qimg + (size_t)((b * 4 + h) * 64 + w) * 4096;

  // Q fragments: lane (qi,g), tile s: Q[q=(wv*2+s)*16+qi][d=8g..8g+7]
  bf16x8 qv[2];
  #pragma unroll
  for (int s = 0; s < 2; ++s) {
    union { uint4 u; bf16x8 v; } tq;
    tq.u = *(const uint4*)(qwin + ((wv * 2 + s) * 16 + qi) * 16 + g * 4);
    qv[s] = tq.v;
  }
  const int4 jv = *(const int4*)(ridx + (b * 64 + w) * 4);
  const int ja[4] = {jv.x, jv.y, jv.z, jv.w};

  const f32x4 fz = {0.f, 0.f, 0.f, 0.f};
  float m[2], l[2];
  f32x4 acc[2][2];
  #pragma unroll
  for (int s = 0; s < 2; ++s) {
    m[s] = -3.0e38f; l[s] = 0.f; acc[s][0] = fz; acc[s][1] = fz;
  }

  // prologue: stage chunk 0 (regs -> LDS); 512 thr x 2 uint4 = 16KB
  uint4 st[2];
  {
    const uint4* s4 = (const uint4*)(kwin + (size_t)ja[0] * 8192);
    #pragma unroll
    for (int i = 0; i < 2; ++i) st[i] = s4[i * 512 + tid];
    uint4* d4 = (uint4*)kvbuf[0];
    #pragma unroll
    for (int i = 0; i < 2; ++i) d4[i * 512 + tid] = st[i];
  }

#define SOFTMAX_PACK(SC, S, PB) {                                           \
    float wmax = -3.0e38f;                                                  \
    _Pragma("unroll") for (int c = 0; c < 4; ++c)                           \
      _Pragma("unroll") for (int u = 0; u < 2; ++u)                         \
        _Pragma("unroll") for (int t2 = 0; t2 < 4; ++t2)                    \
          wmax = fmaxf(wmax, SC[c][u][t2]);                                 \
    wmax = fmaxf(wmax, __shfl_xor(wmax, 16, 64));                           \
    wmax = fmaxf(wmax, __shfl_xor(wmax, 32, 64));                           \
    const float mnew = fmaxf(m[S], wmax);                                   \
    const float corr = exp2f(m[S] - mnew);                                  \
    m[S] = mnew;                                                            \
    acc[S][0] *= corr; acc[S][1] *= corr;                                   \
    float psum = 0.f;                                                       \
    _Pragma("unroll") for (int c = 0; c < 4; ++c)                           \
      _Pragma("unroll") for (int u = 0; u < 2; ++u) {                       \
        const float p0 = exp2f(SC[c][u][0] - mnew);                         \
        const float p1 = exp2f(SC[c][u][1] - mnew);                         \
        const float p2 = exp2f(SC[c][u][2] - mnew);                         \
        const float p3 = exp2f(SC[c][u][3] - mnew);                         \
        psum += (p0 + p1) + (p2 + p3);                                      \
        PB[c][2 * u]     = pr2(p0, p1);                                     \
        PB[c][2 * u + 1] = pr2(p2, p3);                                     \
      }                                                                     \
    l[S] = l[S] * corr + psum;                                              \
  }

  for (int ch = 0; ch < 8; ++ch) {
    if (ch < 7) {
      const int nx = ch + 1;
      const uint4* s4 = (const uint4*)(kwin + (size_t)ja[nx >> 1] * 8192
                                       + (size_t)(nx & 1) * 4096);
      #pragma unroll
      for (int i = 0; i < 2; ++i) st[i] = s4[i * 512 + tid];
    }
    __syncthreads();

    const unsigned int* bc = kvbuf[ch & 1];
    const bf16x8* kp = (const bf16x8*)bc;
    const unsigned short* vsh = (const unsigned short*)(bc + 2048);

    f32x4 scA[4][2], scB[4][2];
    #pragma unroll
    for (int c = 0; c < 4; ++c) {
      #pragma unroll
      for (int u = 0; u < 2; ++u) {
        const int key = 32 * c + 8 * (qi >> 2) + 4 * u + (qi & 3);
        const bf16x8 ka = kp[key * 4 + (g ^ (qi & 3))];
        scA[c][u] = __builtin_amdgcn_mfma_f32_16x16x32_bf16(ka, qv[0], fz, 0, 0, 0);
        scB[c][u] = __builtin_amdgcn_mfma_f32_16x16x32_bf16(ka, qv[1], fz, 0, 0, 0);
      }
    }
    unsigned int pbA[4][4], pbB[4][4];
    SOFTMAX_PACK(scA, 0, pbA);
    SOFTMAX_PACK(scB, 1, pbB);
    #pragma unroll
    for (int c = 0; c < 4; ++c) {
      #pragma unroll
      for (int dt = 0; dt < 2; ++dt) {
        const int d0 = dt * 16 + qi;
        const bf16x8 va = *(const bf16x8*)&vsh[
            (unsigned)((d0 * 128 + 32 * c + 8 * g) ^ ((d0 & 7) << 3))];
        union { unsigned int u4[4]; bf16x8 v; } pva, pvb;
        pva.u4[0] = pbA[c][0]; pva.u4[1] = pbA[c][1];
        pva.u4[2] = pbA[c][2]; pva.u4[3] = pbA[c][3];
        pvb.u4[0] = pbB[c][0]; pvb.u4[1] = pbB[c][1];
        pvb.u4[2] = pbB[c][2]; pvb.u4[3] = pbB[c][3];
        acc[0][dt] = __builtin_amdgcn_mfma_f32_16x16x32_bf16(va, pva.v, acc[0][dt], 0, 0, 0);
        acc[1][dt] = __builtin_amdgcn_mfma_f32_16x16x32_bf16(va, pvb.v, acc[1][dt], 0, 0, 0);
      }
    }
    __syncthreads();
    if (ch < 7) {
      uint4* d4 = (uint4*)kvbuf[(ch & 1) ^ 1];
      #pragma unroll
      for (int i = 0; i < 2; ++i) d4[i * 512 + tid] = st[i];
    }
  }
#undef SOFTMAX_PACK

  // epilogue: lane (qi,g) holds O^T[d = dt*16+4g+t][q = (wv*2+s)*16+qi]
  #pragma unroll
  for (int s = 0; s < 2; ++s) {
    float lsum = l[s];
    lsum += __shfl_xor(lsum, 16, 64);
    lsum += __shfl_xor(lsum, 32, 64);
    const float inv = 1.f / lsum;
    const int hwq = (wy * 16 + wv * 2 + s) * 128 + wx * 16 + qi;
    #pragma unroll
    for (int dt = 0; dt < 2; ++dt)
      #pragma unroll
      for (int t = 0; t < 4; ++t) {
        const int d = dt * 16 + 4 * g + t;
        attnch[(size_t)(b * 128 + h * 32 + d) * P + hwq] = acc[s][dt][t] * inv;
      }
  }
}

// ---------------------------------------------------------------------------
// LayerNorm over 128 channels per pixel. 256 blocks x 256 thr (4 ch-groups)
// ---------------------------------------------------------------------------
__global__ __launch_bounds__(256) void k_ln(
    const float* __restrict__ in, const float* __restrict__ gg,
    const float* __restrict__ bta, float* __restrict__ out)
{
  const int l = threadIdx.x & 63;
  const int grp = threadIdx.x >> 6;
  const int p = blockIdx.x * 64 + l;
  __shared__ float s1[4][64], s2[4][64];
  float vals[32];
  float a = 0.f, b2 = 0.f;
  #pragma unroll
  for (int i = 0; i < 32; ++i) {
    float v = in[(size_t)(grp * 32 + i) * P + p];
    vals[i] = v; a += v; b2 += v * v;
  }
  s1[grp][l] = a; s2[grp][l] = b2;
  __syncthreads();
  const float sum = s1[0][l] + s1[1][l] + s1[2][l] + s1[3][l];
  const float sq  = s2[0][l] + s2[1][l] + s2[2][l] + s2[3][l];
  const float mu = sum * (1.f / 128.f);
  const float var = sq * (1.f / 128.f) - mu * mu;
  const float rs = rsqrtf(var + 1e-5f);
  #pragma unroll
  for (int i = 0; i < 32; ++i) {
    const int c = grp * 32 + i;
    out[(size_t)c * P + p] = (vals[i] - mu) * rs * gg[c] + bta[c];
  }
}

// ---------------------------------------------------------------------------
extern "C" void kernel_launch(void* const* d_in, const int* in_sizes, int n_in,
                              void* d_out, int out_size, void* d_ws, size_t ws_size,
                              hipStream_t stream)
{
  (void)in_sizes; (void)n_in; (void)out_size;
  const float* x      = (const float*)d_in[0];
  const float* qkv2_w = (const float*)d_in[1];
  const float* dw3_w  = (const float*)d_in[2];
  const float* pw3_w  = (const float*)d_in[3];
  const float* dw5_w  = (const float*)d_in[4];
  const float* pw5_w  = (const float*)d_in[5];
  const float* mlp_w  = (const float*)d_in[6];
  const float* mlp_b  = (const float*)d_in[7];
  const float* proj_w = (const float*)d_in[8];
  const float* ln_g   = (const float*)d_in[9];
  const float* ln_b   = (const float*)d_in[10];

  float* ws = (float*)d_ws;
  const size_t CH = (size_t)384 * P;
  float* qkv    = ws;
  float* dwt    = ws + CH;
  float* y3     = ws + 2 * CH;
  float* y5     = ws + 3 * CH;
  float* cat    = ws + 4 * CH;
  float* qwin   = ws + 5 * CH;
  float* kwin   = qwin + 3 * 64 * 128;
  int*   ridx   = (int*)(kwin + 3 * 64 * 128);
  unsigned int* kvimg = (unsigned int*)cat;
  unsigned int* qimg  = (unsigned int*)dwt;
  float* attnch = y3;
  float* projo  = qkv;
  (void)ws_size;

  // qkv conv: 3-way split (6 terms) -> fp32-equivalent, safe for top-k
  k_conv_mfma<3><<<dim3(64, 6, 1), 256, 0, stream>>>(x, qkv2_w, nullptr, qkv, 128, 0, 0);
  k_dw<3><<<dim3(64, 384), 256, 0, stream>>>(qkv, dw3_w, dwt);
  k_pw<<<dim3(64, 12), 256, 0, stream>>>(dwt, pw3_w, y3);
  k_dw<5><<<dim3(64, 384), 256, 0, stream>>>(qkv, dw5_w, dwt);
  k_pw<<<dim3(64, 12), 256, 0, stream>>>(dwt, pw5_w, y5);
  k_winmax<<<dim3(64, 3), 256, 0, stream>>>(qkv, y3, y5, qwin, kwin);
  k_topk<<<dim3(3), 256, 0, stream>>>(qwin, kwin, ridx);
  k_repack<<<dim3(64, 4, 3), 256, 0, stream>>>(qkv, y3, y5, kvimg, qimg);
  k_attn_mfma<<<dim3(64, 4, 3), 512, 0, stream>>>(kvimg, qimg, ridx, attnch);
  // mlp (all 3 branches batched) + proj: 2-way split (3 terms)
  k_conv_mfma<2><<<dim3(64, 2, 3), 256, 0, stream>>>(attnch, mlp_w, mlp_b, cat,
                                                     128, 128 * P, 128 * P);
  k_conv_mfma<2><<<dim3(64, 2, 1), 256, 0, stream>>>(cat, proj_w, nullptr, projo,
                                                     384, 0, 0);
  k_ln<<<dim3(256), 256, 0, stream>>>(projo, ln_g, ln_b, (float*)d_out);
}

// Round 7
// 342.947 us; speedup vs baseline: 2.0533x; 1.1435x over previous
//
#include <hip/hip_runtime.h>
#include <math.h>

#define P 16384               // 128*128 pixels
#define SCALEF 0.08838834764831845f             // 128^-0.5
#define QSCALE 0.12752075616290145f             // SCALEF * log2(e)

typedef short bf16x8 __attribute__((ext_vector_type(8)));
typedef float f32x4 __attribute__((ext_vector_type(4)));

__device__ __forceinline__ unsigned short f2bf(float x) {
  union { float f; unsigned int u; } v; v.f = x;
  unsigned int r = v.u + 0x7fffu + ((v.u >> 16) & 1u);  // RNE
  return (unsigned short)(r >> 16);
}
__device__ __forceinline__ unsigned int packbf(float a, float b) {
  return (unsigned int)f2bf(a) | ((unsigned int)f2bf(b) << 16);
}
// pack two f32 -> bf16 pair (round-half-up) via v_perm: 3 VALU
__device__ __forceinline__ unsigned int pr2(float a, float b) {
  union { float f; unsigned int u; } ua, ub; ua.f = a; ub.f = b;
  return __builtin_amdgcn_perm(ub.u + 0x8000u, ua.u + 0x8000u, 0x07060302u);
}
// pack two f32 -> bf16 pair in ONE VALU (RNE)
__device__ __forceinline__ unsigned int pk2(float a, float b) {
  unsigned int r;
  asm("v_cvt_pk_bf16_f32 %0, %1, %2" : "=v"(r) : "v"(a), "v"(b));
  return r;
}
#define EXP2F(x) __builtin_amdgcn_exp2f(x)

// ---------------------------------------------------------------------------
// Split-bf16 MFMA GEMM for 1x1 conv: out[oc][p] = sum_ic w[oc][ic]*in[ic][p].
// NS=2: x=H+L, 3 terms (err ~1e-5 rel). Block: 64 oc x 256 px, 4 waves.
// ---------------------------------------------------------------------------
template<int NS>
__global__ __launch_bounds__(256) void k_conv_mfma(
    const float* __restrict__ in, const float* __restrict__ w,
    const float* __restrict__ bias, float* __restrict__ out,
    const int IC, const int in_zstr, const int out_zstr)
{
  const int p0  = blockIdx.x * 256;
  const int oc0 = blockIdx.y * 64;
  in  += (size_t)blockIdx.z * (size_t)in_zstr;
  out += (size_t)blockIdx.z * (size_t)out_zstr;
  const int tid = threadIdx.x;
  const int wv = tid >> 6;
  const int lane = tid & 63;
  const int qi = lane & 15, g = lane >> 4;

  __shared__ __align__(16) unsigned int bS[NS][256 * 16];
  __shared__ __align__(16) unsigned int aS[NS][64 * 16];

  const f32x4 fz = {0.f, 0.f, 0.f, 0.f};
  f32x4 acc[4][4];
  #pragma unroll
  for (int j = 0; j < 4; ++j)
    #pragma unroll
    for (int o = 0; o < 4; ++o) acc[j][o] = fz;

  for (int k0 = 0; k0 < IC; k0 += 32) {
    __syncthreads();
    // ---- stage B: thread = k-pair (tid>>4), 16 px starting (tid&15)*16 ----
    {
      const int kB = tid >> 4;
      const int pB = (tid & 15) * 16;
      const float* r0 = in + (size_t)(k0 + 2 * kB) * P + p0 + pB;
      #pragma unroll
      for (int half = 0; half < 2; ++half) {
        float x0[8], x1[8];
        #pragma unroll
        for (int v = 0; v < 2; ++v) {
          float4 a = ((const float4*)r0)[half * 2 + v];
          float4 c = ((const float4*)(r0 + P))[half * 2 + v];
          x0[4*v] = a.x; x0[4*v+1] = a.y; x0[4*v+2] = a.z; x0[4*v+3] = a.w;
          x1[4*v] = c.x; x1[4*v+1] = c.y; x1[4*v+2] = c.z; x1[4*v+3] = c.w;
        }
        #pragma unroll
        for (int ii = 0; ii < 8; ++ii) {
          const int i8 = (ii + tid) & 7;           // bank rotation
          const int i = half * 8 + i8;
          const unsigned idx = (unsigned)((pB + i) * 16 + (kB ^ ((i & 3) << 2)));
          const unsigned u0 = __float_as_uint(x0[i8]);
          const unsigned u1 = __float_as_uint(x1[i8]);
          bS[0][idx] = __builtin_amdgcn_perm(u1, u0, 0x07060302u);
          const float r0f = x0[i8] - __uint_as_float(u0 & 0xffff0000u);
          const float r1f = x1[i8] - __uint_as_float(u1 & 0xffff0000u);
          if (NS == 2) {
            bS[1][idx] = pr2(r0f, r1f);
          } else {
            const unsigned m0 = __float_as_uint(r0f);
            const unsigned m1 = __float_as_uint(r1f);
            bS[1][idx] = __builtin_amdgcn_perm(m1, m0, 0x07060302u);
            const float s0 = r0f - __uint_as_float(m0 & 0xffff0000u);
            const float s1 = r1f - __uint_as_float(m1 & 0xffff0000u);
            bS[NS - 1][idx] = pr2(s0, s1);
          }
        }
      }
    }
    // ---- stage A: thread = oc row tid>>2, k span (tid&3)*8 ----
    {
      const int oA = tid >> 2;
      const int kA = (tid & 3) * 8;
      const float* rw = w + (size_t)(oc0 + oA) * IC + k0 + kA;
      float4 wa = ((const float4*)rw)[0];
      float4 wb = ((const float4*)rw)[1];
      float y[8] = {wa.x, wa.y, wa.z, wa.w, wb.x, wb.y, wb.z, wb.w};
      #pragma unroll
      for (int i = 0; i < 4; ++i) {
        const int dd = (kA >> 1) + i;
        const unsigned idx = (unsigned)(oA * 16 + (dd ^ ((oA & 3) << 2)));
        const unsigned u0 = __float_as_uint(y[2*i]);
        const unsigned u1 = __float_as_uint(y[2*i+1]);
        aS[0][idx] = __builtin_amdgcn_perm(u1, u0, 0x07060302u);
        const float r0f = y[2*i]   - __uint_as_float(u0 & 0xffff0000u);
        const float r1f = y[2*i+1] - __uint_as_float(u1 & 0xffff0000u);
        if (NS == 2) {
          aS[1][idx] = pr2(r0f, r1f);
        } else {
          const unsigned m0 = __float_as_uint(r0f);
          const unsigned m1 = __float_as_uint(r1f);
          aS[1][idx] = __builtin_amdgcn_perm(m1, m0, 0x07060302u);
          const float s0 = r0f - __uint_as_float(m0 & 0xffff0000u);
          const float s1 = r1f - __uint_as_float(m1 & 0xffff0000u);
          aS[NS - 1][idx] = pr2(s0, s1);
        }
      }
    }
    __syncthreads();

    bf16x8 aF[4][NS];
    #pragma unroll
    for (int o = 0; o < 4; ++o) {
      const unsigned ab = (unsigned)((o * 16 + qi) * 16 + 4 * (g ^ (qi & 3)));
      #pragma unroll
      for (int s = 0; s < NS; ++s)
        aF[o][s] = *(const bf16x8*)&aS[s][ab];
    }
    #pragma unroll
    for (int j = 0; j < 4; ++j) {
      const unsigned bb = (unsigned)(((wv * 4 + j) * 16 + qi) * 16 + 4 * (g ^ (qi & 3)));
      const bf16x8 b0 = *(const bf16x8*)&bS[0][bb];
      const bf16x8 b1 = *(const bf16x8*)&bS[1][bb];
      if (NS == 2) {
        #pragma unroll
        for (int o = 0; o < 4; ++o) {
          acc[j][o] = __builtin_amdgcn_mfma_f32_16x16x32_bf16(aF[o][0], b0, acc[j][o], 0, 0, 0);
          acc[j][o] = __builtin_amdgcn_mfma_f32_16x16x32_bf16(aF[o][0], b1, acc[j][o], 0, 0, 0);
          acc[j][o] = __builtin_amdgcn_mfma_f32_16x16x32_bf16(aF[o][1], b0, acc[j][o], 0, 0, 0);
        }
      } else {
        const bf16x8 b2 = *(const bf16x8*)&bS[NS - 1][bb];
        #pragma unroll
        for (int o = 0; o < 4; ++o) {
          acc[j][o] = __builtin_amdgcn_mfma_f32_16x16x32_bf16(aF[o][0], b0, acc[j][o], 0, 0, 0);
          acc[j][o] = __builtin_amdgcn_mfma_f32_16x16x32_bf16(aF[o][0], b1, acc[j][o], 0, 0, 0);
          acc[j][o] = __builtin_amdgcn_mfma_f32_16x16x32_bf16(aF[o][1], b0, acc[j][o], 0, 0, 0);
          acc[j][o] = __builtin_amdgcn_mfma_f32_16x16x32_bf16(aF[o][1], b1, acc[j][o], 0, 0, 0);
          acc[j][o] = __builtin_amdgcn_mfma_f32_16x16x32_bf16(aF[o][0], b2, acc[j][o], 0, 0, 0);
          acc[j][o] = __builtin_amdgcn_mfma_f32_16x16x32_bf16(aF[o][NS - 1], b0, acc[j][o], 0, 0, 0);
        }
      }
    }
  }

  float bv[4][4];
  #pragma unroll
  for (int o = 0; o < 4; ++o)
    #pragma unroll
    for (int t = 0; t < 4; ++t)
      bv[o][t] = bias ? bias[oc0 + o * 16 + 4 * g + t] : 0.f;

  #pragma unroll
  for (int j = 0; j < 4; ++j) {
    const int px = p0 + (wv * 4 + j) * 16 + qi;
    #pragma unroll
    for (int o = 0; o < 4; ++o)
      #pragma unroll
      for (int t = 0; t < 4; ++t)
        out[(size_t)(oc0 + o * 16 + 4 * g + t) * P + px] = acc[j][o][t] + bv[o][t];
  }
}

// ---------------------------------------------------------------------------
// Fold mlp into proj: Wc[o][b*128+i] = sum_j proj_w[o][b*128+j]*mlp_w[j][i]
// ---------------------------------------------------------------------------
__global__ __launch_bounds__(128) void k_foldw(
    const float* __restrict__ proj_w, const float* __restrict__ mlp_w,
    float* __restrict__ Wc)
{
  const int o = blockIdx.x;      // 0..127
  const int b = blockIdx.y;      // 0..2
  const int i = threadIdx.x;     // 0..127
  const float* pw = proj_w + o * 384 + b * 128;
  float acc = 0.f;
  for (int j = 0; j < 128; ++j)
    acc += pw[j] * mlp_w[j * 128 + i];
  Wc[o * 384 + b * 128 + i] = acc;
}
__global__ __launch_bounds__(128) void k_foldb(
    const float* __restrict__ proj_w, const float* __restrict__ mlp_b,
    float* __restrict__ bc)
{
  const int o = threadIdx.x;
  float acc = 0.f;
  for (int c = 0; c < 384; ++c) acc += proj_w[o * 384 + c] * mlp_b[c & 127];
  bc[o] = acc;
}

// ---------------------------------------------------------------------------
// Depthwise KxK conv
// ---------------------------------------------------------------------------
template<int K>
__global__ __launch_bounds__(256) void k_dw(
    const float* __restrict__ in, const float* __restrict__ w,
    float* __restrict__ out)
{
  const int c = blockIdx.y;
  const int p = blockIdx.x * 256 + threadIdx.x;
  const int y = p >> 7, x = p & 127;
  const float* wp = &w[c * K * K];
  const float* ip = &in[c * P];
  float acc = 0.f;
  #pragma unroll
  for (int dy = 0; dy < K; ++dy) {
    int yy = y + dy - K / 2;
    if (yy < 0 || yy > 127) continue;
    #pragma unroll
    for (int dx = 0; dx < K; ++dx) {
      int xx = x + dx - K / 2;
      if (xx < 0 || xx > 127) continue;
      acc += wp[dy * K + dx] * ip[yy * 128 + xx];
    }
  }
  out[c * P + p] = acc;
}

// ---------------------------------------------------------------------------
// Grouped pointwise (12 groups of 32->32)
// ---------------------------------------------------------------------------
__global__ __launch_bounds__(256) void k_pw(
    const float* __restrict__ in, const float* __restrict__ w,
    float* __restrict__ out)
{
  const int g = blockIdx.y;
  const int p = blockIdx.x * 256 + threadIdx.x;
  __shared__ float wL[1024];
  for (int e = threadIdx.x; e < 1024; e += 256) wL[e] = w[g * 1024 + e];
  __syncthreads();
  float r[32];
  #pragma unroll
  for (int i = 0; i < 32; ++i) r[i] = in[(g * 32 + i) * P + p];
  #pragma unroll
  for (int o = 0; o < 32; ++o) {
    float acc = 0.f;
    #pragma unroll
    for (int i = 0; i < 32; ++i) acc += wL[o * 32 + i] * r[i];
    out[(g * 32 + o) * P + p] = acc;
  }
}

// ---------------------------------------------------------------------------
// Window max of q (ch 0..127) and k (ch 128..255)
// ---------------------------------------------------------------------------
__global__ __launch_bounds__(256) void k_winmax(
    const float* __restrict__ e0, const float* __restrict__ e1,
    const float* __restrict__ e2, float* __restrict__ qwin,
    float* __restrict__ kwin)
{
  const int b = blockIdx.y;
  const int wIdx = blockIdx.x;
  const float* e = (b == 0) ? e0 : ((b == 1) ? e1 : e2);
  const int c = threadIdx.x;
  const int wy = wIdx >> 3, wx = wIdx & 7;
  const float* base = &e[c * P + (wy * 16) * 128 + wx * 16];
  float m = -INFINITY;
  for (int iy = 0; iy < 16; ++iy) {
    const float4* row = (const float4*)&base[iy * 128];
    #pragma unroll
    for (int j = 0; j < 4; ++j) {
      float4 v = row[j];
      m = fmaxf(m, fmaxf(fmaxf(v.x, v.y), fmaxf(v.z, v.w)));
    }
  }
  if (c < 128) qwin[(b * 64 + wIdx) * 128 + c] = m;
  else         kwin[(b * 64 + wIdx) * 128 + (c - 128)] = m;
}

// ---------------------------------------------------------------------------
// Window logits (64x64) + top-4 (ties -> lowest index) — exact fp32
// ---------------------------------------------------------------------------
__global__ __launch_bounds__(256) void k_topk(
    const float* __restrict__ qwin, const float* __restrict__ kwin,
    int* __restrict__ ridx)
{
  const int b = blockIdx.x;
  const int i = threadIdx.x & 63, jq = threadIdx.x >> 6;
  __shared__ float lg[64][68];
  float4 qr[32];
  const float4* q4 = (const float4*)&qwin[(b * 64 + i) * 128];
  #pragma unroll
  for (int t = 0; t < 32; ++t) qr[t] = q4[t];
  for (int jj = 0; jj < 16; ++jj) {
    const int j = jq * 16 + jj;
    const float4* k4 = (const float4*)&kwin[(b * 64 + j) * 128];
    float acc = 0.f;
    #pragma unroll
    for (int t = 0; t < 32; ++t) {
      float4 kv = k4[t];
      acc += qr[t].x * kv.x + qr[t].y * kv.y + qr[t].z * kv.z + qr[t].w * kv.w;
    }
    lg[i][j] = acc * SCALEF;
  }
  __syncthreads();
  if (threadIdx.x < 64) {
    unsigned long long mask = 0ull;
    for (int r = 0; r < 4; ++r) {
      float best = -INFINITY; int bj = 0;
      for (int j = 0; j < 64; ++j) {
        if ((mask >> j) & 1ull) continue;
        float v = lg[i][j];
        if (v > best) { best = v; bj = j; }   // strict > keeps lowest index
      }
      mask |= (1ull << bj);
      ridx[(b * 64 + i) * 4 + r] = bj;
    }
  }
}

// ---------------------------------------------------------------------------
// Repack Q/K/V into bf16 images pre-laid-out in LDS byte order.
// ---------------------------------------------------------------------------
__global__ __launch_bounds__(256) void k_repack(
    const float* __restrict__ e0, const float* __restrict__ e1,
    const float* __restrict__ e2, unsigned int* __restrict__ kvimg,
    unsigned int* __restrict__ qimg)
{
  const int fl = blockIdx.x + 64 * (blockIdx.y + 4 * blockIdx.z);
  const int nf = (fl & 7) * 96 + (fl >> 3);       // bijective: 768 = 8*96
  const int w = nf & 63, h = (nf >> 6) & 3, b = nf >> 8;
  const float* e = (b == 0) ? e0 : ((b == 1) ? e1 : e2);
  const int wy = w >> 3, wx = w & 7;
  const int jbase = wy * 16 * 128 + wx * 16;
  const int t = threadIdx.x;
  unsigned int* kwin_img = kvimg + (size_t)((b * 4 + h) * 64 + w) * 8192;
  unsigned int* qwin_img = qimg  + (size_t)((b * 4 + h) * 64 + w) * 4096;

  // K + Q: thread = pixel (key/query) 0..255, 16 u32 each
  {
    const int key = t;
    const int hw = jbase + (key >> 4) * 128 + (key & 15);
    const float* eK = e + (size_t)(128 + h * 32) * P + hw;
    const float* eQ = e + (size_t)(h * 32) * P + hw;
    const int half = key >> 7, kl = key & 127;
    unsigned int* kd = kwin_img + half * 4096 + kl * 16;
    unsigned int* qd = qwin_img + key * 16;
    #pragma unroll
    for (int dd = 0; dd < 16; ++dd) {
      float k0 = eK[(size_t)(2 * dd) * P], k1 = eK[(size_t)(2 * dd + 1) * P];
      kd[dd ^ ((kl & 3) << 2)] = packbf(k0, k1);
      float q0 = eQ[(size_t)(2 * dd) * P] * QSCALE;
      float q1 = eQ[(size_t)(2 * dd + 1) * P] * QSCALE;
      qd[dd] = packbf(q0, q1);
    }
  }
  // V^T: [d][key] row-XOR swizzled, u32 = key-pair; 16 u32 per thread
  {
    const int half = t >> 7, tt = t & 127;
    const int d = tt >> 2;
    const int kp0 = (tt & 3) * 16;
    const float* eV = e + (size_t)(256 + h * 32 + d) * P;
    unsigned int* vd = kwin_img + half * 4096 + 2048 + d * 64;
    #pragma unroll
    for (int i = 0; i < 16; ++i) {
      const int kp2 = kp0 + i;
      const int key = half * 128 + kp2 * 2;
      const int hw = jbase + (key >> 4) * 128 + (key & 15);
      float v0 = eV[hw], v1 = eV[hw + 1];
      vd[kp2 ^ ((d & 7) << 2)] = packbf(v0, v1);
    }
  }
}

// ---------------------------------------------------------------------------
// MFMA flash attention v5. 8 waves x 32 queries; XCD-swizzled. Single-barrier
// double-buffer (write(t+1) and read(t) touch different parities; one barrier
// of separation suffices). Softmax: raw v_exp_f32 + v_cvt_pk_bf16_f32.
// ---------------------------------------------------------------------------
__global__ __launch_bounds__(512, 4) void k_attn_mfma(
    const unsigned int* __restrict__ kvimg, const unsigned int* __restrict__ qimg,
    const int* __restrict__ ridx, float* __restrict__ attnch)
{
  const int fl = blockIdx.x + 64 * (blockIdx.y + 4 * blockIdx.z);
  const int nf = (fl & 7) * 96 + (fl >> 3);       // bijective XCD swizzle
  const int w = nf & 63, h = (nf >> 6) & 3, b = nf >> 8;
  const int tid = threadIdx.x;
  const int wv = tid >> 6, lane = tid & 63;
  const int qi = lane & 15, g = lane >> 4;
  const int wy = w >> 3, wx = w & 7;

  __shared__ __align__(16) unsigned int kvbuf[2][4096];   // 2 x 16KB

  const unsigned int* kwin = kvimg + (size_t)((b * 4 + h) * 64) * 8192;
  const unsigned int* qwin = qimg + (size_t)((b * 4 + h) * 64 + w) * 4096;

  // Q fragments: lane (qi,g), tile s: Q[q=(wv*2+s)*16+qi][d=8g..8g+7]
  bf16x8 qv[2];
  #pragma unroll
  for (int s = 0; s < 2; ++s) {
    union { uint4 u; bf16x8 v; } tq;
    tq.u = *(const uint4*)(qwin + ((wv * 2 + s) * 16 + qi) * 16 + g * 4);
    qv[s] = tq.v;
  }
  const int4 jv = *(const int4*)(ridx + (b * 64 + w) * 4);
  const int ja[4] = {jv.x, jv.y, jv.z, jv.w};

  const f32x4 fz = {0.f, 0.f, 0.f, 0.f};
  float m[2], l[2];
  f32x4 acc[2][2];
  #pragma unroll
  for (int s = 0; s < 2; ++s) {
    m[s] = -3.0e38f; l[s] = 0.f; acc[s][0] = fz; acc[s][1] = fz;
  }

  // prologue: load chunk 0 into regs
  uint4 st0, st1;
  {
    const uint4* s4 = (const uint4*)(kwin + (size_t)ja[0] * 8192);
    st0 = s4[tid]; st1 = s4[512 + tid];
  }

#define SOFTMAX_PACK(SC, S, PB) {                                           \
    float wmax = -3.0e38f;                                                  \
    _Pragma("unroll") for (int c = 0; c < 4; ++c)                           \
      _Pragma("unroll") for (int u = 0; u < 2; ++u)                         \
        _Pragma("unroll") for (int t2 = 0; t2 < 4; ++t2)                    \
          wmax = fmaxf(wmax, SC[c][u][t2]);                                 \
    wmax = fmaxf(wmax, __shfl_xor(wmax, 16, 64));                           \
    wmax = fmaxf(wmax, __shfl_xor(wmax, 32, 64));                           \
    const float mnew = fmaxf(m[S], wmax);                                   \
    const float corr = EXP2F(m[S] - mnew);                                  \
    m[S] = mnew;                                                            \
    acc[S][0] *= corr; acc[S][1] *= corr;                                   \
    float psum = 0.f;                                                       \
    _Pragma("unroll") for (int c = 0; c < 4; ++c)                           \
      _Pragma("unroll") for (int u = 0; u < 2; ++u) {                       \
        const float p0 = EXP2F(SC[c][u][0] - mnew);                         \
        const float p1 = EXP2F(SC[c][u][1] - mnew);                         \
        const float p2 = EXP2F(SC[c][u][2] - mnew);                         \
        const float p3 = EXP2F(SC[c][u][3] - mnew);                         \
        psum += (p0 + p1) + (p2 + p3);                                      \
        PB[c][2 * u]     = pk2(p0, p1);                                     \
        PB[c][2 * u + 1] = pk2(p2, p3);                                     \
      }                                                                     \
    l[S] = l[S] * corr + psum;                                              \
  }

  for (int ch = 0; ch < 8; ++ch) {
    // write chunk ch (staged in regs) into buf[ch&1]
    {
      uint4* d4 = (uint4*)kvbuf[ch & 1];
      d4[tid] = st0; d4[512 + tid] = st1;
    }
    // issue chunk ch+1 loads — latency hides under this chunk's compute
    if (ch < 7) {
      const int nx = ch + 1;
      const uint4* s4 = (const uint4*)(kwin + (size_t)ja[nx >> 1] * 8192
                                       + (size_t)(nx & 1) * 4096);
      st0 = s4[tid]; st1 = s4[512 + tid];
    }
    __syncthreads();   // chunk ch visible; prior chunk's readers are done

    const unsigned int* bc = kvbuf[ch & 1];
    const bf16x8* kp = (const bf16x8*)bc;
    const unsigned short* vsh = (const unsigned short*)(bc + 2048);

    f32x4 scA[4][2], scB[4][2];
    #pragma unroll
    for (int c = 0; c < 4; ++c) {
      #pragma unroll
      for (int u = 0; u < 2; ++u) {
        const int key = 32 * c + 8 * (qi >> 2) + 4 * u + (qi & 3);
        const bf16x8 ka = kp[key * 4 + (g ^ (qi & 3))];
        scA[c][u] = __builtin_amdgcn_mfma_f32_16x16x32_bf16(ka, qv[0], fz, 0, 0, 0);
        scB[c][u] = __builtin_amdgcn_mfma_f32_16x16x32_bf16(ka, qv[1], fz, 0, 0, 0);
      }
    }
    unsigned int pbA[4][4], pbB[4][4];
    SOFTMAX_PACK(scA, 0, pbA);
    SOFTMAX_PACK(scB, 1, pbB);
    #pragma unroll
    for (int c = 0; c < 4; ++c) {
      #pragma unroll
      for (int dt = 0; dt < 2; ++dt) {
        const int d0 = dt * 16 + qi;
        const bf16x8 va = *(const bf16x8*)&vsh[
            (unsigned)((d0 * 128 + 32 * c + 8 * g) ^ ((d0 & 7) << 3))];
        union { unsigned int u4[4]; bf16x8 v; } pva, pvb;
        pva.u4[0] = pbA[c][0]; pva.u4[1] = pbA[c][1];
        pva.u4[2] = pbA[c][2]; pva.u4[3] = pbA[c][3];
        pvb.u4[0] = pbB[c][0]; pvb.u4[1] = pbB[c][1];
        pvb.u4[2] = pbB[c][2]; pvb.u4[3] = pbB[c][3];
        acc[0][dt] = __builtin_amdgcn_mfma_f32_16x16x32_bf16(va, pva.v, acc[0][dt], 0, 0, 0);
        acc[1][dt] = __builtin_amdgcn_mfma_f32_16x16x32_bf16(va, pvb.v, acc[1][dt], 0, 0, 0);
      }
    }
  }
#undef SOFTMAX_PACK

  // epilogue: lane (qi,g) holds O^T[d = dt*16+4g+t][q = (wv*2+s)*16+qi]
  #pragma unroll
  for (int s = 0; s < 2; ++s) {
    float lsum = l[s];
    lsum += __shfl_xor(lsum, 16, 64);
    lsum += __shfl_xor(lsum, 32, 64);
    const float inv = 1.f / lsum;
    const int hwq = (wy * 16 + wv * 2 + s) * 128 + wx * 16 + qi;
    #pragma unroll
    for (int dt = 0; dt < 2; ++dt)
      #pragma unroll
      for (int t = 0; t < 4; ++t) {
        const int d = dt * 16 + 4 * g + t;
        attnch[(size_t)(b * 128 + h * 32 + d) * P + hwq] = acc[s][dt][t] * inv;
      }
  }
}

// ---------------------------------------------------------------------------
// LayerNorm over 128 channels per pixel. 256 blocks x 256 thr (4 ch-groups)
// ---------------------------------------------------------------------------
__global__ __launch_bounds__(256) void k_ln(
    const float* __restrict__ in, const float* __restrict__ gg,
    const float* __restrict__ bta, float* __restrict__ out)
{
  const int l = threadIdx.x & 63;
  const int grp = threadIdx.x >> 6;
  const int p = blockIdx.x * 64 + l;
  __shared__ float s1[4][64], s2[4][64];
  float vals[32];
  float a = 0.f, b2 = 0.f;
  #pragma unroll
  for (int i = 0; i < 32; ++i) {
    float v = in[(size_t)(grp * 32 + i) * P + p];
    vals[i] = v; a += v; b2 += v * v;
  }
  s1[grp][l] = a; s2[grp][l] = b2;
  __syncthreads();
  const float sum = s1[0][l] + s1[1][l] + s1[2][l] + s1[3][l];
  const float sq  = s2[0][l] + s2[1][l] + s2[2][l] + s2[3][l];
  const float mu = sum * (1.f / 128.f);
  const float var = sq * (1.f / 128.f) - mu * mu;
  const float rs = rsqrtf(var + 1e-5f);
  #pragma unroll
  for (int i = 0; i < 32; ++i) {
    const int c = grp * 32 + i;
    out[(size_t)c * P + p] = (vals[i] - mu) * rs * gg[c] + bta[c];
  }
}

// ---------------------------------------------------------------------------
extern "C" void kernel_launch(void* const* d_in, const int* in_sizes, int n_in,
                              void* d_out, int out_size, void* d_ws, size_t ws_size,
                              hipStream_t stream)
{
  (void)in_sizes; (void)n_in; (void)out_size;
  const float* x      = (const float*)d_in[0];
  const float* qkv2_w = (const float*)d_in[1];
  const float* dw3_w  = (const float*)d_in[2];
  const float* pw3_w  = (const float*)d_in[3];
  const float* dw5_w  = (const float*)d_in[4];
  const float* pw5_w  = (const float*)d_in[5];
  const float* mlp_w  = (const float*)d_in[6];
  const float* mlp_b  = (const float*)d_in[7];
  const float* proj_w = (const float*)d_in[8];
  const float* ln_g   = (const float*)d_in[9];
  const float* ln_b   = (const float*)d_in[10];

  float* ws = (float*)d_ws;
  const size_t CH = (size_t)384 * P;
  // region liveness:
  //  ws+0   : qkv (fp32)            -> projo (after repack)
  //  ws+CH  : dwt (dw tmp)          -> qimg (bf16, after pw5)
  //  ws+2CH : y3                    -> attnch (after repack)
  //  ws+3CH : y5
  //  ws+4CH : kvimg (bf16, 25.2MB)
  //  ws+5CH : qwin | kwin | ridx | Wc | bc
  float* qkv    = ws;
  float* dwt    = ws + CH;
  float* y3     = ws + 2 * CH;
  float* y5     = ws + 3 * CH;
  float* qwin   = ws + 5 * CH;
  float* kwin   = qwin + 3 * 64 * 128;
  int*   ridx   = (int*)(kwin + 3 * 64 * 128);
  float* Wc     = (float*)(ridx + 768);
  float* bc     = Wc + 128 * 384;
  unsigned int* kvimg = (unsigned int*)(ws + 4 * CH);
  unsigned int* qimg  = (unsigned int*)dwt;
  float* attnch = y3;
  float* projo  = qkv;
  (void)ws_size;

  // fold mlp into proj (independent of main chain)
  k_foldw<<<dim3(128, 3), 128, 0, stream>>>(proj_w, mlp_w, Wc);
  k_foldb<<<1, 128, 0, stream>>>(proj_w, mlp_b, bc);

  k_conv_mfma<2><<<dim3(64, 6, 1), 256, 0, stream>>>(x, qkv2_w, nullptr, qkv, 128, 0, 0);
  k_dw<3><<<dim3(64, 384), 256, 0, stream>>>(qkv, dw3_w, dwt);
  k_pw<<<dim3(64, 12), 256, 0, stream>>>(dwt, pw3_w, y3);
  k_dw<5><<<dim3(64, 384), 256, 0, stream>>>(qkv, dw5_w, dwt);
  k_pw<<<dim3(64, 12), 256, 0, stream>>>(dwt, pw5_w, y5);
  k_winmax<<<dim3(64, 3), 256, 0, stream>>>(qkv, y3, y5, qwin, kwin);
  k_topk<<<dim3(3), 256, 0, stream>>>(qwin, kwin, ridx);
  k_repack<<<dim3(64, 4, 3), 256, 0, stream>>>(qkv, y3, y5, kvimg, qimg);
  k_attn_mfma<<<dim3(64, 4, 3), 512, 0, stream>>>(kvimg, qimg, ridx, attnch);
  // fused mlp+proj: one IC=384 GEMM on attnch
  k_conv_mfma<2><<<dim3(64, 2, 1), 256, 0, stream>>>(attnch, Wc, bc, projo, 384, 0, 0);
  k_ln<<<dim3(256), 256, 0, stream>>>(projo, ln_g, ln_b, (float*)d_out);
}

// Round 8
// 260.181 us; speedup vs baseline: 2.7065x; 1.3181x over previous
//
#include <hip/hip_runtime.h>
#include <math.h>

#define P 16384               // 128*128 pixels
#define SCALEF 0.08838834764831845f             // 128^-0.5
#define QSCALE 0.12752075616290145f             // SCALEF * log2(e)

typedef short bf16x8 __attribute__((ext_vector_type(8)));
typedef float f32x4 __attribute__((ext_vector_type(4)));

__device__ __forceinline__ unsigned short f2bf(float x) {
  union { float f; unsigned int u; } v; v.f = x;
  unsigned int r = v.u + 0x7fffu + ((v.u >> 16) & 1u);  // RNE
  return (unsigned short)(r >> 16);
}
__device__ __forceinline__ unsigned int packbf(float a, float b) {
  return (unsigned int)f2bf(a) | ((unsigned int)f2bf(b) << 16);
}
// pack two f32 -> bf16 pair (round-half-up) via v_perm: 3 VALU
__device__ __forceinline__ unsigned int pr2(float a, float b) {
  union { float f; unsigned int u; } ua, ub; ua.f = a; ub.f = b;
  return __builtin_amdgcn_perm(ub.u + 0x8000u, ua.u + 0x8000u, 0x07060302u);
}
// pack two f32 -> bf16 pair in ONE VALU (RNE)
__device__ __forceinline__ unsigned int pk2(float a, float b) {
  unsigned int r;
  asm("v_cvt_pk_bf16_f32 %0, %1, %2" : "=v"(r) : "v"(a), "v"(b));
  return r;
}
#define EXP2F(x) __builtin_amdgcn_exp2f(x)

// ---------------------------------------------------------------------------
// Split-bf16 MFMA GEMM for 1x1 conv: out[oc][p] = sum_ic w[oc][ic]*in[ic][p].
// NS=2: x=H+L, 3 terms (err ~1e-5 rel). Block: 64 oc x 256 px, 4 waves.
// ---------------------------------------------------------------------------
template<int NS>
__global__ __launch_bounds__(256) void k_conv_mfma(
    const float* __restrict__ in, const float* __restrict__ w,
    const float* __restrict__ bias, float* __restrict__ out,
    const int IC, const int in_zstr, const int out_zstr)
{
  const int p0  = blockIdx.x * 256;
  const int oc0 = blockIdx.y * 64;
  in  += (size_t)blockIdx.z * (size_t)in_zstr;
  out += (size_t)blockIdx.z * (size_t)out_zstr;
  const int tid = threadIdx.x;
  const int wv = tid >> 6;
  const int lane = tid & 63;
  const int qi = lane & 15, g = lane >> 4;

  __shared__ __align__(16) unsigned int bS[NS][256 * 16];
  __shared__ __align__(16) unsigned int aS[NS][64 * 16];

  const f32x4 fz = {0.f, 0.f, 0.f, 0.f};
  f32x4 acc[4][4];
  #pragma unroll
  for (int j = 0; j < 4; ++j)
    #pragma unroll
    for (int o = 0; o < 4; ++o) acc[j][o] = fz;

  for (int k0 = 0; k0 < IC; k0 += 32) {
    __syncthreads();
    // ---- stage B: thread = k-pair (tid>>4), 16 px starting (tid&15)*16 ----
    {
      const int kB = tid >> 4;
      const int pB = (tid & 15) * 16;
      const float* r0 = in + (size_t)(k0 + 2 * kB) * P + p0 + pB;
      #pragma unroll
      for (int half = 0; half < 2; ++half) {
        float x0[8], x1[8];
        #pragma unroll
        for (int v = 0; v < 2; ++v) {
          float4 a = ((const float4*)r0)[half * 2 + v];
          float4 c = ((const float4*)(r0 + P))[half * 2 + v];
          x0[4*v] = a.x; x0[4*v+1] = a.y; x0[4*v+2] = a.z; x0[4*v+3] = a.w;
          x1[4*v] = c.x; x1[4*v+1] = c.y; x1[4*v+2] = c.z; x1[4*v+3] = c.w;
        }
        #pragma unroll
        for (int ii = 0; ii < 8; ++ii) {
          const int i8 = (ii + tid) & 7;           // bank rotation
          const int i = half * 8 + i8;
          const unsigned idx = (unsigned)((pB + i) * 16 + (kB ^ ((i & 3) << 2)));
          const unsigned u0 = __float_as_uint(x0[i8]);
          const unsigned u1 = __float_as_uint(x1[i8]);
          bS[0][idx] = __builtin_amdgcn_perm(u1, u0, 0x07060302u);
          const float r0f = x0[i8] - __uint_as_float(u0 & 0xffff0000u);
          const float r1f = x1[i8] - __uint_as_float(u1 & 0xffff0000u);
          if (NS == 2) {
            bS[1][idx] = pr2(r0f, r1f);
          } else {
            const unsigned m0 = __float_as_uint(r0f);
            const unsigned m1 = __float_as_uint(r1f);
            bS[1][idx] = __builtin_amdgcn_perm(m1, m0, 0x07060302u);
            const float s0 = r0f - __uint_as_float(m0 & 0xffff0000u);
            const float s1 = r1f - __uint_as_float(m1 & 0xffff0000u);
            bS[NS - 1][idx] = pr2(s0, s1);
          }
        }
      }
    }
    // ---- stage A: thread = oc row tid>>2, k span (tid&3)*8 ----
    {
      const int oA = tid >> 2;
      const int kA = (tid & 3) * 8;
      const float* rw = w + (size_t)(oc0 + oA) * IC + k0 + kA;
      float4 wa = ((const float4*)rw)[0];
      float4 wb = ((const float4*)rw)[1];
      float y[8] = {wa.x, wa.y, wa.z, wa.w, wb.x, wb.y, wb.z, wb.w};
      #pragma unroll
      for (int i = 0; i < 4; ++i) {
        const int dd = (kA >> 1) + i;
        const unsigned idx = (unsigned)(oA * 16 + (dd ^ ((oA & 3) << 2)));
        const unsigned u0 = __float_as_uint(y[2*i]);
        const unsigned u1 = __float_as_uint(y[2*i+1]);
        aS[0][idx] = __builtin_amdgcn_perm(u1, u0, 0x07060302u);
        const float r0f = y[2*i]   - __uint_as_float(u0 & 0xffff0000u);
        const float r1f = y[2*i+1] - __uint_as_float(u1 & 0xffff0000u);
        if (NS == 2) {
          aS[1][idx] = pr2(r0f, r1f);
        } else {
          const unsigned m0 = __float_as_uint(r0f);
          const unsigned m1 = __float_as_uint(r1f);
          aS[1][idx] = __builtin_amdgcn_perm(m1, m0, 0x07060302u);
          const float s0 = r0f - __uint_as_float(m0 & 0xffff0000u);
          const float s1 = r1f - __uint_as_float(m1 & 0xffff0000u);
          aS[NS - 1][idx] = pr2(s0, s1);
        }
      }
    }
    __syncthreads();

    bf16x8 aF[4][NS];
    #pragma unroll
    for (int o = 0; o < 4; ++o) {
      const unsigned ab = (unsigned)((o * 16 + qi) * 16 + 4 * (g ^ (qi & 3)));
      #pragma unroll
      for (int s = 0; s < NS; ++s)
        aF[o][s] = *(const bf16x8*)&aS[s][ab];
    }
    #pragma unroll
    for (int j = 0; j < 4; ++j) {
      const unsigned bb = (unsigned)(((wv * 4 + j) * 16 + qi) * 16 + 4 * (g ^ (qi & 3)));
      const bf16x8 b0 = *(const bf16x8*)&bS[0][bb];
      const bf16x8 b1 = *(const bf16x8*)&bS[1][bb];
      if (NS == 2) {
        #pragma unroll
        for (int o = 0; o < 4; ++o) {
          acc[j][o] = __builtin_amdgcn_mfma_f32_16x16x32_bf16(aF[o][0], b0, acc[j][o], 0, 0, 0);
          acc[j][o] = __builtin_amdgcn_mfma_f32_16x16x32_bf16(aF[o][0], b1, acc[j][o], 0, 0, 0);
          acc[j][o] = __builtin_amdgcn_mfma_f32_16x16x32_bf16(aF[o][1], b0, acc[j][o], 0, 0, 0);
        }
      } else {
        const bf16x8 b2 = *(const bf16x8*)&bS[NS - 1][bb];
        #pragma unroll
        for (int o = 0; o < 4; ++o) {
          acc[j][o] = __builtin_amdgcn_mfma_f32_16x16x32_bf16(aF[o][0], b0, acc[j][o], 0, 0, 0);
          acc[j][o] = __builtin_amdgcn_mfma_f32_16x16x32_bf16(aF[o][0], b1, acc[j][o], 0, 0, 0);
          acc[j][o] = __builtin_amdgcn_mfma_f32_16x16x32_bf16(aF[o][1], b0, acc[j][o], 0, 0, 0);
          acc[j][o] = __builtin_amdgcn_mfma_f32_16x16x32_bf16(aF[o][1], b1, acc[j][o], 0, 0, 0);
          acc[j][o] = __builtin_amdgcn_mfma_f32_16x16x32_bf16(aF[o][0], b2, acc[j][o], 0, 0, 0);
          acc[j][o] = __builtin_amdgcn_mfma_f32_16x16x32_bf16(aF[o][NS - 1], b0, acc[j][o], 0, 0, 0);
        }
      }
    }
  }

  float bv[4][4];
  #pragma unroll
  for (int o = 0; o < 4; ++o)
    #pragma unroll
    for (int t = 0; t < 4; ++t)
      bv[o][t] = bias ? bias[oc0 + o * 16 + 4 * g + t] : 0.f;

  #pragma unroll
  for (int j = 0; j < 4; ++j) {
    const int px = p0 + (wv * 4 + j) * 16 + qi;
    #pragma unroll
    for (int o = 0; o < 4; ++o)
      #pragma unroll
      for (int t = 0; t < 4; ++t)
        out[(size_t)(oc0 + o * 16 + 4 * g + t) * P + px] = acc[j][o][t] + bv[o][t];
  }
}

// ---------------------------------------------------------------------------
// Fold mlp into proj: Wc[o][b*128+i] = sum_j proj_w[o][b*128+j]*mlp_w[j][i]
// ---------------------------------------------------------------------------
__global__ __launch_bounds__(128) void k_foldw(
    const float* __restrict__ proj_w, const float* __restrict__ mlp_w,
    float* __restrict__ Wc)
{
  const int o = blockIdx.x;      // 0..127
  const int b = blockIdx.y;      // 0..2
  const int i = threadIdx.x;     // 0..127
  const float* pw = proj_w + o * 384 + b * 128;
  float acc = 0.f;
  for (int j = 0; j < 128; ++j)
    acc += pw[j] * mlp_w[j * 128 + i];
  Wc[o * 384 + b * 128 + i] = acc;
}
__global__ __launch_bounds__(128) void k_foldb(
    const float* __restrict__ proj_w, const float* __restrict__ mlp_b,
    float* __restrict__ bc)
{
  const int o = threadIdx.x;
  float acc = 0.f;
  for (int c = 0; c < 384; ++c) acc += proj_w[o * 384 + c] * mlp_b[c & 127];
  bc[o] = acc;
}

// ---------------------------------------------------------------------------
// Fused depthwise 3x3 + 5x5. Block = (channel, 128x16 tile). Input staged in
// LDS once with 2-px halo (20x132, 10.3KB); each thread produces 8 px of BOTH
// outputs from 15 ds_read_b128s. Weights are block-uniform -> s_loads.
// ---------------------------------------------------------------------------
__global__ __launch_bounds__(256) void k_dwf(
    const float* __restrict__ in, const float* __restrict__ w3,
    const float* __restrict__ w5, float* __restrict__ out3,
    float* __restrict__ out5)
{
  const int c  = blockIdx.y;          // 0..383
  const int ty = blockIdx.x;          // 0..7
  const int y0 = ty * 16;
  __shared__ float tS[20][132];
  const float* ip = in + (size_t)c * P;

  for (int e = threadIdx.x; e < 20 * 132; e += 256) {
    const int r = e / 132, cc = e - r * 132;
    const int gy = y0 + r - 2, gx = cc - 2;
    float v = 0.f;
    if (gy >= 0 && gy < 128 && gx >= 0 && gx < 128) v = ip[gy * 128 + gx];
    tS[r][cc] = v;
  }
  __syncthreads();

  float a3[9], a5[25];
  #pragma unroll
  for (int i = 0; i < 9; ++i)  a3[i] = w3[c * 9 + i];
  #pragma unroll
  for (int i = 0; i < 25; ++i) a5[i] = w5[c * 25 + i];

  const int py  = threadIdx.x >> 4;           // 0..15
  const int px0 = (threadIdx.x & 15) * 8;     // 0..120
  float o3[8] = {}, o5[8] = {};
  #pragma unroll
  for (int r = 0; r < 5; ++r) {
    float4 sa = *(const float4*)&tS[py + r][px0];
    float4 sb = *(const float4*)&tS[py + r][px0 + 4];
    float4 sc = *(const float4*)&tS[py + r][px0 + 8];
    const float s[12] = {sa.x, sa.y, sa.z, sa.w, sb.x, sb.y, sb.z, sb.w,
                         sc.x, sc.y, sc.z, sc.w};
    #pragma unroll
    for (int j = 0; j < 8; ++j) {
      float acc = a5[r * 5 + 0] * s[j];
      #pragma unroll
      for (int d = 1; d < 5; ++d) acc += a5[r * 5 + d] * s[j + d];
      o5[j] += acc;
    }
    if (r >= 1 && r <= 3) {
      #pragma unroll
      for (int j = 0; j < 8; ++j) {
        float b = a3[(r - 1) * 3 + 0] * s[j + 1];
        b += a3[(r - 1) * 3 + 1] * s[j + 2];
        b += a3[(r - 1) * 3 + 2] * s[j + 3];
        o3[j] += b;
      }
    }
  }
  const size_t ob = (size_t)c * P + (y0 + py) * 128 + px0;
  float4* p3 = (float4*)&out3[ob];
  float4* p5 = (float4*)&out5[ob];
  p3[0] = make_float4(o3[0], o3[1], o3[2], o3[3]);
  p3[1] = make_float4(o3[4], o3[5], o3[6], o3[7]);
  p5[0] = make_float4(o5[0], o5[1], o5[2], o5[3]);
  p5[1] = make_float4(o5[4], o5[5], o5[6], o5[7]);
}

// ---------------------------------------------------------------------------
// Grouped pointwise (12 groups of 32->32). NO restrict on in/out: the pw5
// call runs in-place (safe: all 32 loads precede the stores per thread).
// ---------------------------------------------------------------------------
__global__ __launch_bounds__(256) void k_pw(
    const float* in, const float* __restrict__ w, float* out)
{
  const int g = blockIdx.y;
  const int p = blockIdx.x * 256 + threadIdx.x;
  __shared__ float wL[1024];
  for (int e = threadIdx.x; e < 1024; e += 256) wL[e] = w[g * 1024 + e];
  __syncthreads();
  float r[32];
  #pragma unroll
  for (int i = 0; i < 32; ++i) r[i] = in[(g * 32 + i) * P + p];
  #pragma unroll
  for (int o = 0; o < 32; ++o) {
    float acc = 0.f;
    #pragma unroll
    for (int i = 0; i < 32; ++i) acc += wL[o * 32 + i] * r[i];
    out[(g * 32 + o) * P + p] = acc;
  }
}

// ---------------------------------------------------------------------------
// Window max of q (ch 0..127) and k (ch 128..255)
// ---------------------------------------------------------------------------
__global__ __launch_bounds__(256) void k_winmax(
    const float* __restrict__ e0, const float* __restrict__ e1,
    const float* __restrict__ e2, float* __restrict__ qwin,
    float* __restrict__ kwin)
{
  const int b = blockIdx.y;
  const int wIdx = blockIdx.x;
  const float* e = (b == 0) ? e0 : ((b == 1) ? e1 : e2);
  const int c = threadIdx.x;
  const int wy = wIdx >> 3, wx = wIdx & 7;
  const float* base = &e[c * P + (wy * 16) * 128 + wx * 16];
  float m = -INFINITY;
  for (int iy = 0; iy < 16; ++iy) {
    const float4* row = (const float4*)&base[iy * 128];
    #pragma unroll
    for (int j = 0; j < 4; ++j) {
      float4 v = row[j];
      m = fmaxf(m, fmaxf(fmaxf(v.x, v.y), fmaxf(v.z, v.w)));
    }
  }
  if (c < 128) qwin[(b * 64 + wIdx) * 128 + c] = m;
  else         kwin[(b * 64 + wIdx) * 128 + (c - 128)] = m;
}

// ---------------------------------------------------------------------------
// Window logits (64x64) + top-4 (ties -> lowest index) — exact fp32
// ---------------------------------------------------------------------------
__global__ __launch_bounds__(256) void k_topk(
    const float* __restrict__ qwin, const float* __restrict__ kwin,
    int* __restrict__ ridx)
{
  const int b = blockIdx.x;
  const int i = threadIdx.x & 63, jq = threadIdx.x >> 6;
  __shared__ float lg[64][68];
  float4 qr[32];
  const float4* q4 = (const float4*)&qwin[(b * 64 + i) * 128];
  #pragma unroll
  for (int t = 0; t < 32; ++t) qr[t] = q4[t];
  for (int jj = 0; jj < 16; ++jj) {
    const int j = jq * 16 + jj;
    const float4* k4 = (const float4*)&kwin[(b * 64 + j) * 128];
    float acc = 0.f;
    #pragma unroll
    for (int t = 0; t < 32; ++t) {
      float4 kv = k4[t];
      acc += qr[t].x * kv.x + qr[t].y * kv.y + qr[t].z * kv.z + qr[t].w * kv.w;
    }
    lg[i][j] = acc * SCALEF;
  }
  __syncthreads();
  if (threadIdx.x < 64) {
    unsigned long long mask = 0ull;
    for (int r = 0; r < 4; ++r) {
      float best = -INFINITY; int bj = 0;
      for (int j = 0; j < 64; ++j) {
        if ((mask >> j) & 1ull) continue;
        float v = lg[i][j];
        if (v > best) { best = v; bj = j; }   // strict > keeps lowest index
      }
      mask |= (1ull << bj);
      ridx[(b * 64 + i) * 4 + r] = bj;
    }
  }
}

// ---------------------------------------------------------------------------
// Repack Q/K/V into bf16 images pre-laid-out in LDS byte order.
// ---------------------------------------------------------------------------
__global__ __launch_bounds__(256) void k_repack(
    const float* __restrict__ e0, const float* __restrict__ e1,
    const float* __restrict__ e2, unsigned int* __restrict__ kvimg,
    unsigned int* __restrict__ qimg)
{
  const int fl = blockIdx.x + 64 * (blockIdx.y + 4 * blockIdx.z);
  const int nf = (fl & 7) * 96 + (fl >> 3);       // bijective: 768 = 8*96
  const int w = nf & 63, h = (nf >> 6) & 3, b = nf >> 8;
  const float* e = (b == 0) ? e0 : ((b == 1) ? e1 : e2);
  const int wy = w >> 3, wx = w & 7;
  const int jbase = wy * 16 * 128 + wx * 16;
  const int t = threadIdx.x;
  unsigned int* kwin_img = kvimg + (size_t)((b * 4 + h) * 64 + w) * 8192;
  unsigned int* qwin_img = qimg  + (size_t)((b * 4 + h) * 64 + w) * 4096;

  // K + Q: thread = pixel (key/query) 0..255, 16 u32 each
  {
    const int key = t;
    const int hw = jbase + (key >> 4) * 128 + (key & 15);
    const float* eK = e + (size_t)(128 + h * 32) * P + hw;
    const float* eQ = e + (size_t)(h * 32) * P + hw;
    const int half = key >> 7, kl = key & 127;
    unsigned int* kd = kwin_img + half * 4096 + kl * 16;
    unsigned int* qd = qwin_img + key * 16;
    #pragma unroll
    for (int dd = 0; dd < 16; ++dd) {
      float k0 = eK[(size_t)(2 * dd) * P], k1 = eK[(size_t)(2 * dd + 1) * P];
      kd[dd ^ ((kl & 3) << 2)] = packbf(k0, k1);
      float q0 = eQ[(size_t)(2 * dd) * P] * QSCALE;
      float q1 = eQ[(size_t)(2 * dd + 1) * P] * QSCALE;
      qd[dd] = packbf(q0, q1);
    }
  }
  // V^T: [d][key] row-XOR swizzled, u32 = key-pair; 16 u32 per thread
  {
    const int half = t >> 7, tt = t & 127;
    const int d = tt >> 2;
    const int kp0 = (tt & 3) * 16;
    const float* eV = e + (size_t)(256 + h * 32 + d) * P;
    unsigned int* vd = kwin_img + half * 4096 + 2048 + d * 64;
    #pragma unroll
    for (int i = 0; i < 16; ++i) {
      const int kp2 = kp0 + i;
      const int key = half * 128 + kp2 * 2;
      const int hw = jbase + (key >> 4) * 128 + (key & 15);
      float v0 = eV[hw], v1 = eV[hw + 1];
      vd[kp2 ^ ((d & 7) << 2)] = packbf(v0, v1);
    }
  }
}

// ---------------------------------------------------------------------------
// MFMA flash attention v5. 8 waves x 32 queries; XCD-swizzled. Single-barrier
// double-buffer. Softmax: raw v_exp_f32 + v_cvt_pk_bf16_f32.
// ---------------------------------------------------------------------------
__global__ __launch_bounds__(512, 4) void k_attn_mfma(
    const unsigned int* __restrict__ kvimg, const unsigned int* __restrict__ qimg,
    const int* __restrict__ ridx, float* __restrict__ attnch)
{
  const int fl = blockIdx.x + 64 * (blockIdx.y + 4 * blockIdx.z);
  const int nf = (fl & 7) * 96 + (fl >> 3);       // bijective XCD swizzle
  const int w = nf & 63, h = (nf >> 6) & 3, b = nf >> 8;
  const int tid = threadIdx.x;
  const int wv = tid >> 6, lane = tid & 63;
  const int qi = lane & 15, g = lane >> 4;
  const int wy = w >> 3, wx = w & 7;

  __shared__ __align__(16) unsigned int kvbuf[2][4096];   // 2 x 16KB

  const unsigned int* kwin = kvimg + (size_t)((b * 4 + h) * 64) * 8192;
  const unsigned int* qwin = qimg + (size_t)((b * 4 + h) * 64 + w) * 4096;

  // Q fragments: lane (qi,g), tile s: Q[q=(wv*2+s)*16+qi][d=8g..8g+7]
  bf16x8 qv[2];
  #pragma unroll
  for (int s = 0; s < 2; ++s) {
    union { uint4 u; bf16x8 v; } tq;
    tq.u = *(const uint4*)(qwin + ((wv * 2 + s) * 16 + qi) * 16 + g * 4);
    qv[s] = tq.v;
  }
  const int4 jv = *(const int4*)(ridx + (b * 64 + w) * 4);
  const int ja[4] = {jv.x, jv.y, jv.z, jv.w};

  const f32x4 fz = {0.f, 0.f, 0.f, 0.f};
  float m[2], l[2];
  f32x4 acc[2][2];
  #pragma unroll
  for (int s = 0; s < 2; ++s) {
    m[s] = -3.0e38f; l[s] = 0.f; acc[s][0] = fz; acc[s][1] = fz;
  }

  // prologue: load chunk 0 into regs
  uint4 st0, st1;
  {
    const uint4* s4 = (const uint4*)(kwin + (size_t)ja[0] * 8192);
    st0 = s4[tid]; st1 = s4[512 + tid];
  }

#define SOFTMAX_PACK(SC, S, PB) {                                           \
    float wmax = -3.0e38f;                                                  \
    _Pragma("unroll") for (int c = 0; c < 4; ++c)                           \
      _Pragma("unroll") for (int u = 0; u < 2; ++u)                         \
        _Pragma("unroll") for (int t2 = 0; t2 < 4; ++t2)                    \
          wmax = fmaxf(wmax, SC[c][u][t2]);                                 \
    wmax = fmaxf(wmax, __shfl_xor(wmax, 16, 64));                           \
    wmax = fmaxf(wmax, __shfl_xor(wmax, 32, 64));                           \
    const float mnew = fmaxf(m[S], wmax);                                   \
    const float corr = EXP2F(m[S] - mnew);                                  \
    m[S] = mnew;                                                            \
    acc[S][0] *= corr; acc[S][1] *= corr;                                   \
    float psum = 0.f;                                                       \
    _Pragma("unroll") for (int c = 0; c < 4; ++c)                           \
      _Pragma("unroll") for (int u = 0; u < 2; ++u) {                       \
        const float p0 = EXP2F(SC[c][u][0] - mnew);                         \
        const float p1 = EXP2F(SC[c][u][1] - mnew);                         \
        const float p2 = EXP2F(SC[c][u][2] - mnew);                         \
        const float p3 = EXP2F(SC[c][u][3] - mnew);                         \
        psum += (p0 + p1) + (p2 + p3);                                      \
        PB[c][2 * u]     = pk2(p0, p1);                                     \
        PB[c][2 * u + 1] = pk2(p2, p3);                                     \
      }                                                                     \
    l[S] = l[S] * corr + psum;                                              \
  }

  for (int ch = 0; ch < 8; ++ch) {
    // write chunk ch (staged in regs) into buf[ch&1]
    {
      uint4* d4 = (uint4*)kvbuf[ch & 1];
      d4[tid] = st0; d4[512 + tid] = st1;
    }
    // issue chunk ch+1 loads — latency hides under this chunk's compute
    if (ch < 7) {
      const int nx = ch + 1;
      const uint4* s4 = (const uint4*)(kwin + (size_t)ja[nx >> 1] * 8192
                                       + (size_t)(nx & 1) * 4096);
      st0 = s4[tid]; st1 = s4[512 + tid];
    }
    __syncthreads();   // chunk ch visible; prior chunk's readers are done

    const unsigned int* bc = kvbuf[ch & 1];
    const bf16x8* kp = (const bf16x8*)bc;
    const unsigned short* vsh = (const unsigned short*)(bc + 2048);

    f32x4 scA[4][2], scB[4][2];
    #pragma unroll
    for (int c = 0; c < 4; ++c) {
      #pragma unroll
      for (int u = 0; u < 2; ++u) {
        const int key = 32 * c + 8 * (qi >> 2) + 4 * u + (qi & 3);
        const bf16x8 ka = kp[key * 4 + (g ^ (qi & 3))];
        scA[c][u] = __builtin_amdgcn_mfma_f32_16x16x32_bf16(ka, qv[0], fz, 0, 0, 0);
        scB[c][u] = __builtin_amdgcn_mfma_f32_16x16x32_bf16(ka, qv[1], fz, 0, 0, 0);
      }
    }
    unsigned int pbA[4][4], pbB[4][4];
    SOFTMAX_PACK(scA, 0, pbA);
    SOFTMAX_PACK(scB, 1, pbB);
    #pragma unroll
    for (int c = 0; c < 4; ++c) {
      #pragma unroll
      for (int dt = 0; dt < 2; ++dt) {
        const int d0 = dt * 16 + qi;
        const bf16x8 va = *(const bf16x8*)&vsh[
            (unsigned)((d0 * 128 + 32 * c + 8 * g) ^ ((d0 & 7) << 3))];
        union { unsigned int u4[4]; bf16x8 v; } pva, pvb;
        pva.u4[0] = pbA[c][0]; pva.u4[1] = pbA[c][1];
        pva.u4[2] = pbA[c][2]; pva.u4[3] = pbA[c][3];
        pvb.u4[0] = pbB[c][0]; pvb.u4[1] = pbB[c][1];
        pvb.u4[2] = pbB[c][2]; pvb.u4[3] = pbB[c][3];
        acc[0][dt] = __builtin_amdgcn_mfma_f32_16x16x32_bf16(va, pva.v, acc[0][dt], 0, 0, 0);
        acc[1][dt] = __builtin_amdgcn_mfma_f32_16x16x32_bf16(va, pvb.v, acc[1][dt], 0, 0, 0);
      }
    }
  }
#undef SOFTMAX_PACK

  // epilogue: lane (qi,g) holds O^T[d = dt*16+4g+t][q = (wv*2+s)*16+qi]
  #pragma unroll
  for (int s = 0; s < 2; ++s) {
    float lsum = l[s];
    lsum += __shfl_xor(lsum, 16, 64);
    lsum += __shfl_xor(lsum, 32, 64);
    const float inv = 1.f / lsum;
    const int hwq = (wy * 16 + wv * 2 + s) * 128 + wx * 16 + qi;
    #pragma unroll
    for (int dt = 0; dt < 2; ++dt)
      #pragma unroll
      for (int t = 0; t < 4; ++t) {
        const int d = dt * 16 + 4 * g + t;
        attnch[(size_t)(b * 128 + h * 32 + d) * P + hwq] = acc[s][dt][t] * inv;
      }
  }
}

// ---------------------------------------------------------------------------
// LayerNorm over 128 channels per pixel. 256 blocks x 256 thr (4 ch-groups)
// ---------------------------------------------------------------------------
__global__ __launch_bounds__(256) void k_ln(
    const float* __restrict__ in, const float* __restrict__ gg,
    const float* __restrict__ bta, float* __restrict__ out)
{
  const int l = threadIdx.x & 63;
  const int grp = threadIdx.x >> 6;
  const int p = blockIdx.x * 64 + l;
  __shared__ float s1[4][64], s2[4][64];
  float vals[32];
  float a = 0.f, b2 = 0.f;
  #pragma unroll
  for (int i = 0; i < 32; ++i) {
    float v = in[(size_t)(grp * 32 + i) * P + p];
    vals[i] = v; a += v; b2 += v * v;
  }
  s1[grp][l] = a; s2[grp][l] = b2;
  __syncthreads();
  const float sum = s1[0][l] + s1[1][l] + s1[2][l] + s1[3][l];
  const float sq  = s2[0][l] + s2[1][l] + s2[2][l] + s2[3][l];
  const float mu = sum * (1.f / 128.f);
  const float var = sq * (1.f / 128.f) - mu * mu;
  const float rs = rsqrtf(var + 1e-5f);
  #pragma unroll
  for (int i = 0; i < 32; ++i) {
    const int c = grp * 32 + i;
    out[(size_t)c * P + p] = (vals[i] - mu) * rs * gg[c] + bta[c];
  }
}

// ---------------------------------------------------------------------------
extern "C" void kernel_launch(void* const* d_in, const int* in_sizes, int n_in,
                              void* d_out, int out_size, void* d_ws, size_t ws_size,
                              hipStream_t stream)
{
  (void)in_sizes; (void)n_in; (void)out_size;
  const float* x      = (const float*)d_in[0];
  const float* qkv2_w = (const float*)d_in[1];
  const float* dw3_w  = (const float*)d_in[2];
  const float* pw3_w  = (const float*)d_in[3];
  const float* dw5_w  = (const float*)d_in[4];
  const float* pw5_w  = (const float*)d_in[5];
  const float* mlp_w  = (const float*)d_in[6];
  const float* mlp_b  = (const float*)d_in[7];
  const float* proj_w = (const float*)d_in[8];
  const float* ln_g   = (const float*)d_in[9];
  const float* ln_b   = (const float*)d_in[10];

  float* ws = (float*)d_ws;
  const size_t CH = (size_t)384 * P;
  // region liveness:
  //  ws+0   : qkv (fp32)            -> projo
  //  ws+CH  : dwt3 (dw3 out)        -> qimg (bf16, after repack... after pw3)
  //  ws+2CH : y3
  //  ws+3CH : dwt5 (dw5 out)        -> y5 (pw5 runs in-place)
  //  ws+4CH : kvimg (bf16, 25.2MB)
  //  ws+5CH : qwin | kwin | ridx | Wc | bc
  float* qkv    = ws;
  float* dwt3   = ws + CH;
  float* y3     = ws + 2 * CH;
  float* y5     = ws + 3 * CH;           // also dwt5 (in-place pw5)
  float* qwin   = ws + 5 * CH;
  float* kwin   = qwin + 3 * 64 * 128;
  int*   ridx   = (int*)(kwin + 3 * 64 * 128);
  float* Wc     = (float*)(ridx + 768);
  float* bc     = Wc + 128 * 384;
  unsigned int* kvimg = (unsigned int*)(ws + 4 * CH);
  unsigned int* qimg  = (unsigned int*)dwt3;
  float* attnch = y3;
  float* projo  = qkv;
  (void)ws_size;

  // fold mlp into proj (independent of main chain)
  k_foldw<<<dim3(128, 3), 128, 0, stream>>>(proj_w, mlp_w, Wc);
  k_foldb<<<1, 128, 0, stream>>>(proj_w, mlp_b, bc);

  k_conv_mfma<2><<<dim3(64, 6, 1), 256, 0, stream>>>(x, qkv2_w, nullptr, qkv, 128, 0, 0);
  // fused depthwise 3x3 + 5x5 (reads qkv once)
  k_dwf<<<dim3(8, 384), 256, 0, stream>>>(qkv, dw3_w, dw5_w, dwt3, y5);
  k_pw<<<dim3(64, 12), 256, 0, stream>>>(dwt3, pw3_w, y3);
  k_pw<<<dim3(64, 12), 256, 0, stream>>>(y5, pw5_w, y5);   // in-place (safe)
  k_winmax<<<dim3(64, 3), 256, 0, stream>>>(qkv, y3, y5, qwin, kwin);
  k_topk<<<dim3(3), 256, 0, stream>>>(qwin, kwin, ridx);
  k_repack<<<dim3(64, 4, 3), 256, 0, stream>>>(qkv, y3, y5, kvimg, qimg);
  k_attn_mfma<<<dim3(64, 4, 3), 512, 0, stream>>>(kvimg, qimg, ridx, attnch);
  // fused mlp+proj: one IC=384 GEMM on attnch
  k_conv_mfma<2><<<dim3(64, 2, 1), 256, 0, stream>>>(attnch, Wc, bc, projo, 384, 0, 0);
  k_ln<<<dim3(256), 256, 0, stream>>>(projo, ln_g, ln_b, (float*)d_out);
}

// Round 9
// 233.865 us; speedup vs baseline: 3.0111x; 1.1125x over previous
//
#include <hip/hip_runtime.h>
#include <math.h>

#define P 16384               // 128*128 pixels
#define SCALEF 0.08838834764831845f             // 128^-0.5
#define QSCALE 0.12752075616290145f             // SCALEF * log2(e)

typedef short bf16x8 __attribute__((ext_vector_type(8)));
typedef float f32x4 __attribute__((ext_vector_type(4)));

__device__ __forceinline__ unsigned short f2bf(float x) {
  union { float f; unsigned int u; } v; v.f = x;
  unsigned int r = v.u + 0x7fffu + ((v.u >> 16) & 1u);  // RNE
  return (unsigned short)(r >> 16);
}
__device__ __forceinline__ unsigned int packbf(float a, float b) {
  return (unsigned int)f2bf(a) | ((unsigned int)f2bf(b) << 16);
}
// pack two f32 -> bf16 pair (round-half-up) via v_perm: 3 VALU
__device__ __forceinline__ unsigned int pr2(float a, float b) {
  union { float f; unsigned int u; } ua, ub; ua.f = a; ub.f = b;
  return __builtin_amdgcn_perm(ub.u + 0x8000u, ua.u + 0x8000u, 0x07060302u);
}
// pack two f32 -> bf16 pair in ONE VALU (RNE)
__device__ __forceinline__ unsigned int pk2(float a, float b) {
  unsigned int r;
  asm("v_cvt_pk_bf16_f32 %0, %1, %2" : "=v"(r) : "v"(a), "v"(b));
  return r;
}
#define EXP2F(x) __builtin_amdgcn_exp2f(x)

// ---------------------------------------------------------------------------
// Split-bf16 MFMA GEMM for 1x1 conv: out[oc][p] = sum_ic w[oc][ic]*in[ic][p].
// NS=2: x=H+L, 3 terms (err ~1e-5 rel). Block: 64 oc x 256 px, 4 waves.
// ---------------------------------------------------------------------------
template<int NS>
__global__ __launch_bounds__(256) void k_conv_mfma(
    const float* __restrict__ in, const float* __restrict__ w,
    const float* __restrict__ bias, float* __restrict__ out,
    const int IC, const int in_zstr, const int out_zstr)
{
  const int p0  = blockIdx.x * 256;
  const int oc0 = blockIdx.y * 64;
  in  += (size_t)blockIdx.z * (size_t)in_zstr;
  out += (size_t)blockIdx.z * (size_t)out_zstr;
  const int tid = threadIdx.x;
  const int wv = tid >> 6;
  const int lane = tid & 63;
  const int qi = lane & 15, g = lane >> 4;

  __shared__ __align__(16) unsigned int bS[NS][256 * 16];
  __shared__ __align__(16) unsigned int aS[NS][64 * 16];

  const f32x4 fz = {0.f, 0.f, 0.f, 0.f};
  f32x4 acc[4][4];
  #pragma unroll
  for (int j = 0; j < 4; ++j)
    #pragma unroll
    for (int o = 0; o < 4; ++o) acc[j][o] = fz;

  for (int k0 = 0; k0 < IC; k0 += 32) {
    __syncthreads();
    // ---- stage B: thread = k-pair (tid>>4), 16 px starting (tid&15)*16 ----
    {
      const int kB = tid >> 4;
      const int pB = (tid & 15) * 16;
      const float* r0 = in + (size_t)(k0 + 2 * kB) * P + p0 + pB;
      #pragma unroll
      for (int half = 0; half < 2; ++half) {
        float x0[8], x1[8];
        #pragma unroll
        for (int v = 0; v < 2; ++v) {
          float4 a = ((const float4*)r0)[half * 2 + v];
          float4 c = ((const float4*)(r0 + P))[half * 2 + v];
          x0[4*v] = a.x; x0[4*v+1] = a.y; x0[4*v+2] = a.z; x0[4*v+3] = a.w;
          x1[4*v] = c.x; x1[4*v+1] = c.y; x1[4*v+2] = c.z; x1[4*v+3] = c.w;
        }
        #pragma unroll
        for (int ii = 0; ii < 8; ++ii) {
          const int i8 = (ii + tid) & 7;           // bank rotation
          const int i = half * 8 + i8;
          const unsigned idx = (unsigned)((pB + i) * 16 + (kB ^ ((i & 3) << 2)));
          const unsigned u0 = __float_as_uint(x0[i8]);
          const unsigned u1 = __float_as_uint(x1[i8]);
          bS[0][idx] = __builtin_amdgcn_perm(u1, u0, 0x07060302u);
          const float r0f = x0[i8] - __uint_as_float(u0 & 0xffff0000u);
          const float r1f = x1[i8] - __uint_as_float(u1 & 0xffff0000u);
          if (NS == 2) {
            bS[1][idx] = pr2(r0f, r1f);
          } else {
            const unsigned m0 = __float_as_uint(r0f);
            const unsigned m1 = __float_as_uint(r1f);
            bS[1][idx] = __builtin_amdgcn_perm(m1, m0, 0x07060302u);
            const float s0 = r0f - __uint_as_float(m0 & 0xffff0000u);
            const float s1 = r1f - __uint_as_float(m1 & 0xffff0000u);
            bS[NS - 1][idx] = pr2(s0, s1);
          }
        }
      }
    }
    // ---- stage A: thread = oc row tid>>2, k span (tid&3)*8 ----
    {
      const int oA = tid >> 2;
      const int kA = (tid & 3) * 8;
      const float* rw = w + (size_t)(oc0 + oA) * IC + k0 + kA;
      float4 wa = ((const float4*)rw)[0];
      float4 wb = ((const float4*)rw)[1];
      float y[8] = {wa.x, wa.y, wa.z, wa.w, wb.x, wb.y, wb.z, wb.w};
      #pragma unroll
      for (int i = 0; i < 4; ++i) {
        const int dd = (kA >> 1) + i;
        const unsigned idx = (unsigned)(oA * 16 + (dd ^ ((oA & 3) << 2)));
        const unsigned u0 = __float_as_uint(y[2*i]);
        const unsigned u1 = __float_as_uint(y[2*i+1]);
        aS[0][idx] = __builtin_amdgcn_perm(u1, u0, 0x07060302u);
        const float r0f = y[2*i]   - __uint_as_float(u0 & 0xffff0000u);
        const float r1f = y[2*i+1] - __uint_as_float(u1 & 0xffff0000u);
        if (NS == 2) {
          aS[1][idx] = pr2(r0f, r1f);
        } else {
          const unsigned m0 = __float_as_uint(r0f);
          const unsigned m1 = __float_as_uint(r1f);
          aS[1][idx] = __builtin_amdgcn_perm(m1, m0, 0x07060302u);
          const float s0 = r0f - __uint_as_float(m0 & 0xffff0000u);
          const float s1 = r1f - __uint_as_float(m1 & 0xffff0000u);
          aS[NS - 1][idx] = pr2(s0, s1);
        }
      }
    }
    __syncthreads();

    bf16x8 aF[4][NS];
    #pragma unroll
    for (int o = 0; o < 4; ++o) {
      const unsigned ab = (unsigned)((o * 16 + qi) * 16 + 4 * (g ^ (qi & 3)));
      #pragma unroll
      for (int s = 0; s < NS; ++s)
        aF[o][s] = *(const bf16x8*)&aS[s][ab];
    }
    #pragma unroll
    for (int j = 0; j < 4; ++j) {
      const unsigned bb = (unsigned)(((wv * 4 + j) * 16 + qi) * 16 + 4 * (g ^ (qi & 3)));
      const bf16x8 b0 = *(const bf16x8*)&bS[0][bb];
      const bf16x8 b1 = *(const bf16x8*)&bS[1][bb];
      if (NS == 2) {
        #pragma unroll
        for (int o = 0; o < 4; ++o) {
          acc[j][o] = __builtin_amdgcn_mfma_f32_16x16x32_bf16(aF[o][0], b0, acc[j][o], 0, 0, 0);
          acc[j][o] = __builtin_amdgcn_mfma_f32_16x16x32_bf16(aF[o][0], b1, acc[j][o], 0, 0, 0);
          acc[j][o] = __builtin_amdgcn_mfma_f32_16x16x32_bf16(aF[o][1], b0, acc[j][o], 0, 0, 0);
        }
      } else {
        const bf16x8 b2 = *(const bf16x8*)&bS[NS - 1][bb];
        #pragma unroll
        for (int o = 0; o < 4; ++o) {
          acc[j][o] = __builtin_amdgcn_mfma_f32_16x16x32_bf16(aF[o][0], b0, acc[j][o], 0, 0, 0);
          acc[j][o] = __builtin_amdgcn_mfma_f32_16x16x32_bf16(aF[o][0], b1, acc[j][o], 0, 0, 0);
          acc[j][o] = __builtin_amdgcn_mfma_f32_16x16x32_bf16(aF[o][1], b0, acc[j][o], 0, 0, 0);
          acc[j][o] = __builtin_amdgcn_mfma_f32_16x16x32_bf16(aF[o][1], b1, acc[j][o], 0, 0, 0);
          acc[j][o] = __builtin_amdgcn_mfma_f32_16x16x32_bf16(aF[o][0], b2, acc[j][o], 0, 0, 0);
          acc[j][o] = __builtin_amdgcn_mfma_f32_16x16x32_bf16(aF[o][NS - 1], b0, acc[j][o], 0, 0, 0);
        }
      }
    }
  }

  float bv[4][4];
  #pragma unroll
  for (int o = 0; o < 4; ++o)
    #pragma unroll
    for (int t = 0; t < 4; ++t)
      bv[o][t] = bias ? bias[oc0 + o * 16 + 4 * g + t] : 0.f;

  #pragma unroll
  for (int j = 0; j < 4; ++j) {
    const int px = p0 + (wv * 4 + j) * 16 + qi;
    #pragma unroll
    for (int o = 0; o < 4; ++o)
      #pragma unroll
      for (int t = 0; t < 4; ++t)
        out[(size_t)(oc0 + o * 16 + 4 * g + t) * P + px] = acc[j][o][t] + bv[o][t];
  }
}

// ---------------------------------------------------------------------------
// Fold mlp into proj: Wc[o][b*128+i] = sum_j proj_w[o][b*128+j]*mlp_w[j][i]
// ---------------------------------------------------------------------------
__global__ __launch_bounds__(128) void k_foldw(
    const float* __restrict__ proj_w, const float* __restrict__ mlp_w,
    float* __restrict__ Wc)
{
  const int o = blockIdx.x;      // 0..127
  const int b = blockIdx.y;      // 0..2
  const int i = threadIdx.x;     // 0..127
  const float* pw = proj_w + o * 384 + b * 128;
  float acc = 0.f;
  for (int j = 0; j < 128; ++j)
    acc += pw[j] * mlp_w[j * 128 + i];
  Wc[o * 384 + b * 128 + i] = acc;
}
__global__ __launch_bounds__(128) void k_foldb(
    const float* __restrict__ proj_w, const float* __restrict__ mlp_b,
    float* __restrict__ bc)
{
  const int o = threadIdx.x;
  float acc = 0.f;
  for (int c = 0; c < 384; ++c) acc += proj_w[o * 384 + c] * mlp_b[c & 127];
  bc[o] = acc;
}

// ---------------------------------------------------------------------------
// Fused depthwise 3x3 + 5x5. Block = (channel, 128x16 tile). Input staged in
// LDS once with 2-px halo (20x132, 10.3KB); each thread produces 8 px of BOTH
// outputs from 15 ds_read_b128s. Weights are block-uniform -> s_loads.
// ---------------------------------------------------------------------------
__global__ __launch_bounds__(256) void k_dwf(
    const float* __restrict__ in, const float* __restrict__ w3,
    const float* __restrict__ w5, float* __restrict__ out3,
    float* __restrict__ out5)
{
  const int c  = blockIdx.y;          // 0..383
  const int ty = blockIdx.x;          // 0..7
  const int y0 = ty * 16;
  __shared__ float tS[20][132];
  const float* ip = in + (size_t)c * P;

  for (int e = threadIdx.x; e < 20 * 132; e += 256) {
    const int r = e / 132, cc = e - r * 132;
    const int gy = y0 + r - 2, gx = cc - 2;
    float v = 0.f;
    if (gy >= 0 && gy < 128 && gx >= 0 && gx < 128) v = ip[gy * 128 + gx];
    tS[r][cc] = v;
  }
  __syncthreads();

  float a3[9], a5[25];
  #pragma unroll
  for (int i = 0; i < 9; ++i)  a3[i] = w3[c * 9 + i];
  #pragma unroll
  for (int i = 0; i < 25; ++i) a5[i] = w5[c * 25 + i];

  const int py  = threadIdx.x >> 4;           // 0..15
  const int px0 = (threadIdx.x & 15) * 8;     // 0..120
  float o3[8] = {}, o5[8] = {};
  #pragma unroll
  for (int r = 0; r < 5; ++r) {
    float4 sa = *(const float4*)&tS[py + r][px0];
    float4 sb = *(const float4*)&tS[py + r][px0 + 4];
    float4 sc = *(const float4*)&tS[py + r][px0 + 8];
    const float s[12] = {sa.x, sa.y, sa.z, sa.w, sb.x, sb.y, sb.z, sb.w,
                         sc.x, sc.y, sc.z, sc.w};
    #pragma unroll
    for (int j = 0; j < 8; ++j) {
      float acc = a5[r * 5 + 0] * s[j];
      #pragma unroll
      for (int d = 1; d < 5; ++d) acc += a5[r * 5 + d] * s[j + d];
      o5[j] += acc;
    }
    if (r >= 1 && r <= 3) {
      #pragma unroll
      for (int j = 0; j < 8; ++j) {
        float b = a3[(r - 1) * 3 + 0] * s[j + 1];
        b += a3[(r - 1) * 3 + 1] * s[j + 2];
        b += a3[(r - 1) * 3 + 2] * s[j + 3];
        o3[j] += b;
      }
    }
  }
  const size_t ob = (size_t)c * P + (y0 + py) * 128 + px0;
  float4* p3 = (float4*)&out3[ob];
  float4* p5 = (float4*)&out5[ob];
  p3[0] = make_float4(o3[0], o3[1], o3[2], o3[3]);
  p3[1] = make_float4(o3[4], o3[5], o3[6], o3[7]);
  p5[0] = make_float4(o5[0], o5[1], o5[2], o5[3]);
  p5[1] = make_float4(o5[4], o5[5], o5[6], o5[7]);
}

// ---------------------------------------------------------------------------
// Grouped pointwise (12 groups of 32->32). NO restrict on in/out: the pw5
// call runs in-place (safe: all 32 loads precede the stores per thread).
// ---------------------------------------------------------------------------
__global__ __launch_bounds__(256) void k_pw(
    const float* in, const float* __restrict__ w, float* out)
{
  const int g = blockIdx.y;
  const int p = blockIdx.x * 256 + threadIdx.x;
  __shared__ float wL[1024];
  for (int e = threadIdx.x; e < 1024; e += 256) wL[e] = w[g * 1024 + e];
  __syncthreads();
  float r[32];
  #pragma unroll
  for (int i = 0; i < 32; ++i) r[i] = in[(g * 32 + i) * P + p];
  #pragma unroll
  for (int o = 0; o < 32; ++o) {
    float acc = 0.f;
    #pragma unroll
    for (int i = 0; i < 32; ++i) acc += wL[o * 32 + i] * r[i];
    out[(g * 32 + o) * P + p] = acc;
  }
}

// ---------------------------------------------------------------------------
// Window max v2. Block (window, branch), 4 waves. Per iteration a wave does
// 2 channels: 32 lanes cover the 256-px window (2 lanes/row, 32B each) ->
// coalesced; per-lane 8-max then 5x shfl_xor fmax (fp32 max is exact).
// ---------------------------------------------------------------------------
__global__ __launch_bounds__(256) void k_winmax(
    const float* __restrict__ e0, const float* __restrict__ e1,
    const float* __restrict__ e2, float* __restrict__ qwin,
    float* __restrict__ kwin)
{
  const int b = blockIdx.y;
  const int wIdx = blockIdx.x;
  const float* e = (b == 0) ? e0 : ((b == 1) ? e1 : e2);
  const int wy = wIdx >> 3, wx = wIdx & 7;
  const int wv = threadIdx.x >> 6;
  const int lane = threadIdx.x & 63;
  const int half = lane >> 5, sub = lane & 31;
  const int row = sub >> 1, px8 = (sub & 1) * 8;
  const int base_off = (wy * 16 + row) * 128 + wx * 16 + px8;

  #pragma unroll 4
  for (int it = 0; it < 32; ++it) {
    const int c = it * 8 + wv * 2 + half;
    const float4* p4 = (const float4*)&e[(size_t)c * P + base_off];
    float4 v0 = p4[0], v1 = p4[1];
    float m = fmaxf(fmaxf(fmaxf(v0.x, v0.y), fmaxf(v0.z, v0.w)),
                    fmaxf(fmaxf(v1.x, v1.y), fmaxf(v1.z, v1.w)));
    #pragma unroll
    for (int s = 1; s <= 16; s <<= 1)
      m = fmaxf(m, __shfl_xor(m, s, 64));
    if (sub == 0) {
      if (c < 128) qwin[(b * 64 + wIdx) * 128 + c] = m;
      else         kwin[(b * 64 + wIdx) * 128 + (c - 128)] = m;
    }
  }
}

// ---------------------------------------------------------------------------
// Top-4 v2: one wave per query window. Lane j computes logit(i,j); top-4 by
// 4 rounds of butterfly argmax (lowest index on ties, = jax.lax.top_k).
// SCALEF dropped: positive uniform scale preserves ranking and ties exactly.
// ---------------------------------------------------------------------------
__global__ __launch_bounds__(256) void k_topk(
    const float* __restrict__ qwin, const float* __restrict__ kwin,
    int* __restrict__ ridx)
{
  const int b = blockIdx.y;
  const int i = blockIdx.x * 4 + (threadIdx.x >> 6);
  const int j = threadIdx.x & 63;
  const float4* q4 = (const float4*)&qwin[(b * 64 + i) * 128];
  const float4* k4 = (const float4*)&kwin[(b * 64 + j) * 128];
  float v = 0.f;
  #pragma unroll
  for (int t = 0; t < 32; ++t) {
    float4 a = q4[t], c = k4[t];
    v += a.x * c.x + a.y * c.y + a.z * c.z + a.w * c.w;
  }
  int res[4];
  #pragma unroll
  for (int r = 0; r < 4; ++r) {
    float bv = v; int bj = j;
    #pragma unroll
    for (int s = 1; s < 64; s <<= 1) {
      const float ov = __shfl_xor(bv, s, 64);
      const int   oj = __shfl_xor(bj, s, 64);
      if (ov > bv || (ov == bv && oj < bj)) { bv = ov; bj = oj; }
    }
    res[r] = bj;
    if (j == bj) v = -INFINITY;
  }
  if (j == 0)
    *(int4*)&ridx[(b * 64 + i) * 4] = make_int4(res[0], res[1], res[2], res[3]);
}

// ---------------------------------------------------------------------------
// Repack Q/K/V into bf16 images pre-laid-out in LDS byte order.
// ---------------------------------------------------------------------------
__global__ __launch_bounds__(256) void k_repack(
    const float* __restrict__ e0, const float* __restrict__ e1,
    const float* __restrict__ e2, unsigned int* __restrict__ kvimg,
    unsigned int* __restrict__ qimg)
{
  const int fl = blockIdx.x + 64 * (blockIdx.y + 4 * blockIdx.z);
  const int nf = (fl & 7) * 96 + (fl >> 3);       // bijective: 768 = 8*96
  const int w = nf & 63, h = (nf >> 6) & 3, b = nf >> 8;
  const float* e = (b == 0) ? e0 : ((b == 1) ? e1 : e2);
  const int wy = w >> 3, wx = w & 7;
  const int jbase = wy * 16 * 128 + wx * 16;
  const int t = threadIdx.x;
  unsigned int* kwin_img = kvimg + (size_t)((b * 4 + h) * 64 + w) * 8192;
  unsigned int* qwin_img = qimg  + (size_t)((b * 4 + h) * 64 + w) * 4096;

  // K + Q: thread = pixel (key/query) 0..255, 16 u32 each
  {
    const int key = t;
    const int hw = jbase + (key >> 4) * 128 + (key & 15);
    const float* eK = e + (size_t)(128 + h * 32) * P + hw;
    const float* eQ = e + (size_t)(h * 32) * P + hw;
    const int half = key >> 7, kl = key & 127;
    unsigned int* kd = kwin_img + half * 4096 + kl * 16;
    unsigned int* qd = qwin_img + key * 16;
    #pragma unroll
    for (int dd = 0; dd < 16; ++dd) {
      float k0 = eK[(size_t)(2 * dd) * P], k1 = eK[(size_t)(2 * dd + 1) * P];
      kd[dd ^ ((kl & 3) << 2)] = packbf(k0, k1);
      float q0 = eQ[(size_t)(2 * dd) * P] * QSCALE;
      float q1 = eQ[(size_t)(2 * dd + 1) * P] * QSCALE;
      qd[dd] = packbf(q0, q1);
    }
  }
  // V^T: [d][key] row-XOR swizzled, u32 = key-pair; 16 u32 per thread
  {
    const int half = t >> 7, tt = t & 127;
    const int d = tt >> 2;
    const int kp0 = (tt & 3) * 16;
    const float* eV = e + (size_t)(256 + h * 32 + d) * P;
    unsigned int* vd = kwin_img + half * 4096 + 2048 + d * 64;
    #pragma unroll
    for (int i = 0; i < 16; ++i) {
      const int kp2 = kp0 + i;
      const int key = half * 128 + kp2 * 2;
      const int hw = jbase + (key >> 4) * 128 + (key & 15);
      float v0 = eV[hw], v1 = eV[hw + 1];
      vd[kp2 ^ ((d & 7) << 2)] = packbf(v0, v1);
    }
  }
}

// ---------------------------------------------------------------------------
// MFMA flash attention v5. 8 waves x 32 queries; XCD-swizzled. Single-barrier
// double-buffer. Softmax: raw v_exp_f32 + v_cvt_pk_bf16_f32.
// ---------------------------------------------------------------------------
__global__ __launch_bounds__(512, 4) void k_attn_mfma(
    const unsigned int* __restrict__ kvimg, const unsigned int* __restrict__ qimg,
    const int* __restrict__ ridx, float* __restrict__ attnch)
{
  const int fl = blockIdx.x + 64 * (blockIdx.y + 4 * blockIdx.z);
  const int nf = (fl & 7) * 96 + (fl >> 3);       // bijective XCD swizzle
  const int w = nf & 63, h = (nf >> 6) & 3, b = nf >> 8;
  const int tid = threadIdx.x;
  const int wv = tid >> 6, lane = tid & 63;
  const int qi = lane & 15, g = lane >> 4;
  const int wy = w >> 3, wx = w & 7;

  __shared__ __align__(16) unsigned int kvbuf[2][4096];   // 2 x 16KB

  const unsigned int* kwin = kvimg + (size_t)((b * 4 + h) * 64) * 8192;
  const unsigned int* qwin = qimg + (size_t)((b * 4 + h) * 64 + w) * 4096;

  // Q fragments: lane (qi,g), tile s: Q[q=(wv*2+s)*16+qi][d=8g..8g+7]
  bf16x8 qv[2];
  #pragma unroll
  for (int s = 0; s < 2; ++s) {
    union { uint4 u; bf16x8 v; } tq;
    tq.u = *(const uint4*)(qwin + ((wv * 2 + s) * 16 + qi) * 16 + g * 4);
    qv[s] = tq.v;
  }
  const int4 jv = *(const int4*)(ridx + (b * 64 + w) * 4);
  const int ja[4] = {jv.x, jv.y, jv.z, jv.w};

  const f32x4 fz = {0.f, 0.f, 0.f, 0.f};
  float m[2], l[2];
  f32x4 acc[2][2];
  #pragma unroll
  for (int s = 0; s < 2; ++s) {
    m[s] = -3.0e38f; l[s] = 0.f; acc[s][0] = fz; acc[s][1] = fz;
  }

  // prologue: load chunk 0 into regs
  uint4 st0, st1;
  {
    const uint4* s4 = (const uint4*)(kwin + (size_t)ja[0] * 8192);
    st0 = s4[tid]; st1 = s4[512 + tid];
  }

#define SOFTMAX_PACK(SC, S, PB) {                                           \
    float wmax = -3.0e38f;                                                  \
    _Pragma("unroll") for (int c = 0; c < 4; ++c)                           \
      _Pragma("unroll") for (int u = 0; u < 2; ++u)                         \
        _Pragma("unroll") for (int t2 = 0; t2 < 4; ++t2)                    \
          wmax = fmaxf(wmax, SC[c][u][t2]);                                 \
    wmax = fmaxf(wmax, __shfl_xor(wmax, 16, 64));                           \
    wmax = fmaxf(wmax, __shfl_xor(wmax, 32, 64));                           \
    const float mnew = fmaxf(m[S], wmax);                                   \
    const float corr = EXP2F(m[S] - mnew);                                  \
    m[S] = mnew;                                                            \
    acc[S][0] *= corr; acc[S][1] *= corr;                                   \
    float psum = 0.f;                                                       \
    _Pragma("unroll") for (int c = 0; c < 4; ++c)                           \
      _Pragma("unroll") for (int u = 0; u < 2; ++u) {                       \
        const float p0 = EXP2F(SC[c][u][0] - mnew);                         \
        const float p1 = EXP2F(SC[c][u][1] - mnew);                         \
        const float p2 = EXP2F(SC[c][u][2] - mnew);                         \
        const float p3 = EXP2F(SC[c][u][3] - mnew);                         \
        psum += (p0 + p1) + (p2 + p3);                                      \
        PB[c][2 * u]     = pk2(p0, p1);                                     \
        PB[c][2 * u + 1] = pk2(p2, p3);                                     \
      }                                                                     \
    l[S] = l[S] * corr + psum;                                              \
  }

  for (int ch = 0; ch < 8; ++ch) {
    // write chunk ch (staged in regs) into buf[ch&1]
    {
      uint4* d4 = (uint4*)kvbuf[ch & 1];
      d4[tid] = st0; d4[512 + tid] = st1;
    }
    // issue chunk ch+1 loads — latency hides under this chunk's compute
    if (ch < 7) {
      const int nx = ch + 1;
      const uint4* s4 = (const uint4*)(kwin + (size_t)ja[nx >> 1] * 8192
                                       + (size_t)(nx & 1) * 4096);
      st0 = s4[tid]; st1 = s4[512 + tid];
    }
    __syncthreads();   // chunk ch visible; prior chunk's readers are done

    const unsigned int* bc = kvbuf[ch & 1];
    const bf16x8* kp = (const bf16x8*)bc;
    const unsigned short* vsh = (const unsigned short*)(bc + 2048);

    f32x4 scA[4][2], scB[4][2];
    #pragma unroll
    for (int c = 0; c < 4; ++c) {
      #pragma unroll
      for (int u = 0; u < 2; ++u) {
        const int key = 32 * c + 8 * (qi >> 2) + 4 * u + (qi & 3);
        const bf16x8 ka = kp[key * 4 + (g ^ (qi & 3))];
        scA[c][u] = __builtin_amdgcn_mfma_f32_16x16x32_bf16(ka, qv[0], fz, 0, 0, 0);
        scB[c][u] = __builtin_amdgcn_mfma_f32_16x16x32_bf16(ka, qv[1], fz, 0, 0, 0);
      }
    }
    unsigned int pbA[4][4], pbB[4][4];
    SOFTMAX_PACK(scA, 0, pbA);
    SOFTMAX_PACK(scB, 1, pbB);
    #pragma unroll
    for (int c = 0; c < 4; ++c) {
      #pragma unroll
      for (int dt = 0; dt < 2; ++dt) {
        const int d0 = dt * 16 + qi;
        const bf16x8 va = *(const bf16x8*)&vsh[
            (unsigned)((d0 * 128 + 32 * c + 8 * g) ^ ((d0 & 7) << 3))];
        union { unsigned int u4[4]; bf16x8 v; } pva, pvb;
        pva.u4[0] = pbA[c][0]; pva.u4[1] = pbA[c][1];
        pva.u4[2] = pbA[c][2]; pva.u4[3] = pbA[c][3];
        pvb.u4[0] = pbB[c][0]; pvb.u4[1] = pbB[c][1];
        pvb.u4[2] = pbB[c][2]; pvb.u4[3] = pbB[c][3];
        acc[0][dt] = __builtin_amdgcn_mfma_f32_16x16x32_bf16(va, pva.v, acc[0][dt], 0, 0, 0);
        acc[1][dt] = __builtin_amdgcn_mfma_f32_16x16x32_bf16(va, pvb.v, acc[1][dt], 0, 0, 0);
      }
    }
  }
#undef SOFTMAX_PACK

  // epilogue: lane (qi,g) holds O^T[d = dt*16+4g+t][q = (wv*2+s)*16+qi]
  #pragma unroll
  for (int s = 0; s < 2; ++s) {
    float lsum = l[s];
    lsum += __shfl_xor(lsum, 16, 64);
    lsum += __shfl_xor(lsum, 32, 64);
    const float inv = 1.f / lsum;
    const int hwq = (wy * 16 + wv * 2 + s) * 128 + wx * 16 + qi;
    #pragma unroll
    for (int dt = 0; dt < 2; ++dt)
      #pragma unroll
      for (int t = 0; t < 4; ++t) {
        const int d = dt * 16 + 4 * g + t;
        attnch[(size_t)(b * 128 + h * 32 + d) * P + hwq] = acc[s][dt][t] * inv;
      }
  }
}

// ---------------------------------------------------------------------------
// LayerNorm over 128 channels per pixel. 256 blocks x 256 thr (4 ch-groups)
// ---------------------------------------------------------------------------
__global__ __launch_bounds__(256) void k_ln(
    const float* __restrict__ in, const float* __restrict__ gg,
    const float* __restrict__ bta, float* __restrict__ out)
{
  const int l = threadIdx.x & 63;
  const int grp = threadIdx.x >> 6;
  const int p = blockIdx.x * 64 + l;
  __shared__ float s1[4][64], s2[4][64];
  float vals[32];
  float a = 0.f, b2 = 0.f;
  #pragma unroll
  for (int i = 0; i < 32; ++i) {
    float v = in[(size_t)(grp * 32 + i) * P + p];
    vals[i] = v; a += v; b2 += v * v;
  }
  s1[grp][l] = a; s2[grp][l] = b2;
  __syncthreads();
  const float sum = s1[0][l] + s1[1][l] + s1[2][l] + s1[3][l];
  const float sq  = s2[0][l] + s2[1][l] + s2[2][l] + s2[3][l];
  const float mu = sum * (1.f / 128.f);
  const float var = sq * (1.f / 128.f) - mu * mu;
  const float rs = rsqrtf(var + 1e-5f);
  #pragma unroll
  for (int i = 0; i < 32; ++i) {
    const int c = grp * 32 + i;
    out[(size_t)c * P + p] = (vals[i] - mu) * rs * gg[c] + bta[c];
  }
}

// ---------------------------------------------------------------------------
extern "C" void kernel_launch(void* const* d_in, const int* in_sizes, int n_in,
                              void* d_out, int out_size, void* d_ws, size_t ws_size,
                              hipStream_t stream)
{
  (void)in_sizes; (void)n_in; (void)out_size;
  const float* x      = (const float*)d_in[0];
  const float* qkv2_w = (const float*)d_in[1];
  const float* dw3_w  = (const float*)d_in[2];
  const float* pw3_w  = (const float*)d_in[3];
  const float* dw5_w  = (const float*)d_in[4];
  const float* pw5_w  = (const float*)d_in[5];
  const float* mlp_w  = (const float*)d_in[6];
  const float* mlp_b  = (const float*)d_in[7];
  const float* proj_w = (const float*)d_in[8];
  const float* ln_g   = (const float*)d_in[9];
  const float* ln_b   = (const float*)d_in[10];

  float* ws = (float*)d_ws;
  const size_t CH = (size_t)384 * P;
  // region liveness:
  //  ws+0   : qkv (fp32)            -> projo
  //  ws+CH  : dwt3 (dw3 out)        -> qimg (bf16, after repack... after pw3)
  //  ws+2CH : y3
  //  ws+3CH : dwt5 (dw5 out)        -> y5 (pw5 runs in-place)
  //  ws+4CH : kvimg (bf16, 25.2MB)
  //  ws+5CH : qwin | kwin | ridx | Wc | bc
  float* qkv    = ws;
  float* dwt3   = ws + CH;
  float* y3     = ws + 2 * CH;
  float* y5     = ws + 3 * CH;           // also dwt5 (in-place pw5)
  float* qwin   = ws + 5 * CH;
  float* kwin   = qwin + 3 * 64 * 128;
  int*   ridx   = (int*)(kwin + 3 * 64 * 128);
  float* Wc     = (float*)(ridx + 768);
  float* bc     = Wc + 128 * 384;
  unsigned int* kvimg = (unsigned int*)(ws + 4 * CH);
  unsigned int* qimg  = (unsigned int*)dwt3;
  float* attnch = y3;
  float* projo  = qkv;
  (void)ws_size;

  // fold mlp into proj (independent of main chain)
  k_foldw<<<dim3(128, 3), 128, 0, stream>>>(proj_w, mlp_w, Wc);
  k_foldb<<<1, 128, 0, stream>>>(proj_w, mlp_b, bc);

  k_conv_mfma<2><<<dim3(64, 6, 1), 256, 0, stream>>>(x, qkv2_w, nullptr, qkv, 128, 0, 0);
  // fused depthwise 3x3 + 5x5 (reads qkv once)
  k_dwf<<<dim3(8, 384), 256, 0, stream>>>(qkv, dw3_w, dw5_w, dwt3, y5);
  k_pw<<<dim3(64, 12), 256, 0, stream>>>(dwt3, pw3_w, y3);
  k_pw<<<dim3(64, 12), 256, 0, stream>>>(y5, pw5_w, y5);   // in-place (safe)
  k_winmax<<<dim3(64, 3), 256, 0, stream>>>(qkv, y3, y5, qwin, kwin);
  k_topk<<<dim3(16, 3), 256, 0, stream>>>(qwin, kwin, ridx);
  k_repack<<<dim3(64, 4, 3), 256, 0, stream>>>(qkv, y3, y5, kvimg, qimg);
  k_attn_mfma<<<dim3(64, 4, 3), 512, 0, stream>>>(kvimg, qimg, ridx, attnch);
  // fused mlp+proj: one IC=384 GEMM on attnch
  k_conv_mfma<2><<<dim3(64, 2, 1), 256, 0, stream>>>(attnch, Wc, bc, projo, 384, 0, 0);
  k_ln<<<dim3(256), 256, 0, stream>>>(projo, ln_g, ln_b, (float*)d_out);
}

// Round 10
// 216.507 us; speedup vs baseline: 3.2525x; 1.0802x over previous
//
#include <hip/hip_runtime.h>
#include <math.h>

#define P 16384               // 128*128 pixels
#define SCALEF 0.08838834764831845f             // 128^-0.5
#define QSCALE 0.12752075616290145f             // SCALEF * log2(e)

typedef short bf16x8 __attribute__((ext_vector_type(8)));
typedef float f32x4 __attribute__((ext_vector_type(4)));

__device__ __forceinline__ unsigned short f2bf(float x) {
  union { float f; unsigned int u; } v; v.f = x;
  unsigned int r = v.u + 0x7fffu + ((v.u >> 16) & 1u);  // RNE
  return (unsigned short)(r >> 16);
}
__device__ __forceinline__ unsigned int packbf(float a, float b) {
  return (unsigned int)f2bf(a) | ((unsigned int)f2bf(b) << 16);
}
// pack two f32 -> bf16 pair (round-half-up) via v_perm: 3 VALU
__device__ __forceinline__ unsigned int pr2(float a, float b) {
  union { float f; unsigned int u; } ua, ub; ua.f = a; ub.f = b;
  return __builtin_amdgcn_perm(ub.u + 0x8000u, ua.u + 0x8000u, 0x07060302u);
}
// pack two f32 -> bf16 pair in ONE VALU (RNE)
__device__ __forceinline__ unsigned int pk2(float a, float b) {
  unsigned int r;
  asm("v_cvt_pk_bf16_f32 %0, %1, %2" : "=v"(r) : "v"(a), "v"(b));
  return r;
}
#define EXP2F(x) __builtin_amdgcn_exp2f(x)

// ---------------------------------------------------------------------------
// Split-bf16 MFMA GEMM for 1x1 conv: out[oc][p] = sum_ic w[oc][ic]*in[ic][p].
// NS=2: x=H+L, 3 terms (err ~1e-5 rel). Block: 64 oc x JT*64 px, 4 waves.
// JT=2 -> 128px tiles (better grid balance); JT=4 -> 256px.
// ---------------------------------------------------------------------------
template<int NS, int JT>
__global__ __launch_bounds__(256) void k_conv_mfma(
    const float* __restrict__ in, const float* __restrict__ w,
    const float* __restrict__ bias, float* __restrict__ out,
    const int IC, const int in_zstr, const int out_zstr)
{
  const int p0  = blockIdx.x * (JT * 64);
  const int oc0 = blockIdx.y * 64;
  in  += (size_t)blockIdx.z * (size_t)in_zstr;
  out += (size_t)blockIdx.z * (size_t)out_zstr;
  const int tid = threadIdx.x;
  const int wv = tid >> 6;
  const int lane = tid & 63;
  const int qi = lane & 15, g = lane >> 4;

  __shared__ __align__(16) unsigned int bS[NS][JT * 64 * 16];
  __shared__ __align__(16) unsigned int aS[NS][64 * 16];

  const f32x4 fz = {0.f, 0.f, 0.f, 0.f};
  f32x4 acc[JT][4];
  #pragma unroll
  for (int j = 0; j < JT; ++j)
    #pragma unroll
    for (int o = 0; o < 4; ++o) acc[j][o] = fz;

  for (int k0 = 0; k0 < IC; k0 += 32) {
    __syncthreads();
    // ---- stage B: thread = k-pair (tid>>4), JT*4 px starting (tid&15)*JT*4
    {
      const int kB = tid >> 4;
      const int pB = (tid & 15) * (JT * 4);
      const float* r0 = in + (size_t)(k0 + 2 * kB) * P + p0 + pB;
      #pragma unroll
      for (int half = 0; half < JT / 2; ++half) {
        float x0[8], x1[8];
        #pragma unroll
        for (int v = 0; v < 2; ++v) {
          float4 a = ((const float4*)r0)[half * 2 + v];
          float4 c = ((const float4*)(r0 + P))[half * 2 + v];
          x0[4*v] = a.x; x0[4*v+1] = a.y; x0[4*v+2] = a.z; x0[4*v+3] = a.w;
          x1[4*v] = c.x; x1[4*v+1] = c.y; x1[4*v+2] = c.z; x1[4*v+3] = c.w;
        }
        #pragma unroll
        for (int ii = 0; ii < 8; ++ii) {
          const int i8 = (ii + tid) & 7;           // bank rotation
          const int i = half * 8 + i8;
          const unsigned idx = (unsigned)((pB + i) * 16 + (kB ^ ((i & 3) << 2)));
          const unsigned u0 = __float_as_uint(x0[i8]);
          const unsigned u1 = __float_as_uint(x1[i8]);
          bS[0][idx] = __builtin_amdgcn_perm(u1, u0, 0x07060302u);
          const float r0f = x0[i8] - __uint_as_float(u0 & 0xffff0000u);
          const float r1f = x1[i8] - __uint_as_float(u1 & 0xffff0000u);
          bS[1][idx] = pr2(r0f, r1f);
        }
      }
    }
    // ---- stage A: thread = oc row tid>>2, k span (tid&3)*8 ----
    {
      const int oA = tid >> 2;
      const int kA = (tid & 3) * 8;
      const float* rw = w + (size_t)(oc0 + oA) * IC + k0 + kA;
      float4 wa = ((const float4*)rw)[0];
      float4 wb = ((const float4*)rw)[1];
      float y[8] = {wa.x, wa.y, wa.z, wa.w, wb.x, wb.y, wb.z, wb.w};
      #pragma unroll
      for (int i = 0; i < 4; ++i) {
        const int dd = (kA >> 1) + i;
        const unsigned idx = (unsigned)(oA * 16 + (dd ^ ((oA & 3) << 2)));
        const unsigned u0 = __float_as_uint(y[2*i]);
        const unsigned u1 = __float_as_uint(y[2*i+1]);
        aS[0][idx] = __builtin_amdgcn_perm(u1, u0, 0x07060302u);
        const float r0f = y[2*i]   - __uint_as_float(u0 & 0xffff0000u);
        const float r1f = y[2*i+1] - __uint_as_float(u1 & 0xffff0000u);
        aS[1][idx] = pr2(r0f, r1f);
      }
    }
    __syncthreads();

    bf16x8 aF[4][NS];
    #pragma unroll
    for (int o = 0; o < 4; ++o) {
      const unsigned ab = (unsigned)((o * 16 + qi) * 16 + 4 * (g ^ (qi & 3)));
      #pragma unroll
      for (int s = 0; s < NS; ++s)
        aF[o][s] = *(const bf16x8*)&aS[s][ab];
    }
    #pragma unroll
    for (int j = 0; j < JT; ++j) {
      const unsigned bb = (unsigned)(((wv * JT + j) * 16 + qi) * 16 + 4 * (g ^ (qi & 3)));
      const bf16x8 b0 = *(const bf16x8*)&bS[0][bb];
      const bf16x8 b1 = *(const bf16x8*)&bS[1][bb];
      #pragma unroll
      for (int o = 0; o < 4; ++o) {
        acc[j][o] = __builtin_amdgcn_mfma_f32_16x16x32_bf16(aF[o][0], b0, acc[j][o], 0, 0, 0);
        acc[j][o] = __builtin_amdgcn_mfma_f32_16x16x32_bf16(aF[o][0], b1, acc[j][o], 0, 0, 0);
        acc[j][o] = __builtin_amdgcn_mfma_f32_16x16x32_bf16(aF[o][1], b0, acc[j][o], 0, 0, 0);
      }
    }
  }

  float bv[4][4];
  #pragma unroll
  for (int o = 0; o < 4; ++o)
    #pragma unroll
    for (int t = 0; t < 4; ++t)
      bv[o][t] = bias ? bias[oc0 + o * 16 + 4 * g + t] : 0.f;

  #pragma unroll
  for (int j = 0; j < JT; ++j) {
    const int px = p0 + (wv * JT + j) * 16 + qi;
    #pragma unroll
    for (int o = 0; o < 4; ++o)
      #pragma unroll
      for (int t = 0; t < 4; ++t)
        out[(size_t)(oc0 + o * 16 + 4 * g + t) * P + px] = acc[j][o][t] + bv[o][t];
  }
}

// ---------------------------------------------------------------------------
// Fold mlp into proj: Wc[o][b*128+i] = sum_j proj_w[o][b*128+j]*mlp_w[j][i]
// ---------------------------------------------------------------------------
__global__ __launch_bounds__(128) void k_foldw(
    const float* __restrict__ proj_w, const float* __restrict__ mlp_w,
    float* __restrict__ Wc)
{
  const int o = blockIdx.x;      // 0..127
  const int b = blockIdx.y;      // 0..2
  const int i = threadIdx.x;     // 0..127
  const float* pw = proj_w + o * 384 + b * 128;
  float acc = 0.f;
  for (int j = 0; j < 128; ++j)
    acc += pw[j] * mlp_w[j * 128 + i];
  Wc[o * 384 + b * 128 + i] = acc;
}
__global__ __launch_bounds__(128) void k_foldb(
    const float* __restrict__ proj_w, const float* __restrict__ mlp_b,
    float* __restrict__ bc)
{
  const int o = threadIdx.x;
  float acc = 0.f;
  for (int c = 0; c < 384; ++c) acc += proj_w[o * 384 + c] * mlp_b[c & 127];
  bc[o] = acc;
}

// ---------------------------------------------------------------------------
// Fused depthwise 3x3 + 5x5, v2: coalesced float4 staging.
// tS[r][c] = input x = c-2 (cols 0,1,130,131 always outside image -> 0).
// Interior: 640 float4 loads/block. Compute indexing identical to v1.
// ---------------------------------------------------------------------------
__global__ __launch_bounds__(256) void k_dwf(
    const float* __restrict__ in, const float* __restrict__ w3,
    const float* __restrict__ w5, float* __restrict__ out3,
    float* __restrict__ out5)
{
  const int c  = blockIdx.y;          // 0..383
  const int ty = blockIdx.x;          // 0..7
  const int y0 = ty * 16;
  __shared__ float tS[20][136];
  const float* ip = in + (size_t)c * P;

  if (threadIdx.x < 20) {             // x = -2,-1,128,129 are never in-image
    tS[threadIdx.x][0] = 0.f; tS[threadIdx.x][1] = 0.f;
    tS[threadIdx.x][130] = 0.f; tS[threadIdx.x][131] = 0.f;
  }
  // interior: 20 rows x 32 float4 (coalesced)
  for (int e = threadIdx.x; e < 640; e += 256) {
    const int r = e >> 5, q = e & 31;
    const int gy = y0 + r - 2;
    float4 v = make_float4(0.f, 0.f, 0.f, 0.f);
    if (gy >= 0 && gy < 128) v = *(const float4*)&ip[gy * 128 + q * 4];
    *(float4*)&tS[r][2 + q * 4] = v;   // 8B-aligned; compiler splits to b64 x2
  }
  __syncthreads();

  float a3[9], a5[25];
  #pragma unroll
  for (int i = 0; i < 9; ++i)  a3[i] = w3[c * 9 + i];
  #pragma unroll
  for (int i = 0; i < 25; ++i) a5[i] = w5[c * 25 + i];

  const int py  = threadIdx.x >> 4;           // 0..15
  const int px0 = (threadIdx.x & 15) * 8;     // 0..120
  float o3[8] = {}, o5[8] = {};
  #pragma unroll
  for (int r = 0; r < 5; ++r) {
    float4 sa = *(const float4*)&tS[py + r][px0];
    float4 sb = *(const float4*)&tS[py + r][px0 + 4];
    float4 sc = *(const float4*)&tS[py + r][px0 + 8];
    const float s[12] = {sa.x, sa.y, sa.z, sa.w, sb.x, sb.y, sb.z, sb.w,
                         sc.x, sc.y, sc.z, sc.w};
    #pragma unroll
    for (int j = 0; j < 8; ++j) {
      float acc = a5[r * 5 + 0] * s[j];
      #pragma unroll
      for (int d = 1; d < 5; ++d) acc += a5[r * 5 + d] * s[j + d];
      o5[j] += acc;
    }
    if (r >= 1 && r <= 3) {
      #pragma unroll
      for (int j = 0; j < 8; ++j) {
        float b = a3[(r - 1) * 3 + 0] * s[j + 1];
        b += a3[(r - 1) * 3 + 1] * s[j + 2];
        b += a3[(r - 1) * 3 + 2] * s[j + 3];
        o3[j] += b;
      }
    }
  }
  const size_t ob = (size_t)c * P + (y0 + py) * 128 + px0;
  float4* p3 = (float4*)&out3[ob];
  float4* p5 = (float4*)&out5[ob];
  p3[0] = make_float4(o3[0], o3[1], o3[2], o3[3]);
  p3[1] = make_float4(o3[4], o3[5], o3[6], o3[7]);
  p5[0] = make_float4(o5[0], o5[1], o5[2], o5[3]);
  p5[1] = make_float4(o5[4], o5[5], o5[6], o5[7]);
}

// ---------------------------------------------------------------------------
// Grouped pointwise (12 groups of 32->32), both branches in one launch.
// NO restrict on in/out: branch 1 runs in-place (all loads precede stores).
// ---------------------------------------------------------------------------
__global__ __launch_bounds__(256) void k_pw2(
    const float* in0, const float* __restrict__ w0, float* out0,
    const float* in1, const float* __restrict__ w1, float* out1)
{
  const float* in = blockIdx.z ? in1 : in0;
  const float* w  = blockIdx.z ? w1 : w0;
  float*      out = blockIdx.z ? out1 : out0;
  const int g = blockIdx.y;
  const int p = blockIdx.x * 256 + threadIdx.x;
  __shared__ float wL[1024];
  for (int e = threadIdx.x; e < 1024; e += 256) wL[e] = w[g * 1024 + e];
  __syncthreads();
  float r[32];
  #pragma unroll
  for (int i = 0; i < 32; ++i) r[i] = in[(g * 32 + i) * P + p];
  #pragma unroll
  for (int o = 0; o < 32; ++o) {
    float acc = 0.f;
    #pragma unroll
    for (int i = 0; i < 32; ++i) acc += wL[o * 32 + i] * r[i];
    out[(g * 32 + o) * P + p] = acc;
  }
}

// ---------------------------------------------------------------------------
// Window max v2. Block (window, branch), 4 waves; coalesced; shfl reduce.
// ---------------------------------------------------------------------------
__global__ __launch_bounds__(256) void k_winmax(
    const float* __restrict__ e0, const float* __restrict__ e1,
    const float* __restrict__ e2, float* __restrict__ qwin,
    float* __restrict__ kwin)
{
  const int b = blockIdx.y;
  const int wIdx = blockIdx.x;
  const float* e = (b == 0) ? e0 : ((b == 1) ? e1 : e2);
  const int wy = wIdx >> 3, wx = wIdx & 7;
  const int wv = threadIdx.x >> 6;
  const int lane = threadIdx.x & 63;
  const int half = lane >> 5, sub = lane & 31;
  const int row = sub >> 1, px8 = (sub & 1) * 8;
  const int base_off = (wy * 16 + row) * 128 + wx * 16 + px8;

  #pragma unroll 4
  for (int it = 0; it < 32; ++it) {
    const int c = it * 8 + wv * 2 + half;
    const float4* p4 = (const float4*)&e[(size_t)c * P + base_off];
    float4 v0 = p4[0], v1 = p4[1];
    float m = fmaxf(fmaxf(fmaxf(v0.x, v0.y), fmaxf(v0.z, v0.w)),
                    fmaxf(fmaxf(v1.x, v1.y), fmaxf(v1.z, v1.w)));
    #pragma unroll
    for (int s = 1; s <= 16; s <<= 1)
      m = fmaxf(m, __shfl_xor(m, s, 64));
    if (sub == 0) {
      if (c < 128) qwin[(b * 64 + wIdx) * 128 + c] = m;
      else         kwin[(b * 64 + wIdx) * 128 + (c - 128)] = m;
    }
  }
}

// ---------------------------------------------------------------------------
// Top-4 v2: one wave per query window; butterfly argmax (lowest-index ties).
// ---------------------------------------------------------------------------
__global__ __launch_bounds__(256) void k_topk(
    const float* __restrict__ qwin, const float* __restrict__ kwin,
    int* __restrict__ ridx)
{
  const int b = blockIdx.y;
  const int i = blockIdx.x * 4 + (threadIdx.x >> 6);
  const int j = threadIdx.x & 63;
  const float4* q4 = (const float4*)&qwin[(b * 64 + i) * 128];
  const float4* k4 = (const float4*)&kwin[(b * 64 + j) * 128];
  float v = 0.f;
  #pragma unroll
  for (int t = 0; t < 32; ++t) {
    float4 a = q4[t], c = k4[t];
    v += a.x * c.x + a.y * c.y + a.z * c.z + a.w * c.w;
  }
  int res[4];
  #pragma unroll
  for (int r = 0; r < 4; ++r) {
    float bv = v; int bj = j;
    #pragma unroll
    for (int s = 1; s < 64; s <<= 1) {
      const float ov = __shfl_xor(bv, s, 64);
      const int   oj = __shfl_xor(bj, s, 64);
      if (ov > bv || (ov == bv && oj < bj)) { bv = ov; bj = oj; }
    }
    res[r] = bj;
    if (j == bj) v = -INFINITY;
  }
  if (j == 0)
    *(int4*)&ridx[(b * 64 + i) * 4] = make_int4(res[0], res[1], res[2], res[3]);
}

// ---------------------------------------------------------------------------
// Repack Q/K/V into bf16 images pre-laid-out in LDS byte order.
// ---------------------------------------------------------------------------
__global__ __launch_bounds__(256) void k_repack(
    const float* __restrict__ e0, const float* __restrict__ e1,
    const float* __restrict__ e2, unsigned int* __restrict__ kvimg,
    unsigned int* __restrict__ qimg)
{
  const int fl = blockIdx.x + 64 * (blockIdx.y + 4 * blockIdx.z);
  const int nf = (fl & 7) * 96 + (fl >> 3);       // bijective: 768 = 8*96
  const int w = nf & 63, h = (nf >> 6) & 3, b = nf >> 8;
  const float* e = (b == 0) ? e0 : ((b == 1) ? e1 : e2);
  const int wy = w >> 3, wx = w & 7;
  const int jbase = wy * 16 * 128 + wx * 16;
  const int t = threadIdx.x;
  unsigned int* kwin_img = kvimg + (size_t)((b * 4 + h) * 64 + w) * 8192;
  unsigned int* qwin_img = qimg  + (size_t)((b * 4 + h) * 64 + w) * 4096;

  // K + Q: thread = pixel (key/query) 0..255, 16 u32 each
  {
    const int key = t;
    const int hw = jbase + (key >> 4) * 128 + (key & 15);
    const float* eK = e + (size_t)(128 + h * 32) * P + hw;
    const float* eQ = e + (size_t)(h * 32) * P + hw;
    const int half = key >> 7, kl = key & 127;
    unsigned int* kd = kwin_img + half * 4096 + kl * 16;
    unsigned int* qd = qwin_img + key * 16;
    #pragma unroll
    for (int dd = 0; dd < 16; ++dd) {
      float k0 = eK[(size_t)(2 * dd) * P], k1 = eK[(size_t)(2 * dd + 1) * P];
      kd[dd ^ ((kl & 3) << 2)] = packbf(k0, k1);
      float q0 = eQ[(size_t)(2 * dd) * P] * QSCALE;
      float q1 = eQ[(size_t)(2 * dd + 1) * P] * QSCALE;
      qd[dd] = packbf(q0, q1);
    }
  }
  // V^T: [d][key] row-XOR swizzled, u32 = key-pair; 16 u32 per thread
  {
    const int half = t >> 7, tt = t & 127;
    const int d = tt >> 2;
    const int kp0 = (tt & 3) * 16;
    const float* eV = e + (size_t)(256 + h * 32 + d) * P;
    unsigned int* vd = kwin_img + half * 4096 + 2048 + d * 64;
    #pragma unroll
    for (int i = 0; i < 16; ++i) {
      const int kp2 = kp0 + i;
      const int key = half * 128 + kp2 * 2;
      const int hw = jbase + (key >> 4) * 128 + (key & 15);
      float v0 = eV[hw], v1 = eV[hw + 1];
      vd[kp2 ^ ((d & 7) << 2)] = packbf(v0, v1);
    }
  }
}

// ---------------------------------------------------------------------------
// MFMA flash attention v6. 8 waves x 32 queries; XCD-swizzled. Single-barrier
// double-buffer; v_exp_f32 + v_cvt_pk_bf16_f32 softmax; setprio around MFMA.
// ---------------------------------------------------------------------------
__global__ __launch_bounds__(512, 4) void k_attn_mfma(
    const unsigned int* __restrict__ kvimg, const unsigned int* __restrict__ qimg,
    const int* __restrict__ ridx, float* __restrict__ attnch)
{
  const int fl = blockIdx.x + 64 * (blockIdx.y + 4 * blockIdx.z);
  const int nf = (fl & 7) * 96 + (fl >> 3);       // bijective XCD swizzle
  const int w = nf & 63, h = (nf >> 6) & 3, b = nf >> 8;
  const int tid = threadIdx.x;
  const int wv = tid >> 6, lane = tid & 63;
  const int qi = lane & 15, g = lane >> 4;
  const int wy = w >> 3, wx = w & 7;

  __shared__ __align__(16) unsigned int kvbuf[2][4096];   // 2 x 16KB

  const unsigned int* kwin = kvimg + (size_t)((b * 4 + h) * 64) * 8192;
  const unsigned int* qwin = qimg + (size_t)((b * 4 + h) * 64 + w) * 4096;

  // Q fragments: lane (qi,g), tile s: Q[q=(wv*2+s)*16+qi][d=8g..8g+7]
  bf16x8 qv[2];
  #pragma unroll
  for (int s = 0; s < 2; ++s) {
    union { uint4 u; bf16x8 v; } tq;
    tq.u = *(const uint4*)(qwin + ((wv * 2 + s) * 16 + qi) * 16 + g * 4);
    qv[s] = tq.v;
  }
  const int4 jv = *(const int4*)(ridx + (b * 64 + w) * 4);
  const int ja[4] = {jv.x, jv.y, jv.z, jv.w};

  const f32x4 fz = {0.f, 0.f, 0.f, 0.f};
  float m[2], l[2];
  f32x4 acc[2][2];
  #pragma unroll
  for (int s = 0; s < 2; ++s) {
    m[s] = -3.0e38f; l[s] = 0.f; acc[s][0] = fz; acc[s][1] = fz;
  }

  // prologue: load chunk 0 into regs
  uint4 st0, st1;
  {
    const uint4* s4 = (const uint4*)(kwin + (size_t)ja[0] * 8192);
    st0 = s4[tid]; st1 = s4[512 + tid];
  }

#define SOFTMAX_PACK(SC, S, PB) {                                           \
    float wmax = -3.0e38f;                                                  \
    _Pragma("unroll") for (int c = 0; c < 4; ++c)                           \
      _Pragma("unroll") for (int u = 0; u < 2; ++u)                         \
        _Pragma("unroll") for (int t2 = 0; t2 < 4; ++t2)                    \
          wmax = fmaxf(wmax, SC[c][u][t2]);                                 \
    wmax = fmaxf(wmax, __shfl_xor(wmax, 16, 64));                           \
    wmax = fmaxf(wmax, __shfl_xor(wmax, 32, 64));                           \
    const float mnew = fmaxf(m[S], wmax);                                   \
    const float corr = EXP2F(m[S] - mnew);                                  \
    m[S] = mnew;                                                            \
    acc[S][0] *= corr; acc[S][1] *= corr;                                   \
    float psum = 0.f;                                                       \
    _Pragma("unroll") for (int c = 0; c < 4; ++c)                           \
      _Pragma("unroll") for (int u = 0; u < 2; ++u) {                       \
        const float p0 = EXP2F(SC[c][u][0] - mnew);                         \
        const float p1 = EXP2F(SC[c][u][1] - mnew);                         \
        const float p2 = EXP2F(SC[c][u][2] - mnew);                         \
        const float p3 = EXP2F(SC[c][u][3] - mnew);                         \
        psum += (p0 + p1) + (p2 + p3);                                      \
        PB[c][2 * u]     = pk2(p0, p1);                                     \
        PB[c][2 * u + 1] = pk2(p2, p3);                                     \
      }                                                                     \
    l[S] = l[S] * corr + psum;                                              \
  }

  for (int ch = 0; ch < 8; ++ch) {
    // write chunk ch (staged in regs) into buf[ch&1]
    {
      uint4* d4 = (uint4*)kvbuf[ch & 1];
      d4[tid] = st0; d4[512 + tid] = st1;
    }
    // issue chunk ch+1 loads — latency hides under this chunk's compute
    if (ch < 7) {
      const int nx = ch + 1;
      const uint4* s4 = (const uint4*)(kwin + (size_t)ja[nx >> 1] * 8192
                                       + (size_t)(nx & 1) * 4096);
      st0 = s4[tid]; st1 = s4[512 + tid];
    }
    __syncthreads();   // chunk ch visible; prior chunk's readers are done

    const unsigned int* bc = kvbuf[ch & 1];
    const bf16x8* kp = (const bf16x8*)bc;
    const unsigned short* vsh = (const unsigned short*)(bc + 2048);

    f32x4 scA[4][2], scB[4][2];
    __builtin_amdgcn_s_setprio(1);
    #pragma unroll
    for (int c = 0; c < 4; ++c) {
      #pragma unroll
      for (int u = 0; u < 2; ++u) {
        const int key = 32 * c + 8 * (qi >> 2) + 4 * u + (qi & 3);
        const bf16x8 ka = kp[key * 4 + (g ^ (qi & 3))];
        scA[c][u] = __builtin_amdgcn_mfma_f32_16x16x32_bf16(ka, qv[0], fz, 0, 0, 0);
        scB[c][u] = __builtin_amdgcn_mfma_f32_16x16x32_bf16(ka, qv[1], fz, 0, 0, 0);
      }
    }
    __builtin_amdgcn_s_setprio(0);
    unsigned int pbA[4][4], pbB[4][4];
    SOFTMAX_PACK(scA, 0, pbA);
    SOFTMAX_PACK(scB, 1, pbB);
    __builtin_amdgcn_s_setprio(1);
    #pragma unroll
    for (int c = 0; c < 4; ++c) {
      #pragma unroll
      for (int dt = 0; dt < 2; ++dt) {
        const int d0 = dt * 16 + qi;
        const bf16x8 va = *(const bf16x8*)&vsh[
            (unsigned)((d0 * 128 + 32 * c + 8 * g) ^ ((d0 & 7) << 3))];
        union { unsigned int u4[4]; bf16x8 v; } pva, pvb;
        pva.u4[0] = pbA[c][0]; pva.u4[1] = pbA[c][1];
        pva.u4[2] = pbA[c][2]; pva.u4[3] = pbA[c][3];
        pvb.u4[0] = pbB[c][0]; pvb.u4[1] = pbB[c][1];
        pvb.u4[2] = pbB[c][2]; pvb.u4[3] = pbB[c][3];
        acc[0][dt] = __builtin_amdgcn_mfma_f32_16x16x32_bf16(va, pva.v, acc[0][dt], 0, 0, 0);
        acc[1][dt] = __builtin_amdgcn_mfma_f32_16x16x32_bf16(va, pvb.v, acc[1][dt], 0, 0, 0);
      }
    }
    __builtin_amdgcn_s_setprio(0);
  }
#undef SOFTMAX_PACK

  // epilogue: lane (qi,g) holds O^T[d = dt*16+4g+t][q = (wv*2+s)*16+qi]
  #pragma unroll
  for (int s = 0; s < 2; ++s) {
    float lsum = l[s];
    lsum += __shfl_xor(lsum, 16, 64);
    lsum += __shfl_xor(lsum, 32, 64);
    const float inv = 1.f / lsum;
    const int hwq = (wy * 16 + wv * 2 + s) * 128 + wx * 16 + qi;
    #pragma unroll
    for (int dt = 0; dt < 2; ++dt)
      #pragma unroll
      for (int t = 0; t < 4; ++t) {
        const int d = dt * 16 + 4 * g + t;
        attnch[(size_t)(b * 128 + h * 32 + d) * P + hwq] = acc[s][dt][t] * inv;
      }
  }
}

// ---------------------------------------------------------------------------
// LayerNorm over 128 channels per pixel. 256 blocks x 256 thr (4 ch-groups)
// ---------------------------------------------------------------------------
__global__ __launch_bounds__(256) void k_ln(
    const float* __restrict__ in, const float* __restrict__ gg,
    const float* __restrict__ bta, float* __restrict__ out)
{
  const int l = threadIdx.x & 63;
  const int grp = threadIdx.x >> 6;
  const int p = blockIdx.x * 64 + l;
  __shared__ float s1[4][64], s2[4][64];
  float vals[32];
  float a = 0.f, b2 = 0.f;
  #pragma unroll
  for (int i = 0; i < 32; ++i) {
    float v = in[(size_t)(grp * 32 + i) * P + p];
    vals[i] = v; a += v; b2 += v * v;
  }
  s1[grp][l] = a; s2[grp][l] = b2;
  __syncthreads();
  const float sum = s1[0][l] + s1[1][l] + s1[2][l] + s1[3][l];
  const float sq  = s2[0][l] + s2[1][l] + s2[2][l] + s2[3][l];
  const float mu = sum * (1.f / 128.f);
  const float var = sq * (1.f / 128.f) - mu * mu;
  const float rs = rsqrtf(var + 1e-5f);
  #pragma unroll
  for (int i = 0; i < 32; ++i) {
    const int c = grp * 32 + i;
    out[(size_t)c * P + p] = (vals[i] - mu) * rs * gg[c] + bta[c];
  }
}

// ---------------------------------------------------------------------------
extern "C" void kernel_launch(void* const* d_in, const int* in_sizes, int n_in,
                              void* d_out, int out_size, void* d_ws, size_t ws_size,
                              hipStream_t stream)
{
  (void)in_sizes; (void)n_in; (void)out_size;
  const float* x      = (const float*)d_in[0];
  const float* qkv2_w = (const float*)d_in[1];
  const float* dw3_w  = (const float*)d_in[2];
  const float* pw3_w  = (const float*)d_in[3];
  const float* dw5_w  = (const float*)d_in[4];
  const float* pw5_w  = (const float*)d_in[5];
  const float* mlp_w  = (const float*)d_in[6];
  const float* mlp_b  = (const float*)d_in[7];
  const float* proj_w = (const float*)d_in[8];
  const float* ln_g   = (const float*)d_in[9];
  const float* ln_b   = (const float*)d_in[10];

  float* ws = (float*)d_ws;
  const size_t CH = (size_t)384 * P;
  // region liveness:
  //  ws+0   : qkv (fp32)            -> projo
  //  ws+CH  : dwt3 (dw3 out)        -> qimg (bf16, after repack)
  //  ws+2CH : y3                    -> attnch
  //  ws+3CH : dwt5/y5 (pw in-place)
  //  ws+4CH : kvimg (bf16, 25.2MB)
  //  ws+5CH : qwin | kwin | ridx | Wc | bc
  float* qkv    = ws;
  float* dwt3   = ws + CH;
  float* y3     = ws + 2 * CH;
  float* y5     = ws + 3 * CH;           // also dwt5 (in-place pw5)
  float* qwin   = ws + 5 * CH;
  float* kwin   = qwin + 3 * 64 * 128;
  int*   ridx   = (int*)(kwin + 3 * 64 * 128);
  float* Wc     = (float*)(ridx + 768);
  float* bc     = Wc + 128 * 384;
  unsigned int* kvimg = (unsigned int*)(ws + 4 * CH);
  unsigned int* qimg  = (unsigned int*)dwt3;
  float* attnch = y3;
  float* projo  = qkv;
  (void)ws_size;

  // fold mlp into proj (independent of main chain)
  k_foldw<<<dim3(128, 3), 128, 0, stream>>>(proj_w, mlp_w, Wc);
  k_foldb<<<1, 128, 0, stream>>>(proj_w, mlp_b, bc);

  // qkv: 64oc x 128px tiles -> 768 blocks (3/CU even)
  k_conv_mfma<2, 2><<<dim3(128, 6, 1), 256, 0, stream>>>(x, qkv2_w, nullptr, qkv, 128, 0, 0);
  // fused depthwise 3x3 + 5x5 (reads qkv once), coalesced staging
  k_dwf<<<dim3(8, 384), 256, 0, stream>>>(qkv, dw3_w, dw5_w, dwt3, y5);
  // both grouped-pointwise branches in one launch
  k_pw2<<<dim3(64, 12, 2), 256, 0, stream>>>(dwt3, pw3_w, y3, y5, pw5_w, y5);
  k_winmax<<<dim3(64, 3), 256, 0, stream>>>(qkv, y3, y5, qwin, kwin);
  k_topk<<<dim3(16, 3), 256, 0, stream>>>(qwin, kwin, ridx);
  k_repack<<<dim3(64, 4, 3), 256, 0, stream>>>(qkv, y3, y5, kvimg, qimg);
  k_attn_mfma<<<dim3(64, 4, 3), 512, 0, stream>>>(kvimg, qimg, ridx, attnch);
  // fused mlp+proj: 64oc x 128px tiles -> 256 blocks (1/CU)
  k_conv_mfma<2, 2><<<dim3(128, 2, 1), 256, 0, stream>>>(attnch, Wc, bc, projo, 384, 0, 0);
  k_ln<<<dim3(256), 256, 0, stream>>>(projo, ln_g, ln_b, (float*)d_out);
}